// Round 13
// baseline (383.473 us; speedup 1.0000x reference)
//
#include <hip/hip_runtime.h>
#include <math.h>

#define HID 64
#define DF  128

typedef __attribute__((ext_vector_type(8))) short short8v;   // 8 bf16
typedef __attribute__((ext_vector_type(4))) float float4v;

__device__ __forceinline__ float silu_f(float v) {
    return v * __builtin_amdgcn_rcpf(1.0f + __expf(-v));
}

__device__ __forceinline__ unsigned short f2bf(float f) {   // RNE f32->bf16
    unsigned u = __float_as_uint(f);
    u += 0x7FFFu + ((u >> 16) & 1u);
    return (unsigned short)(u >> 16);
}

// 4 simultaneous wave-wide sums: one 6-level tree, 4-way ILP per level
__device__ __forceinline__ void wredsum4(float& a, float& b, float& c, float& d) {
#pragma unroll
    for (int t = 1; t < 64; t <<= 1) {
        a += __shfl_xor(a, t, 64);
        b += __shfl_xor(b, t, 64);
        c += __shfl_xor(c, t, 64);
        d += __shfl_xor(d, t, 64);
    }
}

// ---------------------------------------------------------------------------
// Weight transposes + bf16 MFMA A-fragment pack of We2.
// WbfA flat j = ((t*2+kc)*64 + lane)*8 + jj = bf16(We2[t*16+(lane&15)][kc*32+(lane>>4)*8+jj])
// ---------------------------------------------------------------------------
__global__ void prep_weights(const float* __restrict__ We1, const float* __restrict__ We2,
                             const float* __restrict__ Wh1, const float* __restrict__ Wh2,
                             float* __restrict__ Wt1, float* __restrict__ Wt2,
                             float* __restrict__ Wht1, float* __restrict__ Wht2,
                             unsigned short* __restrict__ WbfA) {
    int i = blockIdx.x * 256 + threadIdx.x;
    if (i < 257 * 64) {
        int k = i >> 6, f = i & 63;
        Wt1[i] = We1[f * 257 + k];
        return;
    }
    int j = i - 257 * 64;
    if (j < 64 * 64) {
        int k = j >> 6, f = j & 63;
        Wt2[j] = We2[f * 64 + k];
        return;
    }
    j -= 64 * 64;
    if (j < 192 * 64) {
        int k = j >> 6, f = j & 63;
        Wht1[j] = Wh1[f * 192 + k];
        return;
    }
    j -= 192 * 64;
    if (j < 64 * 128) {
        int f = j >> 7, c = j & 127;
        Wht2[j] = Wh2[c * 64 + f];
        return;
    }
    j -= 64 * 128;
    if (j < 4096) {
        int jj = j & 7, lane = (j >> 3) & 63, kc = (j >> 9) & 1, t = (j >> 10) & 3;
        int f = t * 16 + (lane & 15);
        int k = kc * 32 + ((lane >> 4) * 8) + jj;
        WbfA[j] = f2bf(We2[f * 64 + k]);
        return;
    }
}

// ---------------------------------------------------------------------------
// CSR build
// ---------------------------------------------------------------------------
__global__ __launch_bounds__(256) void count_kernel(const int* __restrict__ dst,
                                                    int* __restrict__ cnt,
                                                    int* __restrict__ rank, int E) {
    int e = blockIdx.x * 256 + threadIdx.x;
    if (e >= E) return;
    int r = atomicAdd(&cnt[dst[e]], 1);
    if (rank) rank[e] = r;
}

__global__ __launch_bounds__(1024) void scan1(const int* __restrict__ cnt,
                                              int* __restrict__ off,
                                              int* __restrict__ bsum, int N) {
    __shared__ int sm[1024];
    int tid = threadIdx.x;
    int i = blockIdx.x * 1024 + tid;
    int v = (i < N) ? cnt[i] : 0;
    sm[tid] = v;
    __syncthreads();
    for (int ofs = 1; ofs < 1024; ofs <<= 1) {
        int t = (tid >= ofs) ? sm[tid - ofs] : 0;
        __syncthreads();
        sm[tid] += t;
        __syncthreads();
    }
    if (i < N) off[i] = sm[tid] - v;
    if (tid == 1023) bsum[blockIdx.x] = sm[1023];
}

// scan3 with scan2 folded in: each block prefix-sums bsum (<=64 entries) itself
__global__ __launch_bounds__(256) void scan3(int* __restrict__ off,
                                             const int* __restrict__ bsum,
                                             int Nb, int N, int E) {
    __shared__ int pref[64];
    if (threadIdx.x == 0) {
        int s = 0;
        for (int b = 0; b < Nb; ++b) { pref[b] = s; s += bsum[b]; }
    }
    __syncthreads();
    int i = blockIdx.x * 256 + threadIdx.x;
    if (i > N) return;
    if (i == N) off[N] = E;
    else off[i] += pref[i >> 10];
}

__global__ __launch_bounds__(256) void scatter_src(const int* __restrict__ dst,
                                                   const int* __restrict__ srcI,
                                                   const int* __restrict__ rank,
                                                   const int* __restrict__ off,
                                                   int* __restrict__ csr_src, int E) {
    int e = blockIdx.x * 256 + threadIdx.x;
    if (e >= E) return;
    csr_src[off[dst[e]] + rank[e]] = srcI[e];
}

// degree-bucket sort (quad load balance): bucket = exact degree (capped 63)
__global__ __launch_bounds__(256) void deghist(const int* __restrict__ cnt,
                                               int* __restrict__ dcnt,
                                               int* __restrict__ dnr, int N) {
    int n = blockIdx.x * 256 + threadIdx.x;
    if (n >= N) return;
    int b = min(cnt[n], 63);
    dnr[n] = atomicAdd(&dcnt[b], 1);
}

__global__ void degscan(const int* __restrict__ dcnt, int* __restrict__ dofs) {
    if (threadIdx.x == 0) {
        int s = 0;
        for (int b = 0; b < 64; ++b) { dofs[b] = s; s += dcnt[b]; }
    }
}

__global__ __launch_bounds__(256) void degscatter(const int* __restrict__ cnt,
                                                  const int* __restrict__ dnr,
                                                  const int* __restrict__ dofs,
                                                  int* __restrict__ nodeorder, int N) {
    int n = blockIdx.x * 256 + threadIdx.x;
    if (n >= N) return;
    int b = min(cnt[n], 63);
    nodeorder[dofs[b] + dnr[n]] = n;
}

// ---------------------------------------------------------------------------
// node_pre (wave-feature-split): be1 BAKED into Pd; also packs x -> float4.
// ---------------------------------------------------------------------------
__global__ __launch_bounds__(256) void node_pre(const float* __restrict__ h,
                                                const float* __restrict__ Wt1,
                                                const float* __restrict__ be1,
                                                const float* __restrict__ xin,
                                                float* __restrict__ Ps,
                                                float* __restrict__ Pd,
                                                float4* __restrict__ x4, int N) {
    int lane = threadIdx.x & 63;
    int w = __builtin_amdgcn_readfirstlane(threadIdx.x >> 6);
    int n = blockIdx.x * 64 + lane;
    if (n >= N) return;
    if (w == 0)
        x4[n] = make_float4(xin[3 * n], xin[3 * n + 1], xin[3 * n + 2], 0.f);
    int f0 = w * 16;
    float accS[16], accD[16];
#pragma unroll
    for (int j = 0; j < 16; ++j) { accS[j] = 0.f; accD[j] = be1[f0 + j]; }
    const float4* row = (const float4*)(h + (size_t)n * DF);
    for (int k4 = 0; k4 < DF / 4; ++k4) {
        float4 v = row[k4];
        float hv4[4] = {v.x, v.y, v.z, v.w};
#pragma unroll
        for (int jj = 0; jj < 4; ++jj) {
            int k = k4 * 4 + jj;
            float hv = hv4[jj];
#pragma unroll
            for (int j = 0; j < 16; ++j) {
                accS[j] = fmaf(hv, Wt1[k * HID + f0 + j], accS[j]);
                accD[j] = fmaf(hv, Wt1[(DF + k) * HID + f0 + j], accD[j]);
            }
        }
    }
    float4* ps = (float4*)(Ps + (size_t)n * HID + f0);
    float4* pd = (float4*)(Pd + (size_t)n * HID + f0);
#pragma unroll
    for (int j4 = 0; j4 < 4; ++j4) {
        ps[j4] = make_float4(accS[4 * j4], accS[4 * j4 + 1], accS[4 * j4 + 2], accS[4 * j4 + 3]);
        pd[j4] = make_float4(accD[4 * j4], accD[4 * j4 + 1], accD[4 * j4 + 2], accD[4 * j4 + 3]);
    }
}

// ---------------------------------------------------------------------------
// Gather v10: QUAD-NODE batches. One wave owns 4 degree-sorted nodes; each
// 16-edge MFMA batch takes 4 edges from each node (column c -> node c>>2,
// position c&3). Each lane's column has a FIXED node -> baseK/xdv/beg/end
// are per-lane residents; inner body identical to v9 (LN/gates per-edge).
// Padding drops from E[ceil(deg/16)]=1.47x to ~1.1x.
// NEVER pass a min-waves launch_bounds arg (r3/r11 spill cliffs).
// ---------------------------------------------------------------------------
__global__ __launch_bounds__(256) void gather_kernel(
    const int* __restrict__ csr_src, const int* __restrict__ off,
    const int* __restrict__ nodeorder, const float4* __restrict__ x4,
    const float* __restrict__ Ps, const float* __restrict__ Pd,
    const float* __restrict__ Wt1, const unsigned short* __restrict__ WbfA,
    const float* __restrict__ be2,
    const float* __restrict__ ln_g, const float* __restrict__ ln_b,
    const float* __restrict__ Wx, const float* __restrict__ bx,
    const float* __restrict__ Wg, const float* __restrict__ bg,
    float* __restrict__ agg_h, float* __restrict__ agg_x, int N) {
    const int lane = threadIdx.x & 63;
    const int wid = blockIdx.x * 4 + (threadIdx.x >> 6);
    const int e16 = lane & 15;
    const int hg = lane >> 4;
    const int k0 = hg * 8;
    const int p = e16 & 3;                 // edge position within node
    if (wid * 4 >= N) return;
    const int slot = wid * 4 + (e16 >> 2); // this lane's node slot

    // resident A fragments (We2 bf16)
    short8v a[4][2];
#pragma unroll
    for (int t = 0; t < 4; ++t)
#pragma unroll
        for (int kc = 0; kc < 2; ++kc)
            a[t][kc] = *(const short8v*)&WbfA[(((t * 2 + kc) * 64) + lane) * 8];

    // z-side per-lane k-chunk constants
    const float* colW = Wt1 + 256 * HID;
    float colWk[16];
#pragma unroll
    for (int j = 0; j < 8; ++j) {
        colWk[j] = colW[k0 + j];
        colWk[8 + j] = colW[k0 + 32 + j];
    }
    // m-side per-lane params: be2, g*Wg, g*Wx (ln affine reloaded in epilogue)
    float be2r[16], cgr[16], cxr[16];
#pragma unroll
    for (int t = 0; t < 4; ++t)
#pragma unroll
        for (int r = 0; r < 4; ++r) {
            int f = t * 16 + hg * 4 + r;
            float g = ln_g[f];
            be2r[4 * t + r] = be2[f];
            cgr[4 * t + r] = g * Wg[f];
            cxr[4 * t + r] = g * Wx[f];
        }
    const float bgs = bg[0], bxs = bx[0];

    // wave-uniform loop invariants (feature=lane view)
    float Cg = ln_g[lane] * Wg[lane], Cx = ln_g[lane] * Wx[lane];
    float Cbg = ln_b[lane] * Wg[lane], Cbx = ln_b[lane] * Wx[lane];
    wredsum4(Cg, Cx, Cbg, Cbx);
    const float g0 = (lane < 16) ? 1.0f : 0.0f;

    // per-lane node state (fixed for the wave's lifetime)
    const int nj = (slot < N) ? nodeorder[slot] : -1;
    int beg = 0, end = 0;
    if (nj >= 0) { beg = off[nj]; end = off[nj + 1]; }
    const float4 xdv = (nj >= 0) ? x4[nj] : make_float4(0.f, 0.f, 0.f, 0.f);
    float baseK[16];
    {
        const float4v* pd4 = (const float4v*)(Pd + (size_t)max(nj, 0) * HID + k0);
        float4v p0 = pd4[0], p1 = pd4[1], p2 = pd4[8], p3 = pd4[9];
#pragma unroll
        for (int j = 0; j < 4; ++j) {
            baseK[j] = p0[j];
            baseK[4 + j] = p1[j];
            baseK[8 + j] = p2[j];
            baseK[12 + j] = p3[j];
        }
    }

    // batches = wave-max of per-node ceil(deg/4)
    int nb = (end - beg + 3) >> 2;
#pragma unroll
    for (int mk = 1; mk < 64; mk <<= 1) nb = max(nb, __shfl_xor(nb, mk, 64));
    nb = __builtin_amdgcn_readfirstlane(nb);

    float4v acc[4];
#pragma unroll
    for (int t = 0; t < 4; ++t) acc[t] = (float4v){0.f, 0.f, 0.f, 0.f};
    float ax0 = 0.f, ax1 = 0.f, ax2 = 0.f, Sa = 0.f, Smu = 0.f;

    for (int b = 0; b < nb; ++b) {
        int idx = beg + b * 4 + p;
        float validf = (idx < end) ? 1.0f : 0.0f;
        int ic = (idx < end) ? idx : (end > 0 ? end - 1 : 0);
        int s = csr_src[ic];
        float4 xs = x4[s];
        const float4v* ps4 = (const float4v*)(Ps + (size_t)s * HID + k0);
        float4v q0 = ps4[0], q1 = ps4[1], q2 = ps4[8], q3 = ps4[9];

        float r0 = xs.x - xdv.x, r1 = xs.y - xdv.y, r2 = xs.z - xdv.z;
        float dsq = r0 * r0 + r1 * r1 + r2 * r2;
        float inv = __builtin_amdgcn_rcpf(__builtin_amdgcn_sqrtf(dsq) + 1e-8f);

        short8v b0, b1;
#pragma unroll
        for (int j = 0; j < 4; ++j) {
            float z0 = q0[j] + baseK[j] + dsq * colWk[j];
            float z1 = q1[j] + baseK[4 + j] + dsq * colWk[4 + j];
            float z2 = q2[j] + baseK[8 + j] + dsq * colWk[8 + j];
            float z3 = q3[j] + baseK[12 + j] + dsq * colWk[12 + j];
            b0[j]     = (short)f2bf(silu_f(z0));
            b0[4 + j] = (short)f2bf(silu_f(z1));
            b1[j]     = (short)f2bf(silu_f(z2));
            b1[4 + j] = (short)f2bf(silu_f(z3));
        }

        float ms[16];
        float S1 = 0.f, S2 = 0.f, Sg = 0.f, Sx = 0.f;
#pragma unroll
        for (int t = 0; t < 4; ++t) {
            float4v c = (float4v){be2r[4 * t], be2r[4 * t + 1],
                                  be2r[4 * t + 2], be2r[4 * t + 3]};
            c = __builtin_amdgcn_mfma_f32_16x16x32_bf16(a[t][0], b0, c, 0, 0, 0);
            c = __builtin_amdgcn_mfma_f32_16x16x32_bf16(a[t][1], b1, c, 0, 0, 0);
#pragma unroll
            for (int r = 0; r < 4; ++r) {
                float v = c[r] * __builtin_amdgcn_rcpf(1.0f + __expf(-c[r]));
                ms[4 * t + r] = v;
                S1 += v;
                S2 = fmaf(v, v, S2);
                Sg = fmaf(v, cgr[4 * t + r], Sg);
                Sx = fmaf(v, cxr[4 * t + r], Sx);
            }
        }
        // per-edge sums across the 4 row-groups (columns preserved)
#pragma unroll
        for (int mk = 16; mk < 64; mk <<= 1) {
            S1 += __shfl_xor(S1, mk, 64);
            S2 += __shfl_xor(S2, mk, 64);
            Sg += __shfl_xor(Sg, mk, 64);
            Sx += __shfl_xor(Sx, mk, 64);
        }

        float mu = S1 * (1.0f / HID);
        float var = S2 * (1.0f / HID) - mu * mu;
        float rstd = __builtin_amdgcn_rsqf(var + 1e-5f);
        float dg = fmaf(rstd, Sg - mu * Cg, Cbg);
        float dx = fmaf(rstd, Sx - mu * Cx, Cbx);
        float alpha = __builtin_amdgcn_rcpf(1.0f + __expf(-(dg + bgs))) * validf;
        float ta = __expf(2.0f * fmaf(alpha, dx, bxs));
        float cwv = 1.0f - 2.0f * __builtin_amdgcn_rcpf(ta + 1.0f);

        float u = rstd * alpha;
        Sa += alpha;
        Smu = fmaf(u, mu, Smu);
#pragma unroll
        for (int t = 0; t < 4; ++t) {
            float4v av = acc[t];
#pragma unroll
            for (int r = 0; r < 4; ++r) av[r] = fmaf(u, ms[4 * t + r], av[r]);
            acc[t] = av;
        }
        float rc = inv * cwv * validf * g0;
        ax0 = fmaf(r0, rc, ax0);
        ax1 = fmaf(r1, rc, ax1);
        ax2 = fmaf(r2, rc, ax2);
    }

    // ---- epilogue: reduce over each node's 4 columns (xor 1,2) ----
#pragma unroll
    for (int t = 0; t < 4; ++t) {
        float4v av = acc[t];
#pragma unroll
        for (int r = 0; r < 4; ++r) {
            float v = av[r];
            v += __shfl_xor(v, 1, 64);
            v += __shfl_xor(v, 2, 64);
            av[r] = v;
        }
        acc[t] = av;
    }
    Sa  += __shfl_xor(Sa, 1, 64);  Sa  += __shfl_xor(Sa, 2, 64);
    Smu += __shfl_xor(Smu, 1, 64); Smu += __shfl_xor(Smu, 2, 64);
    ax0 += __shfl_xor(ax0, 1, 64); ax0 += __shfl_xor(ax0, 2, 64);
    ax1 += __shfl_xor(ax1, 1, 64); ax1 += __shfl_xor(ax1, 2, 64);
    ax2 += __shfl_xor(ax2, 1, 64); ax2 += __shfl_xor(ax2, 2, 64);

    if (p == 0 && nj >= 0) {
        float* dstp = agg_h + (size_t)nj * HID + hg * 4;
#pragma unroll
        for (int t = 0; t < 4; ++t) {
            int f = t * 16 + hg * 4;
            float4 o;
            o.x = fmaf(ln_g[f + 0], acc[t][0] - Smu, ln_b[f + 0] * Sa);
            o.y = fmaf(ln_g[f + 1], acc[t][1] - Smu, ln_b[f + 1] * Sa);
            o.z = fmaf(ln_g[f + 2], acc[t][2] - Smu, ln_b[f + 2] * Sa);
            o.w = fmaf(ln_g[f + 3], acc[t][3] - Smu, ln_b[f + 3] * Sa);
            *(float4*)(dstp + t * 16) = o;
        }
        if (hg == 0) {
            agg_x[nj * 3 + 0] = ax0;
            agg_x[nj * 3 + 1] = ax1;
            agg_x[nj * 3 + 2] = ax2;
        }
    }
}

// ---------------------------------------------------------------------------
// Fallback edge kernel (atomic aggregation) — only if ws too small for CSR.
// (Pd includes be1.)
// ---------------------------------------------------------------------------
__global__ __launch_bounds__(256) void edge_kernel_atomic(
    const int* __restrict__ src, const int* __restrict__ dst,
    const float* __restrict__ x,
    const float* __restrict__ Ps, const float* __restrict__ Pd,
    const float* __restrict__ Wt1, const float* __restrict__ Wt2,
    const float* __restrict__ be2,
    const float* __restrict__ ln_g, const float* __restrict__ ln_b,
    const float* __restrict__ Wx, const float* __restrict__ bx,
    const float* __restrict__ Wg, const float* __restrict__ bg,
    float* __restrict__ agg_h, float* __restrict__ agg_x, int E) {
    int e = blockIdx.x * 256 + threadIdx.x;
    if (e >= E) return;
    int s = src[e], d = dst[e];
    float r0 = x[s * 3] - x[d * 3], r1 = x[s * 3 + 1] - x[d * 3 + 1], r2 = x[s * 3 + 2] - x[d * 3 + 2];
    float dsq = r0 * r0 + r1 * r1 + r2 * r2;
    float inv = 1.0f / (sqrtf(dsq) + 1e-8f);
    float rn0 = r0 * inv, rn1 = r1 * inv, rn2 = r2 * inv;
    float z[HID];
    const float4* ps = (const float4*)(Ps + (size_t)s * HID);
    const float4* pd = (const float4*)(Pd + (size_t)d * HID);
    const float* colW = Wt1 + 256 * HID;
#pragma unroll
    for (int f4 = 0; f4 < HID / 4; ++f4) {
        float4 aa = ps[f4];
        float4 b = pd[f4];
        float av[4] = {aa.x, aa.y, aa.z, aa.w};
        float bv[4] = {b.x, b.y, b.z, b.w};
#pragma unroll
        for (int j = 0; j < 4; ++j) {
            int f = 4 * f4 + j;
            z[f] = silu_f(av[j] + bv[j] + dsq * colW[f]);
        }
    }
    float m[HID];
#pragma unroll
    for (int f = 0; f < HID; ++f) m[f] = be2[f];
#pragma unroll
    for (int k = 0; k < HID; ++k) {
        float zv = z[k];
#pragma unroll
        for (int f = 0; f < HID; ++f) m[f] = fmaf(zv, Wt2[k * HID + f], m[f]);
    }
#pragma unroll
    for (int f = 0; f < HID; ++f) m[f] = silu_f(m[f]);
    float mu = 0.f;
#pragma unroll
    for (int f = 0; f < HID; ++f) mu += m[f];
    mu *= (1.0f / HID);
    float var = 0.f;
#pragma unroll
    for (int f = 0; f < HID; ++f) {
        float t = m[f] - mu;
        var = fmaf(t, t, var);
    }
    var *= (1.0f / HID);
    float rstd = 1.0f / sqrtf(var + 1e-5f);
#pragma unroll
    for (int f = 0; f < HID; ++f) m[f] = (m[f] - mu) * rstd * ln_g[f] + ln_b[f];
    float dotg = 0.f, dotx = 0.f;
#pragma unroll
    for (int f = 0; f < HID; ++f) {
        dotg = fmaf(m[f], Wg[f], dotg);
        dotx = fmaf(m[f], Wx[f], dotx);
    }
    float alpha = 1.0f / (1.0f + __expf(-(dotg + bg[0])));
    float ta = __expf(2.0f * fmaf(alpha, dotx, bx[0]));
    float cw = 1.0f - 2.0f / (ta + 1.0f);
    float* ah = agg_h + (size_t)d * HID;
#pragma unroll
    for (int f = 0; f < HID; ++f) atomicAdd(&ah[f], m[f] * alpha);
    atomicAdd(&agg_x[d * 3 + 0], rn0 * cw);
    atomicAdd(&agg_x[d * 3 + 1], rn1 * cw);
    atomicAdd(&agg_x[d * 3 + 2], rn2 * cw);
}

// ---------------------------------------------------------------------------
// node_kernel (wave-feature-split, LDS hh exchange)
// ---------------------------------------------------------------------------
__global__ __launch_bounds__(256) void node_kernel(
    const float* __restrict__ h, const float* __restrict__ x,
    const float* __restrict__ agg_h, const float* __restrict__ agg_x,
    const int* __restrict__ degI,
    const float* __restrict__ Wht1, const float* __restrict__ Wht2,
    const float* __restrict__ bh1, const float* __restrict__ bh2,
    float* __restrict__ out, int N) {
    __shared__ float hh[64 * 65];
    int lane = threadIdx.x & 63;
    int w = __builtin_amdgcn_readfirstlane(threadIdx.x >> 6);
    int n = blockIdx.x * 64 + lane;

    if (n < N) {
        int f0 = w * 16;
        float t[16];
#pragma unroll
        for (int j = 0; j < 16; ++j) t[j] = bh1[f0 + j];
        const float4* rowH = (const float4*)(h + (size_t)n * DF);
        for (int k4 = 0; k4 < DF / 4; ++k4) {
            float4 v = rowH[k4];
            float hv4[4] = {v.x, v.y, v.z, v.w};
#pragma unroll
            for (int jj = 0; jj < 4; ++jj) {
                int k = k4 * 4 + jj;
                float hv = hv4[jj];
#pragma unroll
                for (int j = 0; j < 16; ++j) t[j] = fmaf(hv, Wht1[k * HID + f0 + j], t[j]);
            }
        }
        const float4* rowA = (const float4*)(agg_h + (size_t)n * HID);
        for (int k4 = 0; k4 < HID / 4; ++k4) {
            float4 v = rowA[k4];
            float hv4[4] = {v.x, v.y, v.z, v.w};
#pragma unroll
            for (int jj = 0; jj < 4; ++jj) {
                int k = DF + k4 * 4 + jj;
                float hv = hv4[jj];
#pragma unroll
                for (int j = 0; j < 16; ++j) t[j] = fmaf(hv, Wht1[k * HID + f0 + j], t[j]);
            }
        }
#pragma unroll
        for (int j = 0; j < 16; ++j) hh[lane * 65 + f0 + j] = silu_f(t[j]);
    }
    __syncthreads();
    if (n >= N) return;

    int c0 = w * 32;
    float o[32];
#pragma unroll
    for (int j = 0; j < 32; ++j) o[j] = bh2[c0 + j];
    for (int k = 0; k < HID; ++k) {
        float hv = hh[lane * 65 + k];
#pragma unroll
        for (int j = 0; j < 32; ++j) o[j] = fmaf(hv, Wht2[k * DF + c0 + j], o[j]);
    }
    float* oh = out + (size_t)n * DF + c0;
    const float* hrow = h + (size_t)n * DF + c0;
#pragma unroll
    for (int j4 = 0; j4 < 8; ++j4) {
        float4 hv = ((const float4*)hrow)[j4];
        float4 r;
        r.x = hv.x + o[4 * j4];
        r.y = hv.y + o[4 * j4 + 1];
        r.z = hv.z + o[4 * j4 + 2];
        r.w = hv.w + o[4 * j4 + 3];
        ((float4*)oh)[j4] = r;
    }
    if (w == 0) {
        float dv = (float)degI[n];
        float invd = 1.0f / fmaxf(dv, 1.0f);
        float* ox = out + (size_t)N * DF + (size_t)n * 3;
        ox[0] = x[n * 3 + 0] + agg_x[n * 3 + 0] * invd;
        ox[1] = x[n * 3 + 1] + agg_x[n * 3 + 1] * invd;
        ox[2] = x[n * 3 + 2] + agg_x[n * 3 + 2] * invd;
    }
}

extern "C" void kernel_launch(void* const* d_in, const int* in_sizes, int n_in,
                              void* d_out, int out_size, void* d_ws, size_t ws_size,
                              hipStream_t stream) {
    const float* h    = (const float*)d_in[0];
    const float* x    = (const float*)d_in[1];
    const int*   ei   = (const int*)d_in[2];
    const float* We1  = (const float*)d_in[3];
    const float* be1  = (const float*)d_in[4];
    const float* We2  = (const float*)d_in[5];
    const float* be2  = (const float*)d_in[6];
    const float* ln_g = (const float*)d_in[7];
    const float* ln_b = (const float*)d_in[8];
    const float* Wh1  = (const float*)d_in[9];
    const float* bh1  = (const float*)d_in[10];
    const float* Wh2  = (const float*)d_in[11];
    const float* bh2  = (const float*)d_in[12];
    const float* Wx   = (const float*)d_in[13];
    const float* bx   = (const float*)d_in[14];
    const float* Wg   = (const float*)d_in[15];
    const float* bg   = (const float*)d_in[16];

    const int E = in_sizes[2] / 2;
    const int N = in_sizes[0] / DF;
    const int* src = ei;
    const int* dst = ei + E;

    // ---- workspace carve (16B aligned regions) ----
    char* base = (char*)d_ws;
    size_t o = 0;
    auto carve = [&](size_t bytes) -> void* {
        void* r = base + o;
        o = (o + bytes + 15) & ~(size_t)15;
        return r;
    };
    float* agg_h = (float*)carve((size_t)N * HID * 4);
    float* agg_x = (float*)carve((size_t)N * 3 * 4);
    float* Wt1   = (float*)carve(257 * 64 * 4);
    float* Wt2   = (float*)carve(64 * 64 * 4);
    float* Wht1  = (float*)carve(192 * 64 * 4);
    float* Wht2  = (float*)carve(64 * 128 * 4);
    unsigned short* WbfA = (unsigned short*)carve(4096 * 2);
    int*   cnt   = (int*)carve((size_t)N * 4);
    int*   off   = (int*)carve(((size_t)N + 1) * 4);
    int*   bsum  = (int*)carve(256 * 4);
    int*   dcnt  = (int*)carve(64 * 4);
    int*   dofs  = (int*)carve(64 * 4);
    int*   dnr   = (int*)carve((size_t)N * 4);
    int*   nodeorder = (int*)carve((size_t)N * 4);
    float4* x4   = (float4*)carve((size_t)N * 16);
    int*   rank  = (int*)carve((size_t)E * 4);
    int*   csr_src = (int*)carve((size_t)E * 4);
    size_t need_full = o;

    // Ps/Pd live in d_out (N*128 <= out_size N*131); fully overwritten later.
    float* Ps = (float*)d_out;
    float* Pd = Ps + (size_t)N * HID;

    const int gE  = (E + 255) / 256;
    const int Nb  = (N + 1023) / 1024;
    const int gN64 = (N + 63) / 64;

    hipMemsetAsync(cnt, 0, (size_t)N * 4, stream);
    prep_weights<<<(45120 + 255) / 256, 256, 0, stream>>>(We1, We2, Wh1, Wh2,
                                                          Wt1, Wt2, Wht1, Wht2, WbfA);
    node_pre<<<gN64, 256, 0, stream>>>(h, Wt1, be1, x, Ps, Pd, x4, N);

    if (ws_size >= need_full) {
        // ---- CSR build + degree sort ----
        hipMemsetAsync(dcnt, 0, 64 * 4, stream);
        count_kernel<<<gE, 256, 0, stream>>>(dst, cnt, rank, E);
        scan1<<<Nb, 1024, 0, stream>>>(cnt, off, bsum, N);
        scan3<<<(N + 256) / 256, 256, 0, stream>>>(off, bsum, Nb, N, E);
        scatter_src<<<gE, 256, 0, stream>>>(dst, src, rank, off, csr_src, E);
        deghist<<<(N + 255) / 256, 256, 0, stream>>>(cnt, dcnt, dnr, N);
        degscan<<<1, 64, 0, stream>>>(dcnt, dofs);
        degscatter<<<(N + 255) / 256, 256, 0, stream>>>(cnt, dnr, dofs, nodeorder, N);
        // ---- fused gather: quad-node MFMA batches ----
        const int quads = (N + 3) / 4;              // one wave per quad
        gather_kernel<<<(quads + 3) / 4, 256, 0, stream>>>(
            csr_src, off, nodeorder, x4, Ps, Pd, Wt1, WbfA, be2,
            ln_g, ln_b, Wx, bx, Wg, bg, agg_h, agg_x, N);
    } else {
        // ---- fallback: atomic aggregation ----
        hipMemsetAsync(agg_h, 0, (size_t)N * 67 * 4, stream);
        count_kernel<<<gE, 256, 0, stream>>>(dst, cnt, nullptr, E);
        edge_kernel_atomic<<<gE, 256, 0, stream>>>(src, dst, x, Ps, Pd, Wt1, Wt2,
                                                   be2, ln_g, ln_b, Wx, bx,
                                                   Wg, bg, agg_h, agg_x, E);
    }

    node_kernel<<<gN64, 256, 0, stream>>>(h, x, agg_h, agg_x, cnt,
                                          Wht1, Wht2, bh1, bh2, (float*)d_out, N);
}

// Round 14
// 282.679 us; speedup vs baseline: 1.3566x; 1.3566x over previous
//
#include <hip/hip_runtime.h>
#include <math.h>

#define HID 64
#define DF  128
#define HB  256   // hist block size

typedef __attribute__((ext_vector_type(8))) short short8v;   // 8 bf16
typedef __attribute__((ext_vector_type(4))) float float4v;

__device__ __forceinline__ float silu_f(float v) {
    return v * __builtin_amdgcn_rcpf(1.0f + __expf(-v));
}

__device__ __forceinline__ unsigned short f2bf(float f) {   // RNE f32->bf16
    unsigned u = __float_as_uint(f);
    u += 0x7FFFu + ((u >> 16) & 1u);
    return (unsigned short)(u >> 16);
}

// 4 simultaneous wave-wide sums: one 6-level tree, 4-way ILP per level
__device__ __forceinline__ void wredsum4(float& a, float& b, float& c, float& d) {
#pragma unroll
    for (int t = 1; t < 64; t <<= 1) {
        a += __shfl_xor(a, t, 64);
        b += __shfl_xor(b, t, 64);
        c += __shfl_xor(c, t, 64);
        d += __shfl_xor(d, t, 64);
    }
}

// ---------------------------------------------------------------------------
// Weight transposes + bf16 MFMA A-fragment pack of We2.
// ---------------------------------------------------------------------------
__global__ void prep_weights(const float* __restrict__ We1, const float* __restrict__ We2,
                             const float* __restrict__ Wh1, const float* __restrict__ Wh2,
                             float* __restrict__ Wt1, float* __restrict__ Wt2,
                             float* __restrict__ Wht1, float* __restrict__ Wht2,
                             unsigned short* __restrict__ WbfA) {
    int i = blockIdx.x * 256 + threadIdx.x;
    if (i < 257 * 64) {
        int k = i >> 6, f = i & 63;
        Wt1[i] = We1[f * 257 + k];
        return;
    }
    int j = i - 257 * 64;
    if (j < 64 * 64) {
        int k = j >> 6, f = j & 63;
        Wt2[j] = We2[f * 64 + k];
        return;
    }
    j -= 64 * 64;
    if (j < 192 * 64) {
        int k = j >> 6, f = j & 63;
        Wht1[j] = Wh1[f * 192 + k];
        return;
    }
    j -= 192 * 64;
    if (j < 64 * 128) {
        int f = j >> 7, c = j & 127;
        Wht2[j] = Wh2[c * 64 + f];
        return;
    }
    j -= 64 * 128;
    if (j < 4096) {
        int jj = j & 7, lane = (j >> 3) & 63, kc = (j >> 9) & 1, t = (j >> 10) & 3;
        int f = t * 16 + (lane & 15);
        int k = kc * 32 + ((lane >> 4) * 8) + jj;
        WbfA[j] = f2bf(We2[f * 64 + k]);
        return;
    }
}

// ---------------------------------------------------------------------------
// CSR build
// ---------------------------------------------------------------------------
__global__ __launch_bounds__(256) void count_kernel(const int* __restrict__ dst,
                                                    int* __restrict__ cnt,
                                                    int* __restrict__ rank, int E) {
    int e = blockIdx.x * 256 + threadIdx.x;
    if (e >= E) return;
    int r = atomicAdd(&cnt[dst[e]], 1);
    if (rank) rank[e] = r;
}

__global__ __launch_bounds__(1024) void scan1(const int* __restrict__ cnt,
                                              int* __restrict__ off,
                                              int* __restrict__ bsum, int N) {
    __shared__ int sm[1024];
    int tid = threadIdx.x;
    int i = blockIdx.x * 1024 + tid;
    int v = (i < N) ? cnt[i] : 0;
    sm[tid] = v;
    __syncthreads();
    for (int ofs = 1; ofs < 1024; ofs <<= 1) {
        int t = (tid >= ofs) ? sm[tid - ofs] : 0;
        __syncthreads();
        sm[tid] += t;
        __syncthreads();
    }
    if (i < N) off[i] = sm[tid] - v;
    if (tid == 1023) bsum[blockIdx.x] = sm[1023];
}

// scan3 with scan2 folded in: each block prefix-sums bsum (<=64 entries) itself
__global__ __launch_bounds__(256) void scan3(int* __restrict__ off,
                                             const int* __restrict__ bsum,
                                             int Nb, int N, int E) {
    __shared__ int pref[64];
    if (threadIdx.x == 0) {
        int s = 0;
        for (int b = 0; b < Nb; ++b) { pref[b] = s; s += bsum[b]; }
    }
    __syncthreads();
    int i = blockIdx.x * 256 + threadIdx.x;
    if (i > N) return;
    if (i == N) off[N] = E;
    else off[i] += pref[i >> 10];
}

__global__ __launch_bounds__(256) void scatter_src(const int* __restrict__ dst,
                                                   const int* __restrict__ srcI,
                                                   const int* __restrict__ rank,
                                                   const int* __restrict__ off,
                                                   int* __restrict__ csr_src, int E) {
    int e = blockIdx.x * 256 + threadIdx.x;
    if (e >= E) return;
    csr_src[off[dst[e]] + rank[e]] = srcI[e];
}

// ---------------------------------------------------------------------------
// Degree counting-sort, two-level (NO global atomics — r13's deghist was a
// 64-address atomic contention bomb at 142us):
//  1) hist_local: per-block LDS histogram; local rank from LDS atomic return
//  2) hist_scan: 64 threads (1/bucket) turn blockcnt into global bases in place
//  3) degscatter2: pure scattered stores
// ---------------------------------------------------------------------------
__global__ __launch_bounds__(HB) void hist_local(const int* __restrict__ cnt,
                                                 int* __restrict__ lrank,
                                                 int* __restrict__ blockcnt, int N) {
    __shared__ int lh[64];
    int tid = threadIdx.x;
    if (tid < 64) lh[tid] = 0;
    __syncthreads();
    int n = blockIdx.x * HB + tid;
    if (n < N) {
        int b = min(cnt[n], 63);
        lrank[n] = atomicAdd(&lh[b], 1);
    }
    __syncthreads();
    if (tid < 64) blockcnt[blockIdx.x * 64 + tid] = lh[tid];
}

__global__ void hist_scan(int* __restrict__ blockcnt, int nblk) {
    __shared__ int tot[64];
    int b = threadIdx.x;
    if (b >= 64) return;
    int s = 0;
    for (int k = 0; k < nblk; ++k) s += blockcnt[k * 64 + b];
    tot[b] = s;
    __syncthreads();
    int base = 0;
    for (int k = 0; k < b; ++k) base += tot[k];
    int run = base;
    for (int k = 0; k < nblk; ++k) {
        int c = blockcnt[k * 64 + b];
        blockcnt[k * 64 + b] = run;
        run += c;
    }
}

__global__ __launch_bounds__(HB) void degscatter2(const int* __restrict__ cnt,
                                                  const int* __restrict__ lrank,
                                                  const int* __restrict__ blockcnt,
                                                  int* __restrict__ nodeorder, int N) {
    int n = blockIdx.x * HB + threadIdx.x;
    if (n >= N) return;
    int b = min(cnt[n], 63);
    nodeorder[blockcnt[(n / HB) * 64 + b] + lrank[n]] = n;
}

// ---------------------------------------------------------------------------
// node_pre (wave-feature-split): be1 BAKED into Pd; also packs x -> float4.
// ---------------------------------------------------------------------------
__global__ __launch_bounds__(256) void node_pre(const float* __restrict__ h,
                                                const float* __restrict__ Wt1,
                                                const float* __restrict__ be1,
                                                const float* __restrict__ xin,
                                                float* __restrict__ Ps,
                                                float* __restrict__ Pd,
                                                float4* __restrict__ x4, int N) {
    int lane = threadIdx.x & 63;
    int w = __builtin_amdgcn_readfirstlane(threadIdx.x >> 6);
    int n = blockIdx.x * 64 + lane;
    if (n >= N) return;
    if (w == 0)
        x4[n] = make_float4(xin[3 * n], xin[3 * n + 1], xin[3 * n + 2], 0.f);
    int f0 = w * 16;
    float accS[16], accD[16];
#pragma unroll
    for (int j = 0; j < 16; ++j) { accS[j] = 0.f; accD[j] = be1[f0 + j]; }
    const float4* row = (const float4*)(h + (size_t)n * DF);
    for (int k4 = 0; k4 < DF / 4; ++k4) {
        float4 v = row[k4];
        float hv4[4] = {v.x, v.y, v.z, v.w};
#pragma unroll
        for (int jj = 0; jj < 4; ++jj) {
            int k = k4 * 4 + jj;
            float hv = hv4[jj];
#pragma unroll
            for (int j = 0; j < 16; ++j) {
                accS[j] = fmaf(hv, Wt1[k * HID + f0 + j], accS[j]);
                accD[j] = fmaf(hv, Wt1[(DF + k) * HID + f0 + j], accD[j]);
            }
        }
    }
    float4* ps = (float4*)(Ps + (size_t)n * HID + f0);
    float4* pd = (float4*)(Pd + (size_t)n * HID + f0);
#pragma unroll
    for (int j4 = 0; j4 < 4; ++j4) {
        ps[j4] = make_float4(accS[4 * j4], accS[4 * j4 + 1], accS[4 * j4 + 2], accS[4 * j4 + 3]);
        pd[j4] = make_float4(accD[4 * j4], accD[4 * j4 + 1], accD[4 * j4 + 2], accD[4 * j4 + 3]);
    }
}

// ---------------------------------------------------------------------------
// Gather v10: QUAD-NODE batches (unchanged from r13 — that part worked).
// One wave owns 4 degree-sorted nodes; each 16-edge MFMA batch takes 4 edges
// from each node (column c -> node c>>2, position c&3).
// NEVER pass a min-waves launch_bounds arg (r3/r11 spill cliffs).
// ---------------------------------------------------------------------------
__global__ __launch_bounds__(256) void gather_kernel(
    const int* __restrict__ csr_src, const int* __restrict__ off,
    const int* __restrict__ nodeorder, const float4* __restrict__ x4,
    const float* __restrict__ Ps, const float* __restrict__ Pd,
    const float* __restrict__ Wt1, const unsigned short* __restrict__ WbfA,
    const float* __restrict__ be2,
    const float* __restrict__ ln_g, const float* __restrict__ ln_b,
    const float* __restrict__ Wx, const float* __restrict__ bx,
    const float* __restrict__ Wg, const float* __restrict__ bg,
    float* __restrict__ agg_h, float* __restrict__ agg_x, int N) {
    const int lane = threadIdx.x & 63;
    const int wid = blockIdx.x * 4 + (threadIdx.x >> 6);
    const int e16 = lane & 15;
    const int hg = lane >> 4;
    const int k0 = hg * 8;
    const int p = e16 & 3;                 // edge position within node
    if (wid * 4 >= N) return;
    const int slot = wid * 4 + (e16 >> 2); // this lane's node slot

    // resident A fragments (We2 bf16)
    short8v a[4][2];
#pragma unroll
    for (int t = 0; t < 4; ++t)
#pragma unroll
        for (int kc = 0; kc < 2; ++kc)
            a[t][kc] = *(const short8v*)&WbfA[(((t * 2 + kc) * 64) + lane) * 8];

    // z-side per-lane k-chunk constants
    const float* colW = Wt1 + 256 * HID;
    float colWk[16];
#pragma unroll
    for (int j = 0; j < 8; ++j) {
        colWk[j] = colW[k0 + j];
        colWk[8 + j] = colW[k0 + 32 + j];
    }
    // m-side per-lane params: be2, g*Wg, g*Wx (ln affine reloaded in epilogue)
    float be2r[16], cgr[16], cxr[16];
#pragma unroll
    for (int t = 0; t < 4; ++t)
#pragma unroll
        for (int r = 0; r < 4; ++r) {
            int f = t * 16 + hg * 4 + r;
            float g = ln_g[f];
            be2r[4 * t + r] = be2[f];
            cgr[4 * t + r] = g * Wg[f];
            cxr[4 * t + r] = g * Wx[f];
        }
    const float bgs = bg[0], bxs = bx[0];

    // wave-uniform loop invariants (feature=lane view)
    float Cg = ln_g[lane] * Wg[lane], Cx = ln_g[lane] * Wx[lane];
    float Cbg = ln_b[lane] * Wg[lane], Cbx = ln_b[lane] * Wx[lane];
    wredsum4(Cg, Cx, Cbg, Cbx);
    const float g0 = (lane < 16) ? 1.0f : 0.0f;

    // per-lane node state (fixed for the wave's lifetime)
    const int nj = (slot < N) ? nodeorder[slot] : -1;
    int beg = 0, end = 0;
    if (nj >= 0) { beg = off[nj]; end = off[nj + 1]; }
    const float4 xdv = (nj >= 0) ? x4[nj] : make_float4(0.f, 0.f, 0.f, 0.f);
    float baseK[16];
    {
        const float4v* pd4 = (const float4v*)(Pd + (size_t)max(nj, 0) * HID + k0);
        float4v p0 = pd4[0], p1 = pd4[1], p2 = pd4[8], p3 = pd4[9];
#pragma unroll
        for (int j = 0; j < 4; ++j) {
            baseK[j] = p0[j];
            baseK[4 + j] = p1[j];
            baseK[8 + j] = p2[j];
            baseK[12 + j] = p3[j];
        }
    }

    // batches = wave-max of per-node ceil(deg/4)
    int nb = (end - beg + 3) >> 2;
#pragma unroll
    for (int mk = 1; mk < 64; mk <<= 1) nb = max(nb, __shfl_xor(nb, mk, 64));
    nb = __builtin_amdgcn_readfirstlane(nb);

    float4v acc[4];
#pragma unroll
    for (int t = 0; t < 4; ++t) acc[t] = (float4v){0.f, 0.f, 0.f, 0.f};
    float ax0 = 0.f, ax1 = 0.f, ax2 = 0.f, Sa = 0.f, Smu = 0.f;

    for (int b = 0; b < nb; ++b) {
        int idx = beg + b * 4 + p;
        float validf = (idx < end) ? 1.0f : 0.0f;
        int ic = (idx < end) ? idx : (end > 0 ? end - 1 : 0);
        int s = csr_src[ic];
        float4 xs = x4[s];
        const float4v* ps4 = (const float4v*)(Ps + (size_t)s * HID + k0);
        float4v q0 = ps4[0], q1 = ps4[1], q2 = ps4[8], q3 = ps4[9];

        float r0 = xs.x - xdv.x, r1 = xs.y - xdv.y, r2 = xs.z - xdv.z;
        float dsq = r0 * r0 + r1 * r1 + r2 * r2;
        float inv = __builtin_amdgcn_rcpf(__builtin_amdgcn_sqrtf(dsq) + 1e-8f);

        short8v b0, b1;
#pragma unroll
        for (int j = 0; j < 4; ++j) {
            float z0 = q0[j] + baseK[j] + dsq * colWk[j];
            float z1 = q1[j] + baseK[4 + j] + dsq * colWk[4 + j];
            float z2 = q2[j] + baseK[8 + j] + dsq * colWk[8 + j];
            float z3 = q3[j] + baseK[12 + j] + dsq * colWk[12 + j];
            b0[j]     = (short)f2bf(silu_f(z0));
            b0[4 + j] = (short)f2bf(silu_f(z1));
            b1[j]     = (short)f2bf(silu_f(z2));
            b1[4 + j] = (short)f2bf(silu_f(z3));
        }

        float ms[16];
        float S1 = 0.f, S2 = 0.f, Sg = 0.f, Sx = 0.f;
#pragma unroll
        for (int t = 0; t < 4; ++t) {
            float4v c = (float4v){be2r[4 * t], be2r[4 * t + 1],
                                  be2r[4 * t + 2], be2r[4 * t + 3]};
            c = __builtin_amdgcn_mfma_f32_16x16x32_bf16(a[t][0], b0, c, 0, 0, 0);
            c = __builtin_amdgcn_mfma_f32_16x16x32_bf16(a[t][1], b1, c, 0, 0, 0);
#pragma unroll
            for (int r = 0; r < 4; ++r) {
                float v = c[r] * __builtin_amdgcn_rcpf(1.0f + __expf(-c[r]));
                ms[4 * t + r] = v;
                S1 += v;
                S2 = fmaf(v, v, S2);
                Sg = fmaf(v, cgr[4 * t + r], Sg);
                Sx = fmaf(v, cxr[4 * t + r], Sx);
            }
        }
        // per-edge sums across the 4 row-groups (columns preserved)
#pragma unroll
        for (int mk = 16; mk < 64; mk <<= 1) {
            S1 += __shfl_xor(S1, mk, 64);
            S2 += __shfl_xor(S2, mk, 64);
            Sg += __shfl_xor(Sg, mk, 64);
            Sx += __shfl_xor(Sx, mk, 64);
        }

        float mu = S1 * (1.0f / HID);
        float var = S2 * (1.0f / HID) - mu * mu;
        float rstd = __builtin_amdgcn_rsqf(var + 1e-5f);
        float dg = fmaf(rstd, Sg - mu * Cg, Cbg);
        float dx = fmaf(rstd, Sx - mu * Cx, Cbx);
        float alpha = __builtin_amdgcn_rcpf(1.0f + __expf(-(dg + bgs))) * validf;
        float ta = __expf(2.0f * fmaf(alpha, dx, bxs));
        float cwv = 1.0f - 2.0f * __builtin_amdgcn_rcpf(ta + 1.0f);

        float u = rstd * alpha;
        Sa += alpha;
        Smu = fmaf(u, mu, Smu);
#pragma unroll
        for (int t = 0; t < 4; ++t) {
            float4v av = acc[t];
#pragma unroll
            for (int r = 0; r < 4; ++r) av[r] = fmaf(u, ms[4 * t + r], av[r]);
            acc[t] = av;
        }
        float rc = inv * cwv * validf * g0;
        ax0 = fmaf(r0, rc, ax0);
        ax1 = fmaf(r1, rc, ax1);
        ax2 = fmaf(r2, rc, ax2);
    }

    // ---- epilogue: reduce over each node's 4 columns (xor 1,2) ----
#pragma unroll
    for (int t = 0; t < 4; ++t) {
        float4v av = acc[t];
#pragma unroll
        for (int r = 0; r < 4; ++r) {
            float v = av[r];
            v += __shfl_xor(v, 1, 64);
            v += __shfl_xor(v, 2, 64);
            av[r] = v;
        }
        acc[t] = av;
    }
    Sa  += __shfl_xor(Sa, 1, 64);  Sa  += __shfl_xor(Sa, 2, 64);
    Smu += __shfl_xor(Smu, 1, 64); Smu += __shfl_xor(Smu, 2, 64);
    ax0 += __shfl_xor(ax0, 1, 64); ax0 += __shfl_xor(ax0, 2, 64);
    ax1 += __shfl_xor(ax1, 1, 64); ax1 += __shfl_xor(ax1, 2, 64);
    ax2 += __shfl_xor(ax2, 1, 64); ax2 += __shfl_xor(ax2, 2, 64);

    if (p == 0 && nj >= 0) {
        float* dstp = agg_h + (size_t)nj * HID + hg * 4;
#pragma unroll
        for (int t = 0; t < 4; ++t) {
            int f = t * 16 + hg * 4;
            float4 o;
            o.x = fmaf(ln_g[f + 0], acc[t][0] - Smu, ln_b[f + 0] * Sa);
            o.y = fmaf(ln_g[f + 1], acc[t][1] - Smu, ln_b[f + 1] * Sa);
            o.z = fmaf(ln_g[f + 2], acc[t][2] - Smu, ln_b[f + 2] * Sa);
            o.w = fmaf(ln_g[f + 3], acc[t][3] - Smu, ln_b[f + 3] * Sa);
            *(float4*)(dstp + t * 16) = o;
        }
        if (hg == 0) {
            agg_x[nj * 3 + 0] = ax0;
            agg_x[nj * 3 + 1] = ax1;
            agg_x[nj * 3 + 2] = ax2;
        }
    }
}

// ---------------------------------------------------------------------------
// Fallback edge kernel (atomic aggregation) — only if ws too small for CSR.
// (Pd includes be1.)
// ---------------------------------------------------------------------------
__global__ __launch_bounds__(256) void edge_kernel_atomic(
    const int* __restrict__ src, const int* __restrict__ dst,
    const float* __restrict__ x,
    const float* __restrict__ Ps, const float* __restrict__ Pd,
    const float* __restrict__ Wt1, const float* __restrict__ Wt2,
    const float* __restrict__ be2,
    const float* __restrict__ ln_g, const float* __restrict__ ln_b,
    const float* __restrict__ Wx, const float* __restrict__ bx,
    const float* __restrict__ Wg, const float* __restrict__ bg,
    float* __restrict__ agg_h, float* __restrict__ agg_x, int E) {
    int e = blockIdx.x * 256 + threadIdx.x;
    if (e >= E) return;
    int s = src[e], d = dst[e];
    float r0 = x[s * 3] - x[d * 3], r1 = x[s * 3 + 1] - x[d * 3 + 1], r2 = x[s * 3 + 2] - x[d * 3 + 2];
    float dsq = r0 * r0 + r1 * r1 + r2 * r2;
    float inv = 1.0f / (sqrtf(dsq) + 1e-8f);
    float rn0 = r0 * inv, rn1 = r1 * inv, rn2 = r2 * inv;
    float z[HID];
    const float4* ps = (const float4*)(Ps + (size_t)s * HID);
    const float4* pd = (const float4*)(Pd + (size_t)d * HID);
    const float* colW = Wt1 + 256 * HID;
#pragma unroll
    for (int f4 = 0; f4 < HID / 4; ++f4) {
        float4 aa = ps[f4];
        float4 b = pd[f4];
        float av[4] = {aa.x, aa.y, aa.z, aa.w};
        float bv[4] = {b.x, b.y, b.z, b.w};
#pragma unroll
        for (int j = 0; j < 4; ++j) {
            int f = 4 * f4 + j;
            z[f] = silu_f(av[j] + bv[j] + dsq * colW[f]);
        }
    }
    float m[HID];
#pragma unroll
    for (int f = 0; f < HID; ++f) m[f] = be2[f];
#pragma unroll
    for (int k = 0; k < HID; ++k) {
        float zv = z[k];
#pragma unroll
        for (int f = 0; f < HID; ++f) m[f] = fmaf(zv, Wt2[k * HID + f], m[f]);
    }
#pragma unroll
    for (int f = 0; f < HID; ++f) m[f] = silu_f(m[f]);
    float mu = 0.f;
#pragma unroll
    for (int f = 0; f < HID; ++f) mu += m[f];
    mu *= (1.0f / HID);
    float var = 0.f;
#pragma unroll
    for (int f = 0; f < HID; ++f) {
        float t = m[f] - mu;
        var = fmaf(t, t, var);
    }
    var *= (1.0f / HID);
    float rstd = 1.0f / sqrtf(var + 1e-5f);
#pragma unroll
    for (int f = 0; f < HID; ++f) m[f] = (m[f] - mu) * rstd * ln_g[f] + ln_b[f];
    float dotg = 0.f, dotx = 0.f;
#pragma unroll
    for (int f = 0; f < HID; ++f) {
        dotg = fmaf(m[f], Wg[f], dotg);
        dotx = fmaf(m[f], Wx[f], dotx);
    }
    float alpha = 1.0f / (1.0f + __expf(-(dotg + bg[0])));
    float ta = __expf(2.0f * fmaf(alpha, dotx, bx[0]));
    float cw = 1.0f - 2.0f / (ta + 1.0f);
    float* ah = agg_h + (size_t)d * HID;
#pragma unroll
    for (int f = 0; f < HID; ++f) atomicAdd(&ah[f], m[f] * alpha);
    atomicAdd(&agg_x[d * 3 + 0], rn0 * cw);
    atomicAdd(&agg_x[d * 3 + 1], rn1 * cw);
    atomicAdd(&agg_x[d * 3 + 2], rn2 * cw);
}

// ---------------------------------------------------------------------------
// node_kernel (wave-feature-split, LDS hh exchange)
// ---------------------------------------------------------------------------
__global__ __launch_bounds__(256) void node_kernel(
    const float* __restrict__ h, const float* __restrict__ x,
    const float* __restrict__ agg_h, const float* __restrict__ agg_x,
    const int* __restrict__ degI,
    const float* __restrict__ Wht1, const float* __restrict__ Wht2,
    const float* __restrict__ bh1, const float* __restrict__ bh2,
    float* __restrict__ out, int N) {
    __shared__ float hh[64 * 65];
    int lane = threadIdx.x & 63;
    int w = __builtin_amdgcn_readfirstlane(threadIdx.x >> 6);
    int n = blockIdx.x * 64 + lane;

    if (n < N) {
        int f0 = w * 16;
        float t[16];
#pragma unroll
        for (int j = 0; j < 16; ++j) t[j] = bh1[f0 + j];
        const float4* rowH = (const float4*)(h + (size_t)n * DF);
        for (int k4 = 0; k4 < DF / 4; ++k4) {
            float4 v = rowH[k4];
            float hv4[4] = {v.x, v.y, v.z, v.w};
#pragma unroll
            for (int jj = 0; jj < 4; ++jj) {
                int k = k4 * 4 + jj;
                float hv = hv4[jj];
#pragma unroll
                for (int j = 0; j < 16; ++j) t[j] = fmaf(hv, Wht1[k * HID + f0 + j], t[j]);
            }
        }
        const float4* rowA = (const float4*)(agg_h + (size_t)n * HID);
        for (int k4 = 0; k4 < HID / 4; ++k4) {
            float4 v = rowA[k4];
            float hv4[4] = {v.x, v.y, v.z, v.w};
#pragma unroll
            for (int jj = 0; jj < 4; ++jj) {
                int k = DF + k4 * 4 + jj;
                float hv = hv4[jj];
#pragma unroll
                for (int j = 0; j < 16; ++j) t[j] = fmaf(hv, Wht1[k * HID + f0 + j], t[j]);
            }
        }
#pragma unroll
        for (int j = 0; j < 16; ++j) hh[lane * 65 + f0 + j] = silu_f(t[j]);
    }
    __syncthreads();
    if (n >= N) return;

    int c0 = w * 32;
    float o[32];
#pragma unroll
    for (int j = 0; j < 32; ++j) o[j] = bh2[c0 + j];
    for (int k = 0; k < HID; ++k) {
        float hv = hh[lane * 65 + k];
#pragma unroll
        for (int j = 0; j < 32; ++j) o[j] = fmaf(hv, Wht2[k * DF + c0 + j], o[j]);
    }
    float* oh = out + (size_t)n * DF + c0;
    const float* hrow = h + (size_t)n * DF + c0;
#pragma unroll
    for (int j4 = 0; j4 < 8; ++j4) {
        float4 hv = ((const float4*)hrow)[j4];
        float4 r;
        r.x = hv.x + o[4 * j4];
        r.y = hv.y + o[4 * j4 + 1];
        r.z = hv.z + o[4 * j4 + 2];
        r.w = hv.w + o[4 * j4 + 3];
        ((float4*)oh)[j4] = r;
    }
    if (w == 0) {
        float dv = (float)degI[n];
        float invd = 1.0f / fmaxf(dv, 1.0f);
        float* ox = out + (size_t)N * DF + (size_t)n * 3;
        ox[0] = x[n * 3 + 0] + agg_x[n * 3 + 0] * invd;
        ox[1] = x[n * 3 + 1] + agg_x[n * 3 + 1] * invd;
        ox[2] = x[n * 3 + 2] + agg_x[n * 3 + 2] * invd;
    }
}

extern "C" void kernel_launch(void* const* d_in, const int* in_sizes, int n_in,
                              void* d_out, int out_size, void* d_ws, size_t ws_size,
                              hipStream_t stream) {
    const float* h    = (const float*)d_in[0];
    const float* x    = (const float*)d_in[1];
    const int*   ei   = (const int*)d_in[2];
    const float* We1  = (const float*)d_in[3];
    const float* be1  = (const float*)d_in[4];
    const float* We2  = (const float*)d_in[5];
    const float* be2  = (const float*)d_in[6];
    const float* ln_g = (const float*)d_in[7];
    const float* ln_b = (const float*)d_in[8];
    const float* Wh1  = (const float*)d_in[9];
    const float* bh1  = (const float*)d_in[10];
    const float* Wh2  = (const float*)d_in[11];
    const float* bh2  = (const float*)d_in[12];
    const float* Wx   = (const float*)d_in[13];
    const float* bx   = (const float*)d_in[14];
    const float* Wg   = (const float*)d_in[15];
    const float* bg   = (const float*)d_in[16];

    const int E = in_sizes[2] / 2;
    const int N = in_sizes[0] / DF;
    const int* src = ei;
    const int* dst = ei + E;

    // ---- workspace carve (16B aligned regions) ----
    char* base = (char*)d_ws;
    size_t o = 0;
    auto carve = [&](size_t bytes) -> void* {
        void* r = base + o;
        o = (o + bytes + 15) & ~(size_t)15;
        return r;
    };
    const int nblk = (N + HB - 1) / HB;
    float* agg_h = (float*)carve((size_t)N * HID * 4);
    float* agg_x = (float*)carve((size_t)N * 3 * 4);
    float* Wt1   = (float*)carve(257 * 64 * 4);
    float* Wt2   = (float*)carve(64 * 64 * 4);
    float* Wht1  = (float*)carve(192 * 64 * 4);
    float* Wht2  = (float*)carve(64 * 128 * 4);
    unsigned short* WbfA = (unsigned short*)carve(4096 * 2);
    int*   cnt   = (int*)carve((size_t)N * 4);
    int*   off   = (int*)carve(((size_t)N + 1) * 4);
    int*   bsum  = (int*)carve(256 * 4);
    int*   lrank = (int*)carve((size_t)N * 4);
    int*   blockcnt = (int*)carve((size_t)nblk * 64 * 4);
    int*   nodeorder = (int*)carve((size_t)N * 4);
    float4* x4   = (float4*)carve((size_t)N * 16);
    int*   rank  = (int*)carve((size_t)E * 4);
    int*   csr_src = (int*)carve((size_t)E * 4);
    size_t need_full = o;

    // Ps/Pd live in d_out (N*128 <= out_size N*131); fully overwritten later.
    float* Ps = (float*)d_out;
    float* Pd = Ps + (size_t)N * HID;

    const int gE  = (E + 255) / 256;
    const int Nb  = (N + 1023) / 1024;
    const int gN64 = (N + 63) / 64;

    hipMemsetAsync(cnt, 0, (size_t)N * 4, stream);
    prep_weights<<<(45120 + 255) / 256, 256, 0, stream>>>(We1, We2, Wh1, Wh2,
                                                          Wt1, Wt2, Wht1, Wht2, WbfA);
    node_pre<<<gN64, 256, 0, stream>>>(h, Wt1, be1, x, Ps, Pd, x4, N);

    if (ws_size >= need_full) {
        // ---- CSR build + two-level degree counting sort ----
        count_kernel<<<gE, 256, 0, stream>>>(dst, cnt, rank, E);
        scan1<<<Nb, 1024, 0, stream>>>(cnt, off, bsum, N);
        scan3<<<(N + 256) / 256, 256, 0, stream>>>(off, bsum, Nb, N, E);
        scatter_src<<<gE, 256, 0, stream>>>(dst, src, rank, off, csr_src, E);
        hist_local<<<nblk, HB, 0, stream>>>(cnt, lrank, blockcnt, N);
        hist_scan<<<1, 64, 0, stream>>>(blockcnt, nblk);
        degscatter2<<<nblk, HB, 0, stream>>>(cnt, lrank, blockcnt, nodeorder, N);
        // ---- fused gather: quad-node MFMA batches ----
        const int quads = (N + 3) / 4;              // one wave per quad
        gather_kernel<<<(quads + 3) / 4, 256, 0, stream>>>(
            csr_src, off, nodeorder, x4, Ps, Pd, Wt1, WbfA, be2,
            ln_g, ln_b, Wx, bx, Wg, bg, agg_h, agg_x, N);
    } else {
        // ---- fallback: atomic aggregation ----
        hipMemsetAsync(agg_h, 0, (size_t)N * 67 * 4, stream);
        count_kernel<<<gE, 256, 0, stream>>>(dst, cnt, nullptr, E);
        edge_kernel_atomic<<<gE, 256, 0, stream>>>(src, dst, x, Ps, Pd, Wt1, Wt2,
                                                   be2, ln_g, ln_b, Wx, bx,
                                                   Wg, bg, agg_h, agg_x, E);
    }

    node_kernel<<<gN64, 256, 0, stream>>>(h, x, agg_h, agg_x, cnt,
                                          Wht1, Wht2, bh1, bh2, (float*)d_out, N);
}

// Round 15
// 236.410 us; speedup vs baseline: 1.6221x; 1.1957x over previous
//
#include <hip/hip_runtime.h>
#include <math.h>

#define HID 64
#define DF  128
#define HB  256   // hist block size

typedef __attribute__((ext_vector_type(8))) short short8v;   // 8 bf16
typedef __attribute__((ext_vector_type(4))) float float4v;

__device__ __forceinline__ float silu_f(float v) {
    return v * __builtin_amdgcn_rcpf(1.0f + __expf(-v));
}

__device__ __forceinline__ unsigned short f2bf(float f) {   // RNE f32->bf16
    unsigned u = __float_as_uint(f);
    u += 0x7FFFu + ((u >> 16) & 1u);
    return (unsigned short)(u >> 16);
}

// 4 simultaneous wave-wide sums: one 6-level tree, 4-way ILP per level
__device__ __forceinline__ void wredsum4(float& a, float& b, float& c, float& d) {
#pragma unroll
    for (int t = 1; t < 64; t <<= 1) {
        a += __shfl_xor(a, t, 64);
        b += __shfl_xor(b, t, 64);
        c += __shfl_xor(c, t, 64);
        d += __shfl_xor(d, t, 64);
    }
}

// ---------------------------------------------------------------------------
// Weight transposes + bf16 MFMA A-fragment pack of We2.
// ---------------------------------------------------------------------------
__global__ void prep_weights(const float* __restrict__ We1, const float* __restrict__ We2,
                             const float* __restrict__ Wh1, const float* __restrict__ Wh2,
                             float* __restrict__ Wt1, float* __restrict__ Wt2,
                             float* __restrict__ Wht1, float* __restrict__ Wht2,
                             unsigned short* __restrict__ WbfA) {
    int i = blockIdx.x * 256 + threadIdx.x;
    if (i < 257 * 64) {
        int k = i >> 6, f = i & 63;
        Wt1[i] = We1[f * 257 + k];
        return;
    }
    int j = i - 257 * 64;
    if (j < 64 * 64) {
        int k = j >> 6, f = j & 63;
        Wt2[j] = We2[f * 64 + k];
        return;
    }
    j -= 64 * 64;
    if (j < 192 * 64) {
        int k = j >> 6, f = j & 63;
        Wht1[j] = Wh1[f * 192 + k];
        return;
    }
    j -= 192 * 64;
    if (j < 64 * 128) {
        int f = j >> 7, c = j & 127;
        Wht2[j] = Wh2[c * 64 + f];
        return;
    }
    j -= 64 * 128;
    if (j < 4096) {
        int jj = j & 7, lane = (j >> 3) & 63, kc = (j >> 9) & 1, t = (j >> 10) & 3;
        int f = t * 16 + (lane & 15);
        int k = kc * 32 + ((lane >> 4) * 8) + jj;
        WbfA[j] = f2bf(We2[f * 64 + k]);
        return;
    }
}

// ---------------------------------------------------------------------------
// CSR build
// ---------------------------------------------------------------------------
__global__ __launch_bounds__(256) void count_kernel(const int* __restrict__ dst,
                                                    int* __restrict__ cnt,
                                                    int* __restrict__ rank, int E) {
    int e = blockIdx.x * 256 + threadIdx.x;
    if (e >= E) return;
    int r = atomicAdd(&cnt[dst[e]], 1);
    if (rank) rank[e] = r;
}

__global__ __launch_bounds__(1024) void scan1(const int* __restrict__ cnt,
                                              int* __restrict__ off,
                                              int* __restrict__ bsum, int N) {
    __shared__ int sm[1024];
    int tid = threadIdx.x;
    int i = blockIdx.x * 1024 + tid;
    int v = (i < N) ? cnt[i] : 0;
    sm[tid] = v;
    __syncthreads();
    for (int ofs = 1; ofs < 1024; ofs <<= 1) {
        int t = (tid >= ofs) ? sm[tid - ofs] : 0;
        __syncthreads();
        sm[tid] += t;
        __syncthreads();
    }
    if (i < N) off[i] = sm[tid] - v;
    if (tid == 1023) bsum[blockIdx.x] = sm[1023];
}

// scan3 with scan2 folded in: each block prefix-sums bsum (<=64 entries) itself
__global__ __launch_bounds__(256) void scan3(int* __restrict__ off,
                                             const int* __restrict__ bsum,
                                             int Nb, int N, int E) {
    __shared__ int pref[64];
    if (threadIdx.x == 0) {
        int s = 0;
        for (int b = 0; b < Nb; ++b) { pref[b] = s; s += bsum[b]; }
    }
    __syncthreads();
    int i = blockIdx.x * 256 + threadIdx.x;
    if (i > N) return;
    if (i == N) off[N] = E;
    else off[i] += pref[i >> 10];
}

__global__ __launch_bounds__(256) void scatter_src(const int* __restrict__ dst,
                                                   const int* __restrict__ srcI,
                                                   const int* __restrict__ rank,
                                                   const int* __restrict__ off,
                                                   int* __restrict__ csr_src, int E) {
    int e = blockIdx.x * 256 + threadIdx.x;
    if (e >= E) return;
    csr_src[off[dst[e]] + rank[e]] = srcI[e];
}

// ---------------------------------------------------------------------------
// Degree counting-sort, two-level, NO global atomics and NO serial scans
// (r13: 64-address atomic bomb 142us; r14: 1-wave serial scan ~40us):
//  1) hist_local: per-block LDS histogram; local rank from LDS atomic return
//  2) hist_tot: 1024 threads, 16-way-parallel bucket totals -> bucket bases
//  3) hist_scan2: 64 blocks (1 wave each), shfl_up wave-scan per bucket
//  4) degscatter2: pure scattered stores, DESCENDING degree (heavy first)
// ---------------------------------------------------------------------------
__global__ __launch_bounds__(HB) void hist_local(const int* __restrict__ cnt,
                                                 int* __restrict__ lrank,
                                                 int* __restrict__ blockcnt, int N) {
    __shared__ int lh[64];
    int tid = threadIdx.x;
    if (tid < 64) lh[tid] = 0;
    __syncthreads();
    int n = blockIdx.x * HB + tid;
    if (n < N) {
        int b = min(cnt[n], 63);
        lrank[n] = atomicAdd(&lh[b], 1);
    }
    __syncthreads();
    if (tid < 64) blockcnt[blockIdx.x * 64 + tid] = lh[tid];
}

__global__ __launch_bounds__(1024) void hist_tot(const int* __restrict__ blockcnt,
                                                 int* __restrict__ bucketbase, int nblk) {
    __shared__ int part[16][64];
    int b = threadIdx.x & 63, j = threadIdx.x >> 6;
    int s = 0;
    for (int k = j; k < nblk; k += 16) s += blockcnt[k * 64 + b];
    part[j][b] = s;
    __syncthreads();
    if (threadIdx.x < 64) {
        int t = 0;
#pragma unroll
        for (int jj = 1; jj < 16; ++jj) t += part[jj][threadIdx.x];
        part[0][threadIdx.x] += t;   // tot[b]
    }
    __syncthreads();
    if (threadIdx.x == 0) {
        int base = 0;
        for (int bb = 0; bb < 64; ++bb) {
            int t = part[0][bb];
            bucketbase[bb] = base;
            base += t;
        }
    }
}

__global__ __launch_bounds__(64) void hist_scan2(int* __restrict__ blockcnt,
                                                 const int* __restrict__ bucketbase,
                                                 int nblk) {
    int b = blockIdx.x;
    int lane = threadIdx.x;
    int carry = bucketbase[b];
    for (int chunk = 0; chunk * 64 < nblk; ++chunk) {
        int k = chunk * 64 + lane;
        int c = (k < nblk) ? blockcnt[k * 64 + b] : 0;
        int v = c;  // inclusive wave scan
#pragma unroll
        for (int ofs = 1; ofs < 64; ofs <<= 1) {
            int t = __shfl_up(v, ofs, 64);
            if (lane >= ofs) v += t;
        }
        if (k < nblk) blockcnt[k * 64 + b] = carry + v - c;  // exclusive + base
        carry += __shfl(v, 63, 64);
    }
}

__global__ __launch_bounds__(HB) void degscatter2(const int* __restrict__ cnt,
                                                  const int* __restrict__ lrank,
                                                  const int* __restrict__ blockcnt,
                                                  int* __restrict__ nodeorder, int N) {
    int n = blockIdx.x * HB + threadIdx.x;
    if (n >= N) return;
    int b = min(cnt[n], 63);
    int pos = blockcnt[(n / HB) * 64 + b] + lrank[n];
    nodeorder[N - 1 - pos] = n;   // descending degree: heavy quads scheduled first
}

// ---------------------------------------------------------------------------
// node_pre (wave-feature-split): be1 BAKED into Pd; also packs x -> float4.
// ---------------------------------------------------------------------------
__global__ __launch_bounds__(256) void node_pre(const float* __restrict__ h,
                                                const float* __restrict__ Wt1,
                                                const float* __restrict__ be1,
                                                const float* __restrict__ xin,
                                                float* __restrict__ Ps,
                                                float* __restrict__ Pd,
                                                float4* __restrict__ x4, int N) {
    int lane = threadIdx.x & 63;
    int w = __builtin_amdgcn_readfirstlane(threadIdx.x >> 6);
    int n = blockIdx.x * 64 + lane;
    if (n >= N) return;
    if (w == 0)
        x4[n] = make_float4(xin[3 * n], xin[3 * n + 1], xin[3 * n + 2], 0.f);
    int f0 = w * 16;
    float accS[16], accD[16];
#pragma unroll
    for (int j = 0; j < 16; ++j) { accS[j] = 0.f; accD[j] = be1[f0 + j]; }
    const float4* row = (const float4*)(h + (size_t)n * DF);
    for (int k4 = 0; k4 < DF / 4; ++k4) {
        float4 v = row[k4];
        float hv4[4] = {v.x, v.y, v.z, v.w};
#pragma unroll
        for (int jj = 0; jj < 4; ++jj) {
            int k = k4 * 4 + jj;
            float hv = hv4[jj];
#pragma unroll
            for (int j = 0; j < 16; ++j) {
                accS[j] = fmaf(hv, Wt1[k * HID + f0 + j], accS[j]);
                accD[j] = fmaf(hv, Wt1[(DF + k) * HID + f0 + j], accD[j]);
            }
        }
    }
    float4* ps = (float4*)(Ps + (size_t)n * HID + f0);
    float4* pd = (float4*)(Pd + (size_t)n * HID + f0);
#pragma unroll
    for (int j4 = 0; j4 < 4; ++j4) {
        ps[j4] = make_float4(accS[4 * j4], accS[4 * j4 + 1], accS[4 * j4 + 2], accS[4 * j4 + 3]);
        pd[j4] = make_float4(accD[4 * j4], accD[4 * j4 + 1], accD[4 * j4 + 2], accD[4 * j4 + 3]);
    }
}

// ---------------------------------------------------------------------------
// Gather v10: QUAD-NODE batches (unchanged from r14 — 91us, VGPR 112).
// NEVER pass a min-waves launch_bounds arg (r3/r11 spill cliffs).
// ---------------------------------------------------------------------------
__global__ __launch_bounds__(256) void gather_kernel(
    const int* __restrict__ csr_src, const int* __restrict__ off,
    const int* __restrict__ nodeorder, const float4* __restrict__ x4,
    const float* __restrict__ Ps, const float* __restrict__ Pd,
    const float* __restrict__ Wt1, const unsigned short* __restrict__ WbfA,
    const float* __restrict__ be2,
    const float* __restrict__ ln_g, const float* __restrict__ ln_b,
    const float* __restrict__ Wx, const float* __restrict__ bx,
    const float* __restrict__ Wg, const float* __restrict__ bg,
    float* __restrict__ agg_h, float* __restrict__ agg_x, int N) {
    const int lane = threadIdx.x & 63;
    const int wid = blockIdx.x * 4 + (threadIdx.x >> 6);
    const int e16 = lane & 15;
    const int hg = lane >> 4;
    const int k0 = hg * 8;
    const int p = e16 & 3;                 // edge position within node
    if (wid * 4 >= N) return;
    const int slot = wid * 4 + (e16 >> 2); // this lane's node slot

    // resident A fragments (We2 bf16)
    short8v a[4][2];
#pragma unroll
    for (int t = 0; t < 4; ++t)
#pragma unroll
        for (int kc = 0; kc < 2; ++kc)
            a[t][kc] = *(const short8v*)&WbfA[(((t * 2 + kc) * 64) + lane) * 8];

    // z-side per-lane k-chunk constants
    const float* colW = Wt1 + 256 * HID;
    float colWk[16];
#pragma unroll
    for (int j = 0; j < 8; ++j) {
        colWk[j] = colW[k0 + j];
        colWk[8 + j] = colW[k0 + 32 + j];
    }
    // m-side per-lane params: be2, g*Wg, g*Wx (ln affine reloaded in epilogue)
    float be2r[16], cgr[16], cxr[16];
#pragma unroll
    for (int t = 0; t < 4; ++t)
#pragma unroll
        for (int r = 0; r < 4; ++r) {
            int f = t * 16 + hg * 4 + r;
            float g = ln_g[f];
            be2r[4 * t + r] = be2[f];
            cgr[4 * t + r] = g * Wg[f];
            cxr[4 * t + r] = g * Wx[f];
        }
    const float bgs = bg[0], bxs = bx[0];

    // wave-uniform loop invariants (feature=lane view)
    float Cg = ln_g[lane] * Wg[lane], Cx = ln_g[lane] * Wx[lane];
    float Cbg = ln_b[lane] * Wg[lane], Cbx = ln_b[lane] * Wx[lane];
    wredsum4(Cg, Cx, Cbg, Cbx);
    const float g0 = (lane < 16) ? 1.0f : 0.0f;

    // per-lane node state (fixed for the wave's lifetime)
    const int nj = (slot < N) ? nodeorder[slot] : -1;
    int beg = 0, end = 0;
    if (nj >= 0) { beg = off[nj]; end = off[nj + 1]; }
    const float4 xdv = (nj >= 0) ? x4[nj] : make_float4(0.f, 0.f, 0.f, 0.f);
    float baseK[16];
    {
        const float4v* pd4 = (const float4v*)(Pd + (size_t)max(nj, 0) * HID + k0);
        float4v p0 = pd4[0], p1 = pd4[1], p2 = pd4[8], p3 = pd4[9];
#pragma unroll
        for (int j = 0; j < 4; ++j) {
            baseK[j] = p0[j];
            baseK[4 + j] = p1[j];
            baseK[8 + j] = p2[j];
            baseK[12 + j] = p3[j];
        }
    }

    // batches = wave-max of per-node ceil(deg/4)
    int nb = (end - beg + 3) >> 2;
#pragma unroll
    for (int mk = 1; mk < 64; mk <<= 1) nb = max(nb, __shfl_xor(nb, mk, 64));
    nb = __builtin_amdgcn_readfirstlane(nb);

    float4v acc[4];
#pragma unroll
    for (int t = 0; t < 4; ++t) acc[t] = (float4v){0.f, 0.f, 0.f, 0.f};
    float ax0 = 0.f, ax1 = 0.f, ax2 = 0.f, Sa = 0.f, Smu = 0.f;

    for (int b = 0; b < nb; ++b) {
        int idx = beg + b * 4 + p;
        float validf = (idx < end) ? 1.0f : 0.0f;
        int ic = (idx < end) ? idx : (end > 0 ? end - 1 : 0);
        int s = csr_src[ic];
        float4 xs = x4[s];
        const float4v* ps4 = (const float4v*)(Ps + (size_t)s * HID + k0);
        float4v q0 = ps4[0], q1 = ps4[1], q2 = ps4[8], q3 = ps4[9];

        float r0 = xs.x - xdv.x, r1 = xs.y - xdv.y, r2 = xs.z - xdv.z;
        float dsq = r0 * r0 + r1 * r1 + r2 * r2;
        float inv = __builtin_amdgcn_rcpf(__builtin_amdgcn_sqrtf(dsq) + 1e-8f);

        short8v b0, b1;
#pragma unroll
        for (int j = 0; j < 4; ++j) {
            float z0 = q0[j] + baseK[j] + dsq * colWk[j];
            float z1 = q1[j] + baseK[4 + j] + dsq * colWk[4 + j];
            float z2 = q2[j] + baseK[8 + j] + dsq * colWk[8 + j];
            float z3 = q3[j] + baseK[12 + j] + dsq * colWk[12 + j];
            b0[j]     = (short)f2bf(silu_f(z0));
            b0[4 + j] = (short)f2bf(silu_f(z1));
            b1[j]     = (short)f2bf(silu_f(z2));
            b1[4 + j] = (short)f2bf(silu_f(z3));
        }

        float ms[16];
        float S1 = 0.f, S2 = 0.f, Sg = 0.f, Sx = 0.f;
#pragma unroll
        for (int t = 0; t < 4; ++t) {
            float4v c = (float4v){be2r[4 * t], be2r[4 * t + 1],
                                  be2r[4 * t + 2], be2r[4 * t + 3]};
            c = __builtin_amdgcn_mfma_f32_16x16x32_bf16(a[t][0], b0, c, 0, 0, 0);
            c = __builtin_amdgcn_mfma_f32_16x16x32_bf16(a[t][1], b1, c, 0, 0, 0);
#pragma unroll
            for (int r = 0; r < 4; ++r) {
                float v = c[r] * __builtin_amdgcn_rcpf(1.0f + __expf(-c[r]));
                ms[4 * t + r] = v;
                S1 += v;
                S2 = fmaf(v, v, S2);
                Sg = fmaf(v, cgr[4 * t + r], Sg);
                Sx = fmaf(v, cxr[4 * t + r], Sx);
            }
        }
        // per-edge sums across the 4 row-groups (columns preserved)
#pragma unroll
        for (int mk = 16; mk < 64; mk <<= 1) {
            S1 += __shfl_xor(S1, mk, 64);
            S2 += __shfl_xor(S2, mk, 64);
            Sg += __shfl_xor(Sg, mk, 64);
            Sx += __shfl_xor(Sx, mk, 64);
        }

        float mu = S1 * (1.0f / HID);
        float var = S2 * (1.0f / HID) - mu * mu;
        float rstd = __builtin_amdgcn_rsqf(var + 1e-5f);
        float dg = fmaf(rstd, Sg - mu * Cg, Cbg);
        float dx = fmaf(rstd, Sx - mu * Cx, Cbx);
        float alpha = __builtin_amdgcn_rcpf(1.0f + __expf(-(dg + bgs))) * validf;
        float ta = __expf(2.0f * fmaf(alpha, dx, bxs));
        float cwv = 1.0f - 2.0f * __builtin_amdgcn_rcpf(ta + 1.0f);

        float u = rstd * alpha;
        Sa += alpha;
        Smu = fmaf(u, mu, Smu);
#pragma unroll
        for (int t = 0; t < 4; ++t) {
            float4v av = acc[t];
#pragma unroll
            for (int r = 0; r < 4; ++r) av[r] = fmaf(u, ms[4 * t + r], av[r]);
            acc[t] = av;
        }
        float rc = inv * cwv * validf * g0;
        ax0 = fmaf(r0, rc, ax0);
        ax1 = fmaf(r1, rc, ax1);
        ax2 = fmaf(r2, rc, ax2);
    }

    // ---- epilogue: reduce over each node's 4 columns (xor 1,2) ----
#pragma unroll
    for (int t = 0; t < 4; ++t) {
        float4v av = acc[t];
#pragma unroll
        for (int r = 0; r < 4; ++r) {
            float v = av[r];
            v += __shfl_xor(v, 1, 64);
            v += __shfl_xor(v, 2, 64);
            av[r] = v;
        }
        acc[t] = av;
    }
    Sa  += __shfl_xor(Sa, 1, 64);  Sa  += __shfl_xor(Sa, 2, 64);
    Smu += __shfl_xor(Smu, 1, 64); Smu += __shfl_xor(Smu, 2, 64);
    ax0 += __shfl_xor(ax0, 1, 64); ax0 += __shfl_xor(ax0, 2, 64);
    ax1 += __shfl_xor(ax1, 1, 64); ax1 += __shfl_xor(ax1, 2, 64);
    ax2 += __shfl_xor(ax2, 1, 64); ax2 += __shfl_xor(ax2, 2, 64);

    if (p == 0 && nj >= 0) {
        float* dstp = agg_h + (size_t)nj * HID + hg * 4;
#pragma unroll
        for (int t = 0; t < 4; ++t) {
            int f = t * 16 + hg * 4;
            float4 o;
            o.x = fmaf(ln_g[f + 0], acc[t][0] - Smu, ln_b[f + 0] * Sa);
            o.y = fmaf(ln_g[f + 1], acc[t][1] - Smu, ln_b[f + 1] * Sa);
            o.z = fmaf(ln_g[f + 2], acc[t][2] - Smu, ln_b[f + 2] * Sa);
            o.w = fmaf(ln_g[f + 3], acc[t][3] - Smu, ln_b[f + 3] * Sa);
            *(float4*)(dstp + t * 16) = o;
        }
        if (hg == 0) {
            agg_x[nj * 3 + 0] = ax0;
            agg_x[nj * 3 + 1] = ax1;
            agg_x[nj * 3 + 2] = ax2;
        }
    }
}

// ---------------------------------------------------------------------------
// Fallback edge kernel (atomic aggregation) — only if ws too small for CSR.
// (Pd includes be1.)
// ---------------------------------------------------------------------------
__global__ __launch_bounds__(256) void edge_kernel_atomic(
    const int* __restrict__ src, const int* __restrict__ dst,
    const float* __restrict__ x,
    const float* __restrict__ Ps, const float* __restrict__ Pd,
    const float* __restrict__ Wt1, const float* __restrict__ Wt2,
    const float* __restrict__ be2,
    const float* __restrict__ ln_g, const float* __restrict__ ln_b,
    const float* __restrict__ Wx, const float* __restrict__ bx,
    const float* __restrict__ Wg, const float* __restrict__ bg,
    float* __restrict__ agg_h, float* __restrict__ agg_x, int E) {
    int e = blockIdx.x * 256 + threadIdx.x;
    if (e >= E) return;
    int s = src[e], d = dst[e];
    float r0 = x[s * 3] - x[d * 3], r1 = x[s * 3 + 1] - x[d * 3 + 1], r2 = x[s * 3 + 2] - x[d * 3 + 2];
    float dsq = r0 * r0 + r1 * r1 + r2 * r2;
    float inv = 1.0f / (sqrtf(dsq) + 1e-8f);
    float rn0 = r0 * inv, rn1 = r1 * inv, rn2 = r2 * inv;
    float z[HID];
    const float4* ps = (const float4*)(Ps + (size_t)s * HID);
    const float4* pd = (const float4*)(Pd + (size_t)d * HID);
    const float* colW = Wt1 + 256 * HID;
#pragma unroll
    for (int f4 = 0; f4 < HID / 4; ++f4) {
        float4 aa = ps[f4];
        float4 b = pd[f4];
        float av[4] = {aa.x, aa.y, aa.z, aa.w};
        float bv[4] = {b.x, b.y, b.z, b.w};
#pragma unroll
        for (int j = 0; j < 4; ++j) {
            int f = 4 * f4 + j;
            z[f] = silu_f(av[j] + bv[j] + dsq * colW[f]);
        }
    }
    float m[HID];
#pragma unroll
    for (int f = 0; f < HID; ++f) m[f] = be2[f];
#pragma unroll
    for (int k = 0; k < HID; ++k) {
        float zv = z[k];
#pragma unroll
        for (int f = 0; f < HID; ++f) m[f] = fmaf(zv, Wt2[k * HID + f], m[f]);
    }
#pragma unroll
    for (int f = 0; f < HID; ++f) m[f] = silu_f(m[f]);
    float mu = 0.f;
#pragma unroll
    for (int f = 0; f < HID; ++f) mu += m[f];
    mu *= (1.0f / HID);
    float var = 0.f;
#pragma unroll
    for (int f = 0; f < HID; ++f) {
        float t = m[f] - mu;
        var = fmaf(t, t, var);
    }
    var *= (1.0f / HID);
    float rstd = 1.0f / sqrtf(var + 1e-5f);
#pragma unroll
    for (int f = 0; f < HID; ++f) m[f] = (m[f] - mu) * rstd * ln_g[f] + ln_b[f];
    float dotg = 0.f, dotx = 0.f;
#pragma unroll
    for (int f = 0; f < HID; ++f) {
        dotg = fmaf(m[f], Wg[f], dotg);
        dotx = fmaf(m[f], Wx[f], dotx);
    }
    float alpha = 1.0f / (1.0f + __expf(-(dotg + bg[0])));
    float ta = __expf(2.0f * fmaf(alpha, dotx, bx[0]));
    float cw = 1.0f - 2.0f / (ta + 1.0f);
    float* ah = agg_h + (size_t)d * HID;
#pragma unroll
    for (int f = 0; f < HID; ++f) atomicAdd(&ah[f], m[f] * alpha);
    atomicAdd(&agg_x[d * 3 + 0], rn0 * cw);
    atomicAdd(&agg_x[d * 3 + 1], rn1 * cw);
    atomicAdd(&agg_x[d * 3 + 2], rn2 * cw);
}

// ---------------------------------------------------------------------------
// node_kernel (wave-feature-split, LDS hh exchange)
// ---------------------------------------------------------------------------
__global__ __launch_bounds__(256) void node_kernel(
    const float* __restrict__ h, const float* __restrict__ x,
    const float* __restrict__ agg_h, const float* __restrict__ agg_x,
    const int* __restrict__ degI,
    const float* __restrict__ Wht1, const float* __restrict__ Wht2,
    const float* __restrict__ bh1, const float* __restrict__ bh2,
    float* __restrict__ out, int N) {
    __shared__ float hh[64 * 65];
    int lane = threadIdx.x & 63;
    int w = __builtin_amdgcn_readfirstlane(threadIdx.x >> 6);
    int n = blockIdx.x * 64 + lane;

    if (n < N) {
        int f0 = w * 16;
        float t[16];
#pragma unroll
        for (int j = 0; j < 16; ++j) t[j] = bh1[f0 + j];
        const float4* rowH = (const float4*)(h + (size_t)n * DF);
        for (int k4 = 0; k4 < DF / 4; ++k4) {
            float4 v = rowH[k4];
            float hv4[4] = {v.x, v.y, v.z, v.w};
#pragma unroll
            for (int jj = 0; jj < 4; ++jj) {
                int k = k4 * 4 + jj;
                float hv = hv4[jj];
#pragma unroll
                for (int j = 0; j < 16; ++j) t[j] = fmaf(hv, Wht1[k * HID + f0 + j], t[j]);
            }
        }
        const float4* rowA = (const float4*)(agg_h + (size_t)n * HID);
        for (int k4 = 0; k4 < HID / 4; ++k4) {
            float4 v = rowA[k4];
            float hv4[4] = {v.x, v.y, v.z, v.w};
#pragma unroll
            for (int jj = 0; jj < 4; ++jj) {
                int k = DF + k4 * 4 + jj;
                float hv = hv4[jj];
#pragma unroll
                for (int j = 0; j < 16; ++j) t[j] = fmaf(hv, Wht1[k * HID + f0 + j], t[j]);
            }
        }
#pragma unroll
        for (int j = 0; j < 16; ++j) hh[lane * 65 + f0 + j] = silu_f(t[j]);
    }
    __syncthreads();
    if (n >= N) return;

    int c0 = w * 32;
    float o[32];
#pragma unroll
    for (int j = 0; j < 32; ++j) o[j] = bh2[c0 + j];
    for (int k = 0; k < HID; ++k) {
        float hv = hh[lane * 65 + k];
#pragma unroll
        for (int j = 0; j < 32; ++j) o[j] = fmaf(hv, Wht2[k * DF + c0 + j], o[j]);
    }
    float* oh = out + (size_t)n * DF + c0;
    const float* hrow = h + (size_t)n * DF + c0;
#pragma unroll
    for (int j4 = 0; j4 < 8; ++j4) {
        float4 hv = ((const float4*)hrow)[j4];
        float4 r;
        r.x = hv.x + o[4 * j4];
        r.y = hv.y + o[4 * j4 + 1];
        r.z = hv.z + o[4 * j4 + 2];
        r.w = hv.w + o[4 * j4 + 3];
        ((float4*)oh)[j4] = r;
    }
    if (w == 0) {
        float dv = (float)degI[n];
        float invd = 1.0f / fmaxf(dv, 1.0f);
        float* ox = out + (size_t)N * DF + (size_t)n * 3;
        ox[0] = x[n * 3 + 0] + agg_x[n * 3 + 0] * invd;
        ox[1] = x[n * 3 + 1] + agg_x[n * 3 + 1] * invd;
        ox[2] = x[n * 3 + 2] + agg_x[n * 3 + 2] * invd;
    }
}

extern "C" void kernel_launch(void* const* d_in, const int* in_sizes, int n_in,
                              void* d_out, int out_size, void* d_ws, size_t ws_size,
                              hipStream_t stream) {
    const float* h    = (const float*)d_in[0];
    const float* x    = (const float*)d_in[1];
    const int*   ei   = (const int*)d_in[2];
    const float* We1  = (const float*)d_in[3];
    const float* be1  = (const float*)d_in[4];
    const float* We2  = (const float*)d_in[5];
    const float* be2  = (const float*)d_in[6];
    const float* ln_g = (const float*)d_in[7];
    const float* ln_b = (const float*)d_in[8];
    const float* Wh1  = (const float*)d_in[9];
    const float* bh1  = (const float*)d_in[10];
    const float* Wh2  = (const float*)d_in[11];
    const float* bh2  = (const float*)d_in[12];
    const float* Wx   = (const float*)d_in[13];
    const float* bx   = (const float*)d_in[14];
    const float* Wg   = (const float*)d_in[15];
    const float* bg   = (const float*)d_in[16];

    const int E = in_sizes[2] / 2;
    const int N = in_sizes[0] / DF;
    const int* src = ei;
    const int* dst = ei + E;

    // ---- workspace carve (16B aligned regions) ----
    char* base = (char*)d_ws;
    size_t o = 0;
    auto carve = [&](size_t bytes) -> void* {
        void* r = base + o;
        o = (o + bytes + 15) & ~(size_t)15;
        return r;
    };
    const int nblk = (N + HB - 1) / HB;
    float* agg_h = (float*)carve((size_t)N * HID * 4);
    float* agg_x = (float*)carve((size_t)N * 3 * 4);
    float* Wt1   = (float*)carve(257 * 64 * 4);
    float* Wt2   = (float*)carve(64 * 64 * 4);
    float* Wht1  = (float*)carve(192 * 64 * 4);
    float* Wht2  = (float*)carve(64 * 128 * 4);
    unsigned short* WbfA = (unsigned short*)carve(4096 * 2);
    int*   cnt   = (int*)carve((size_t)N * 4);
    int*   off   = (int*)carve(((size_t)N + 1) * 4);
    int*   bsum  = (int*)carve(256 * 4);
    int*   lrank = (int*)carve((size_t)N * 4);
    int*   blockcnt = (int*)carve((size_t)nblk * 64 * 4);
    int*   bucketbase = (int*)carve(64 * 4);
    int*   nodeorder = (int*)carve((size_t)N * 4);
    float4* x4   = (float4*)carve((size_t)N * 16);
    int*   rank  = (int*)carve((size_t)E * 4);
    int*   csr_src = (int*)carve((size_t)E * 4);
    size_t need_full = o;

    // Ps/Pd live in d_out (N*128 <= out_size N*131); fully overwritten later.
    float* Ps = (float*)d_out;
    float* Pd = Ps + (size_t)N * HID;

    const int gE  = (E + 255) / 256;
    const int Nb  = (N + 1023) / 1024;
    const int gN64 = (N + 63) / 64;

    hipMemsetAsync(cnt, 0, (size_t)N * 4, stream);
    prep_weights<<<(45120 + 255) / 256, 256, 0, stream>>>(We1, We2, Wh1, Wh2,
                                                          Wt1, Wt2, Wht1, Wht2, WbfA);
    node_pre<<<gN64, 256, 0, stream>>>(h, Wt1, be1, x, Ps, Pd, x4, N);

    if (ws_size >= need_full) {
        // ---- CSR build + parallel two-level degree counting sort ----
        count_kernel<<<gE, 256, 0, stream>>>(dst, cnt, rank, E);
        scan1<<<Nb, 1024, 0, stream>>>(cnt, off, bsum, N);
        scan3<<<(N + 256) / 256, 256, 0, stream>>>(off, bsum, Nb, N, E);
        scatter_src<<<gE, 256, 0, stream>>>(dst, src, rank, off, csr_src, E);
        hist_local<<<nblk, HB, 0, stream>>>(cnt, lrank, blockcnt, N);
        hist_tot<<<1, 1024, 0, stream>>>(blockcnt, bucketbase, nblk);
        hist_scan2<<<64, 64, 0, stream>>>(blockcnt, bucketbase, nblk);
        degscatter2<<<nblk, HB, 0, stream>>>(cnt, lrank, blockcnt, nodeorder, N);
        // ---- fused gather: quad-node MFMA batches ----
        const int quads = (N + 3) / 4;              // one wave per quad
        gather_kernel<<<(quads + 3) / 4, 256, 0, stream>>>(
            csr_src, off, nodeorder, x4, Ps, Pd, Wt1, WbfA, be2,
            ln_g, ln_b, Wx, bx, Wg, bg, agg_h, agg_x, N);
    } else {
        // ---- fallback: atomic aggregation ----
        hipMemsetAsync(agg_h, 0, (size_t)N * 67 * 4, stream);
        count_kernel<<<gE, 256, 0, stream>>>(dst, cnt, nullptr, E);
        edge_kernel_atomic<<<gE, 256, 0, stream>>>(src, dst, x, Ps, Pd, Wt1, Wt2,
                                                   be2, ln_g, ln_b, Wx, bx,
                                                   Wg, bg, agg_h, agg_x, E);
    }

    node_kernel<<<gN64, 256, 0, stream>>>(h, x, agg_h, agg_x, cnt,
                                          Wht1, Wht2, bh1, bh2, (float*)d_out, N);
}

// Round 16
// 197.930 us; speedup vs baseline: 1.9374x; 1.1944x over previous
//
#include <hip/hip_runtime.h>
#include <math.h>

#define HID 64
#define DF  128
#define HB  256   // hist block size

typedef __attribute__((ext_vector_type(8))) short short8v;   // 8 bf16
typedef __attribute__((ext_vector_type(4))) float float4v;

__device__ __forceinline__ float silu_f(float v) {
    return v * __builtin_amdgcn_rcpf(1.0f + __expf(-v));
}

__device__ __forceinline__ unsigned short f2bf(float f) {   // RNE f32->bf16
    unsigned u = __float_as_uint(f);
    u += 0x7FFFu + ((u >> 16) & 1u);
    return (unsigned short)(u >> 16);
}

__device__ __forceinline__ short8v pack_bf16(float4 a, float4 b) {
    short8v r;
    r[0] = (short)f2bf(a.x); r[1] = (short)f2bf(a.y);
    r[2] = (short)f2bf(a.z); r[3] = (short)f2bf(a.w);
    r[4] = (short)f2bf(b.x); r[5] = (short)f2bf(b.y);
    r[6] = (short)f2bf(b.z); r[7] = (short)f2bf(b.w);
    return r;
}

// 4 simultaneous wave-wide sums
__device__ __forceinline__ void wredsum4(float& a, float& b, float& c, float& d) {
#pragma unroll
    for (int t = 1; t < 64; t <<= 1) {
        a += __shfl_xor(a, t, 64);
        b += __shfl_xor(b, t, 64);
        c += __shfl_xor(c, t, 64);
        d += __shfl_xor(d, t, 64);
    }
}

// ---------------------------------------------------------------------------
// Weight prep: Wt1/Wt2 transposes (gather colW + fallback), plus bf16 MFMA
// B-operand packs. Fragment layouts match the verified gather layouts:
//   A/B: k = (lane>>4)*8 + j ; A row / B col = lane&15 ; D col=lane&15,
//   row=(lane>>4)*4+reg.
//  WbfA : We2 A-frags for gather              (4096 sh)
//  WpB1 : [Ps|Pd] B-frags, 8 ftiles x 4 kc    (16384 sh)  f<64:We1[f][k] else We1[f-64][128+k]
//  WpH1 : Wh1 B-frags, 4 ftiles x 6 kc        (12288 sh)
//  WpH2 : Wh2 B-frags, 8 ftiles x 2 kc        (8192 sh)
// ---------------------------------------------------------------------------
__global__ void prep_weights(const float* __restrict__ We1, const float* __restrict__ We2,
                             const float* __restrict__ Wh1, const float* __restrict__ Wh2,
                             float* __restrict__ Wt1, float* __restrict__ Wt2,
                             unsigned short* __restrict__ WbfA,
                             unsigned short* __restrict__ WpB1,
                             unsigned short* __restrict__ WpH1,
                             unsigned short* __restrict__ WpH2) {
    int i = blockIdx.x * 256 + threadIdx.x;
    if (i < 257 * 64) {
        int k = i >> 6, f = i & 63;
        Wt1[i] = We1[f * 257 + k];
        return;
    }
    int j = i - 257 * 64;
    if (j < 64 * 64) {
        int k = j >> 6, f = j & 63;
        Wt2[j] = We2[f * 64 + k];
        return;
    }
    j -= 64 * 64;
    if (j < 4096) {
        int jj = j & 7, lane = (j >> 3) & 63, kc = (j >> 9) & 1, t = (j >> 10) & 3;
        int f = t * 16 + (lane & 15);
        int k = kc * 32 + ((lane >> 4) * 8) + jj;
        WbfA[j] = f2bf(We2[f * 64 + k]);
        return;
    }
    j -= 4096;
    if (j < 16384) {
        int jj = j & 7, lane = (j >> 3) & 63, kc = (j >> 9) & 3, ft = j >> 11;
        int f = ft * 16 + (lane & 15);
        int k = kc * 32 + ((lane >> 4) * 8) + jj;
        float v = (f < 64) ? We1[f * 257 + k] : We1[(f - 64) * 257 + 128 + k];
        WpB1[j] = f2bf(v);
        return;
    }
    j -= 16384;
    if (j < 12288) {
        int jj = j & 7, lane = (j >> 3) & 63, idx = j >> 9;
        int kc = idx % 6, ft = idx / 6;
        int f = ft * 16 + (lane & 15);
        int k = kc * 32 + ((lane >> 4) * 8) + jj;
        WpH1[j] = f2bf(Wh1[f * 192 + k]);
        return;
    }
    j -= 12288;
    if (j < 8192) {
        int jj = j & 7, lane = (j >> 3) & 63, idx = j >> 9;
        int kc = idx & 1, ft = idx >> 1;
        int c = ft * 16 + (lane & 15);
        int k = kc * 32 + ((lane >> 4) * 8) + jj;
        WpH2[j] = f2bf(Wh2[c * 64 + k]);
        return;
    }
}

// ---------------------------------------------------------------------------
// CSR build
// ---------------------------------------------------------------------------
__global__ __launch_bounds__(256) void count_kernel(const int* __restrict__ dst,
                                                    int* __restrict__ cnt,
                                                    int* __restrict__ rank, int E) {
    int e = blockIdx.x * 256 + threadIdx.x;
    if (e >= E) return;
    int r = atomicAdd(&cnt[dst[e]], 1);
    if (rank) rank[e] = r;
}

__global__ __launch_bounds__(1024) void scan1(const int* __restrict__ cnt,
                                              int* __restrict__ off,
                                              int* __restrict__ bsum, int N) {
    __shared__ int sm[1024];
    int tid = threadIdx.x;
    int i = blockIdx.x * 1024 + tid;
    int v = (i < N) ? cnt[i] : 0;
    sm[tid] = v;
    __syncthreads();
    for (int ofs = 1; ofs < 1024; ofs <<= 1) {
        int t = (tid >= ofs) ? sm[tid - ofs] : 0;
        __syncthreads();
        sm[tid] += t;
        __syncthreads();
    }
    if (i < N) off[i] = sm[tid] - v;
    if (tid == 1023) bsum[blockIdx.x] = sm[1023];
}

__global__ __launch_bounds__(256) void scan3(int* __restrict__ off,
                                             const int* __restrict__ bsum,
                                             int Nb, int N, int E) {
    __shared__ int pref[64];
    if (threadIdx.x == 0) {
        int s = 0;
        for (int b = 0; b < Nb; ++b) { pref[b] = s; s += bsum[b]; }
    }
    __syncthreads();
    int i = blockIdx.x * 256 + threadIdx.x;
    if (i > N) return;
    if (i == N) off[N] = E;
    else off[i] += pref[i >> 10];
}

__global__ __launch_bounds__(256) void scatter_src(const int* __restrict__ dst,
                                                   const int* __restrict__ srcI,
                                                   const int* __restrict__ rank,
                                                   const int* __restrict__ off,
                                                   int* __restrict__ csr_src, int E) {
    int e = blockIdx.x * 256 + threadIdx.x;
    if (e >= E) return;
    csr_src[off[dst[e]] + rank[e]] = srcI[e];
}

// ---------------------------------------------------------------------------
// Degree counting-sort, two-level, no global atomics, no serial scans.
// ---------------------------------------------------------------------------
__global__ __launch_bounds__(HB) void hist_local(const int* __restrict__ cnt,
                                                 int* __restrict__ lrank,
                                                 int* __restrict__ blockcnt, int N) {
    __shared__ int lh[64];
    int tid = threadIdx.x;
    if (tid < 64) lh[tid] = 0;
    __syncthreads();
    int n = blockIdx.x * HB + tid;
    if (n < N) {
        int b = min(cnt[n], 63);
        lrank[n] = atomicAdd(&lh[b], 1);
    }
    __syncthreads();
    if (tid < 64) blockcnt[blockIdx.x * 64 + tid] = lh[tid];
}

__global__ __launch_bounds__(1024) void hist_tot(const int* __restrict__ blockcnt,
                                                 int* __restrict__ bucketbase, int nblk) {
    __shared__ int part[16][64];
    int b = threadIdx.x & 63, j = threadIdx.x >> 6;
    int s = 0;
    for (int k = j; k < nblk; k += 16) s += blockcnt[k * 64 + b];
    part[j][b] = s;
    __syncthreads();
    if (threadIdx.x < 64) {
        int t = 0;
#pragma unroll
        for (int jj = 1; jj < 16; ++jj) t += part[jj][threadIdx.x];
        part[0][threadIdx.x] += t;
    }
    __syncthreads();
    if (threadIdx.x == 0) {
        int base = 0;
        for (int bb = 0; bb < 64; ++bb) {
            int t = part[0][bb];
            bucketbase[bb] = base;
            base += t;
        }
    }
}

__global__ __launch_bounds__(64) void hist_scan2(int* __restrict__ blockcnt,
                                                 const int* __restrict__ bucketbase,
                                                 int nblk) {
    int b = blockIdx.x;
    int lane = threadIdx.x;
    int carry = bucketbase[b];
    for (int chunk = 0; chunk * 64 < nblk; ++chunk) {
        int k = chunk * 64 + lane;
        int c = (k < nblk) ? blockcnt[k * 64 + b] : 0;
        int v = c;
#pragma unroll
        for (int ofs = 1; ofs < 64; ofs <<= 1) {
            int t = __shfl_up(v, ofs, 64);
            if (lane >= ofs) v += t;
        }
        if (k < nblk) blockcnt[k * 64 + b] = carry + v - c;
        carry += __shfl(v, 63, 64);
    }
}

__global__ __launch_bounds__(HB) void degscatter2(const int* __restrict__ cnt,
                                                  const int* __restrict__ lrank,
                                                  const int* __restrict__ blockcnt,
                                                  int* __restrict__ nodeorder, int N) {
    int n = blockIdx.x * HB + threadIdx.x;
    if (n >= N) return;
    int b = min(cnt[n], 63);
    int pos = blockcnt[(n / HB) * 64 + b] + lrank[n];
    nodeorder[N - 1 - pos] = n;   // descending degree
}

// ---------------------------------------------------------------------------
// node_pre (MFMA): one wave per 16-node tile. Ps|Pd = h @ [Wsrc|Wdst]^T
// (be1 baked into Pd). Also packs x -> float4.
// ---------------------------------------------------------------------------
__global__ __launch_bounds__(256) void node_pre(
    const float* __restrict__ h, const unsigned short* __restrict__ WpB1,
    const float* __restrict__ be1, const float* __restrict__ xin,
    float* __restrict__ Ps, float* __restrict__ Pd,
    float4* __restrict__ x4, int N) {
    const int lane = threadIdx.x & 63;
    const int wslot = threadIdx.x >> 6;
    {
        int n = blockIdx.x * 64 + threadIdx.x;
        if (threadIdx.x < 64 && n < N)
            x4[n] = make_float4(xin[3 * n], xin[3 * n + 1], xin[3 * n + 2], 0.f);
    }
    const int tile = (blockIdx.x * 4 + wslot) * 16;
    if (tile >= N) return;
    const int r15 = lane & 15, kg = lane >> 4;
    const int arow = min(tile + r15, N - 1);
    const float* hr = h + (size_t)arow * DF + kg * 8;
    short8v A[4];
#pragma unroll
    for (int kc = 0; kc < 4; ++kc) {
        float4 q0 = *(const float4*)(hr + kc * 32);
        float4 q1 = *(const float4*)(hr + kc * 32 + 4);
        A[kc] = pack_bf16(q0, q1);
    }
#pragma unroll
    for (int ft = 0; ft < 8; ++ft) {
        float4v c = (float4v){0.f, 0.f, 0.f, 0.f};
#pragma unroll
        for (int kc = 0; kc < 4; ++kc) {
            short8v B = *(const short8v*)&WpB1[(((ft * 4 + kc) * 64) + lane) * 8];
            c = __builtin_amdgcn_mfma_f32_16x16x32_bf16(A[kc], B, c, 0, 0, 0);
        }
        int f = ft * 16 + r15;
        float bias = (f >= 64) ? be1[f - 64] : 0.f;
#pragma unroll
        for (int r = 0; r < 4; ++r) {
            int n = tile + kg * 4 + r;
            if (n < N) {
                float v = c[r] + bias;
                if (f < 64) Ps[(size_t)n * 64 + f] = v;
                else        Pd[(size_t)n * 64 + (f - 64)] = v;
            }
        }
    }
}

// ---------------------------------------------------------------------------
// Gather v10 (unchanged from r15: 85us, VGPR 112). Quad-node MFMA batches.
// NEVER pass a min-waves launch_bounds arg (r3/r11 spill cliffs).
// ---------------------------------------------------------------------------
__global__ __launch_bounds__(256) void gather_kernel(
    const int* __restrict__ csr_src, const int* __restrict__ off,
    const int* __restrict__ nodeorder, const float4* __restrict__ x4,
    const float* __restrict__ Ps, const float* __restrict__ Pd,
    const float* __restrict__ Wt1, const unsigned short* __restrict__ WbfA,
    const float* __restrict__ be2,
    const float* __restrict__ ln_g, const float* __restrict__ ln_b,
    const float* __restrict__ Wx, const float* __restrict__ bx,
    const float* __restrict__ Wg, const float* __restrict__ bg,
    float* __restrict__ agg_h, float* __restrict__ agg_x, int N) {
    const int lane = threadIdx.x & 63;
    const int wid = blockIdx.x * 4 + (threadIdx.x >> 6);
    const int e16 = lane & 15;
    const int hg = lane >> 4;
    const int k0 = hg * 8;
    const int p = e16 & 3;
    if (wid * 4 >= N) return;
    const int slot = wid * 4 + (e16 >> 2);

    short8v a[4][2];
#pragma unroll
    for (int t = 0; t < 4; ++t)
#pragma unroll
        for (int kc = 0; kc < 2; ++kc)
            a[t][kc] = *(const short8v*)&WbfA[(((t * 2 + kc) * 64) + lane) * 8];

    const float* colW = Wt1 + 256 * HID;
    float colWk[16];
#pragma unroll
    for (int j = 0; j < 8; ++j) {
        colWk[j] = colW[k0 + j];
        colWk[8 + j] = colW[k0 + 32 + j];
    }
    float be2r[16], cgr[16], cxr[16];
#pragma unroll
    for (int t = 0; t < 4; ++t)
#pragma unroll
        for (int r = 0; r < 4; ++r) {
            int f = t * 16 + hg * 4 + r;
            float g = ln_g[f];
            be2r[4 * t + r] = be2[f];
            cgr[4 * t + r] = g * Wg[f];
            cxr[4 * t + r] = g * Wx[f];
        }
    const float bgs = bg[0], bxs = bx[0];

    float Cg = ln_g[lane] * Wg[lane], Cx = ln_g[lane] * Wx[lane];
    float Cbg = ln_b[lane] * Wg[lane], Cbx = ln_b[lane] * Wx[lane];
    wredsum4(Cg, Cx, Cbg, Cbx);
    const float g0 = (lane < 16) ? 1.0f : 0.0f;

    const int nj = (slot < N) ? nodeorder[slot] : -1;
    int beg = 0, end = 0;
    if (nj >= 0) { beg = off[nj]; end = off[nj + 1]; }
    const float4 xdv = (nj >= 0) ? x4[nj] : make_float4(0.f, 0.f, 0.f, 0.f);
    float baseK[16];
    {
        const float4v* pd4 = (const float4v*)(Pd + (size_t)max(nj, 0) * HID + k0);
        float4v p0 = pd4[0], p1 = pd4[1], p2 = pd4[8], p3 = pd4[9];
#pragma unroll
        for (int j = 0; j < 4; ++j) {
            baseK[j] = p0[j];
            baseK[4 + j] = p1[j];
            baseK[8 + j] = p2[j];
            baseK[12 + j] = p3[j];
        }
    }

    int nb = (end - beg + 3) >> 2;
#pragma unroll
    for (int mk = 1; mk < 64; mk <<= 1) nb = max(nb, __shfl_xor(nb, mk, 64));
    nb = __builtin_amdgcn_readfirstlane(nb);

    float4v acc[4];
#pragma unroll
    for (int t = 0; t < 4; ++t) acc[t] = (float4v){0.f, 0.f, 0.f, 0.f};
    float ax0 = 0.f, ax1 = 0.f, ax2 = 0.f, Sa = 0.f, Smu = 0.f;

    for (int b = 0; b < nb; ++b) {
        int idx = beg + b * 4 + p;
        float validf = (idx < end) ? 1.0f : 0.0f;
        int ic = (idx < end) ? idx : (end > 0 ? end - 1 : 0);
        int s = csr_src[ic];
        float4 xs = x4[s];
        const float4v* ps4 = (const float4v*)(Ps + (size_t)s * HID + k0);
        float4v q0 = ps4[0], q1 = ps4[1], q2 = ps4[8], q3 = ps4[9];

        float r0 = xs.x - xdv.x, r1 = xs.y - xdv.y, r2 = xs.z - xdv.z;
        float dsq = r0 * r0 + r1 * r1 + r2 * r2;
        float inv = __builtin_amdgcn_rcpf(__builtin_amdgcn_sqrtf(dsq) + 1e-8f);

        short8v b0, b1;
#pragma unroll
        for (int j = 0; j < 4; ++j) {
            float z0 = q0[j] + baseK[j] + dsq * colWk[j];
            float z1 = q1[j] + baseK[4 + j] + dsq * colWk[4 + j];
            float z2 = q2[j] + baseK[8 + j] + dsq * colWk[8 + j];
            float z3 = q3[j] + baseK[12 + j] + dsq * colWk[12 + j];
            b0[j]     = (short)f2bf(silu_f(z0));
            b0[4 + j] = (short)f2bf(silu_f(z1));
            b1[j]     = (short)f2bf(silu_f(z2));
            b1[4 + j] = (short)f2bf(silu_f(z3));
        }

        float ms[16];
        float S1 = 0.f, S2 = 0.f, Sg = 0.f, Sx = 0.f;
#pragma unroll
        for (int t = 0; t < 4; ++t) {
            float4v c = (float4v){be2r[4 * t], be2r[4 * t + 1],
                                  be2r[4 * t + 2], be2r[4 * t + 3]};
            c = __builtin_amdgcn_mfma_f32_16x16x32_bf16(a[t][0], b0, c, 0, 0, 0);
            c = __builtin_amdgcn_mfma_f32_16x16x32_bf16(a[t][1], b1, c, 0, 0, 0);
#pragma unroll
            for (int r = 0; r < 4; ++r) {
                float v = c[r] * __builtin_amdgcn_rcpf(1.0f + __expf(-c[r]));
                ms[4 * t + r] = v;
                S1 += v;
                S2 = fmaf(v, v, S2);
                Sg = fmaf(v, cgr[4 * t + r], Sg);
                Sx = fmaf(v, cxr[4 * t + r], Sx);
            }
        }
#pragma unroll
        for (int mk = 16; mk < 64; mk <<= 1) {
            S1 += __shfl_xor(S1, mk, 64);
            S2 += __shfl_xor(S2, mk, 64);
            Sg += __shfl_xor(Sg, mk, 64);
            Sx += __shfl_xor(Sx, mk, 64);
        }

        float mu = S1 * (1.0f / HID);
        float var = S2 * (1.0f / HID) - mu * mu;
        float rstd = __builtin_amdgcn_rsqf(var + 1e-5f);
        float dg = fmaf(rstd, Sg - mu * Cg, Cbg);
        float dx = fmaf(rstd, Sx - mu * Cx, Cbx);
        float alpha = __builtin_amdgcn_rcpf(1.0f + __expf(-(dg + bgs))) * validf;
        float ta = __expf(2.0f * fmaf(alpha, dx, bxs));
        float cwv = 1.0f - 2.0f * __builtin_amdgcn_rcpf(ta + 1.0f);

        float u = rstd * alpha;
        Sa += alpha;
        Smu = fmaf(u, mu, Smu);
#pragma unroll
        for (int t = 0; t < 4; ++t) {
            float4v av = acc[t];
#pragma unroll
            for (int r = 0; r < 4; ++r) av[r] = fmaf(u, ms[4 * t + r], av[r]);
            acc[t] = av;
        }
        float rc = inv * cwv * validf * g0;
        ax0 = fmaf(r0, rc, ax0);
        ax1 = fmaf(r1, rc, ax1);
        ax2 = fmaf(r2, rc, ax2);
    }

#pragma unroll
    for (int t = 0; t < 4; ++t) {
        float4v av = acc[t];
#pragma unroll
        for (int r = 0; r < 4; ++r) {
            float v = av[r];
            v += __shfl_xor(v, 1, 64);
            v += __shfl_xor(v, 2, 64);
            av[r] = v;
        }
        acc[t] = av;
    }
    Sa  += __shfl_xor(Sa, 1, 64);  Sa  += __shfl_xor(Sa, 2, 64);
    Smu += __shfl_xor(Smu, 1, 64); Smu += __shfl_xor(Smu, 2, 64);
    ax0 += __shfl_xor(ax0, 1, 64); ax0 += __shfl_xor(ax0, 2, 64);
    ax1 += __shfl_xor(ax1, 1, 64); ax1 += __shfl_xor(ax1, 2, 64);
    ax2 += __shfl_xor(ax2, 1, 64); ax2 += __shfl_xor(ax2, 2, 64);

    if (p == 0 && nj >= 0) {
        float* dstp = agg_h + (size_t)nj * HID + hg * 4;
#pragma unroll
        for (int t = 0; t < 4; ++t) {
            int f = t * 16 + hg * 4;
            float4 o;
            o.x = fmaf(ln_g[f + 0], acc[t][0] - Smu, ln_b[f + 0] * Sa);
            o.y = fmaf(ln_g[f + 1], acc[t][1] - Smu, ln_b[f + 1] * Sa);
            o.z = fmaf(ln_g[f + 2], acc[t][2] - Smu, ln_b[f + 2] * Sa);
            o.w = fmaf(ln_g[f + 3], acc[t][3] - Smu, ln_b[f + 3] * Sa);
            *(float4*)(dstp + t * 16) = o;
        }
        if (hg == 0) {
            agg_x[nj * 3 + 0] = ax0;
            agg_x[nj * 3 + 1] = ax1;
            agg_x[nj * 3 + 2] = ax2;
        }
    }
}

// ---------------------------------------------------------------------------
// Fallback edge kernel (atomic aggregation) — only if ws too small for CSR.
// ---------------------------------------------------------------------------
__global__ __launch_bounds__(256) void edge_kernel_atomic(
    const int* __restrict__ src, const int* __restrict__ dst,
    const float* __restrict__ x,
    const float* __restrict__ Ps, const float* __restrict__ Pd,
    const float* __restrict__ Wt1, const float* __restrict__ Wt2,
    const float* __restrict__ be2,
    const float* __restrict__ ln_g, const float* __restrict__ ln_b,
    const float* __restrict__ Wx, const float* __restrict__ bx,
    const float* __restrict__ Wg, const float* __restrict__ bg,
    float* __restrict__ agg_h, float* __restrict__ agg_x, int E) {
    int e = blockIdx.x * 256 + threadIdx.x;
    if (e >= E) return;
    int s = src[e], d = dst[e];
    float r0 = x[s * 3] - x[d * 3], r1 = x[s * 3 + 1] - x[d * 3 + 1], r2 = x[s * 3 + 2] - x[d * 3 + 2];
    float dsq = r0 * r0 + r1 * r1 + r2 * r2;
    float inv = 1.0f / (sqrtf(dsq) + 1e-8f);
    float rn0 = r0 * inv, rn1 = r1 * inv, rn2 = r2 * inv;
    float z[HID];
    const float4* ps = (const float4*)(Ps + (size_t)s * HID);
    const float4* pd = (const float4*)(Pd + (size_t)d * HID);
    const float* colW = Wt1 + 256 * HID;
#pragma unroll
    for (int f4 = 0; f4 < HID / 4; ++f4) {
        float4 aa = ps[f4];
        float4 b = pd[f4];
        float av[4] = {aa.x, aa.y, aa.z, aa.w};
        float bv[4] = {b.x, b.y, b.z, b.w};
#pragma unroll
        for (int j = 0; j < 4; ++j) {
            int f = 4 * f4 + j;
            z[f] = silu_f(av[j] + bv[j] + dsq * colW[f]);
        }
    }
    float m[HID];
#pragma unroll
    for (int f = 0; f < HID; ++f) m[f] = be2[f];
#pragma unroll
    for (int k = 0; k < HID; ++k) {
        float zv = z[k];
#pragma unroll
        for (int f = 0; f < HID; ++f) m[f] = fmaf(zv, Wt2[k * HID + f], m[f]);
    }
#pragma unroll
    for (int f = 0; f < HID; ++f) m[f] = silu_f(m[f]);
    float mu = 0.f;
#pragma unroll
    for (int f = 0; f < HID; ++f) mu += m[f];
    mu *= (1.0f / HID);
    float var = 0.f;
#pragma unroll
    for (int f = 0; f < HID; ++f) {
        float t = m[f] - mu;
        var = fmaf(t, t, var);
    }
    var *= (1.0f / HID);
    float rstd = 1.0f / sqrtf(var + 1e-5f);
#pragma unroll
    for (int f = 0; f < HID; ++f) m[f] = (m[f] - mu) * rstd * ln_g[f] + ln_b[f];
    float dotg = 0.f, dotx = 0.f;
#pragma unroll
    for (int f = 0; f < HID; ++f) {
        dotg = fmaf(m[f], Wg[f], dotg);
        dotx = fmaf(m[f], Wx[f], dotx);
    }
    float alpha = 1.0f / (1.0f + __expf(-(dotg + bg[0])));
    float ta = __expf(2.0f * fmaf(alpha, dotx, bx[0]));
    float cw = 1.0f - 2.0f / (ta + 1.0f);
    float* ah = agg_h + (size_t)d * HID;
#pragma unroll
    for (int f = 0; f < HID; ++f) atomicAdd(&ah[f], m[f] * alpha);
    atomicAdd(&agg_x[d * 3 + 0], rn0 * cw);
    atomicAdd(&agg_x[d * 3 + 1], rn1 * cw);
    atomicAdd(&agg_x[d * 3 + 2], rn2 * cw);
}

// ---------------------------------------------------------------------------
// node_kernel (MFMA): one wave per 16-node tile.
//  stage1: hh = silu([h|agg_h] @ Wh1^T + bh1)   (6 kc x 4 ftiles, via LDS)
//  stage2: out = h + hh @ Wh2^T + bh2           (2 kc x 8 ftiles)
//  x-update tail by lanes 0..63 per block.
// ---------------------------------------------------------------------------
__global__ __launch_bounds__(256) void node_kernel(
    const float* __restrict__ h, const float* __restrict__ xin,
    const float* __restrict__ agg_h, const float* __restrict__ agg_x,
    const int* __restrict__ degI,
    const unsigned short* __restrict__ WpH1, const unsigned short* __restrict__ WpH2,
    const float* __restrict__ bh1, const float* __restrict__ bh2,
    float* __restrict__ out, int N) {
    __shared__ float hhL[4][16][72];   // stride 72 floats: 16B-aligned rows
    const int lane = threadIdx.x & 63;
    const int wslot = threadIdx.x >> 6;
    {
        int n = blockIdx.x * 64 + threadIdx.x;
        if (threadIdx.x < 64 && n < N) {
            float dv = (float)degI[n];
            float invd = 1.0f / fmaxf(dv, 1.0f);
            float* ox = out + (size_t)N * DF + (size_t)n * 3;
            ox[0] = xin[n * 3 + 0] + agg_x[n * 3 + 0] * invd;
            ox[1] = xin[n * 3 + 1] + agg_x[n * 3 + 1] * invd;
            ox[2] = xin[n * 3 + 2] + agg_x[n * 3 + 2] * invd;
        }
    }
    const int tile = (blockIdx.x * 4 + wslot) * 16;
    if (tile >= N) return;
    const int r15 = lane & 15, kg = lane >> 4;
    const int arow = min(tile + r15, N - 1);

    short8v A[6];
    const float* hr = h + (size_t)arow * DF + kg * 8;
#pragma unroll
    for (int kc = 0; kc < 4; ++kc) {
        float4 q0 = *(const float4*)(hr + kc * 32);
        float4 q1 = *(const float4*)(hr + kc * 32 + 4);
        A[kc] = pack_bf16(q0, q1);
    }
    const float* ar = agg_h + (size_t)arow * HID + kg * 8;
#pragma unroll
    for (int kc = 0; kc < 2; ++kc) {
        float4 q0 = *(const float4*)(ar + kc * 32);
        float4 q1 = *(const float4*)(ar + kc * 32 + 4);
        A[4 + kc] = pack_bf16(q0, q1);
    }

    // stage 1 -> LDS
#pragma unroll
    for (int ft = 0; ft < 4; ++ft) {
        float4v c = (float4v){0.f, 0.f, 0.f, 0.f};
#pragma unroll
        for (int kc = 0; kc < 6; ++kc) {
            short8v B = *(const short8v*)&WpH1[(((ft * 6 + kc) * 64) + lane) * 8];
            c = __builtin_amdgcn_mfma_f32_16x16x32_bf16(A[kc], B, c, 0, 0, 0);
        }
        int f = ft * 16 + r15;
        float b1v = bh1[f];
#pragma unroll
        for (int r = 0; r < 4; ++r)
            hhL[wslot][kg * 4 + r][f] = silu_f(c[r] + b1v);
    }
    __builtin_amdgcn_wave_barrier();

    // stage 2 A-frags from LDS (row = r15, k consecutive)
    short8v HA[2];
#pragma unroll
    for (int kc = 0; kc < 2; ++kc) {
        float4 q0 = *(const float4*)&hhL[wslot][r15][kc * 32 + kg * 8];
        float4 q1 = *(const float4*)&hhL[wslot][r15][kc * 32 + kg * 8 + 4];
        HA[kc] = pack_bf16(q0, q1);
    }

#pragma unroll
    for (int ft = 0; ft < 8; ++ft) {
        float4v c = (float4v){0.f, 0.f, 0.f, 0.f};
#pragma unroll
        for (int kc = 0; kc < 2; ++kc) {
            short8v B = *(const short8v*)&WpH2[(((ft * 2 + kc) * 64) + lane) * 8];
            c = __builtin_amdgcn_mfma_f32_16x16x32_bf16(HA[kc], B, c, 0, 0, 0);
        }
        int cc = ft * 16 + r15;
        float b2 = bh2[cc];
#pragma unroll
        for (int r = 0; r < 4; ++r) {
            int n = tile + kg * 4 + r;
            if (n < N)
                out[(size_t)n * DF + cc] = h[(size_t)n * DF + cc] + c[r] + b2;
        }
    }
}

extern "C" void kernel_launch(void* const* d_in, const int* in_sizes, int n_in,
                              void* d_out, int out_size, void* d_ws, size_t ws_size,
                              hipStream_t stream) {
    const float* h    = (const float*)d_in[0];
    const float* x    = (const float*)d_in[1];
    const int*   ei   = (const int*)d_in[2];
    const float* We1  = (const float*)d_in[3];
    const float* be1  = (const float*)d_in[4];
    const float* We2  = (const float*)d_in[5];
    const float* be2  = (const float*)d_in[6];
    const float* ln_g = (const float*)d_in[7];
    const float* ln_b = (const float*)d_in[8];
    const float* Wh1  = (const float*)d_in[9];
    const float* bh1  = (const float*)d_in[10];
    const float* Wh2  = (const float*)d_in[11];
    const float* bh2  = (const float*)d_in[12];
    const float* Wx   = (const float*)d_in[13];
    const float* bx   = (const float*)d_in[14];
    const float* Wg   = (const float*)d_in[15];
    const float* bg   = (const float*)d_in[16];

    const int E = in_sizes[2] / 2;
    const int N = in_sizes[0] / DF;
    const int* src = ei;
    const int* dst = ei + E;

    // ---- workspace carve (16B aligned regions) ----
    char* base = (char*)d_ws;
    size_t o = 0;
    auto carve = [&](size_t bytes) -> void* {
        void* r = base + o;
        o = (o + bytes + 15) & ~(size_t)15;
        return r;
    };
    const int nblk = (N + HB - 1) / HB;
    float* agg_h = (float*)carve((size_t)N * HID * 4);
    float* agg_x = (float*)carve((size_t)N * 3 * 4);
    float* Wt1   = (float*)carve(257 * 64 * 4);
    float* Wt2   = (float*)carve(64 * 64 * 4);
    unsigned short* WbfA = (unsigned short*)carve(4096 * 2);
    unsigned short* WpB1 = (unsigned short*)carve(16384 * 2);
    unsigned short* WpH1 = (unsigned short*)carve(12288 * 2);
    unsigned short* WpH2 = (unsigned short*)carve(8192 * 2);
    int*   cnt   = (int*)carve((size_t)N * 4);
    int*   off   = (int*)carve(((size_t)N + 1) * 4);
    int*   bsum  = (int*)carve(256 * 4);
    int*   lrank = (int*)carve((size_t)N * 4);
    int*   blockcnt = (int*)carve((size_t)nblk * 64 * 4);
    int*   bucketbase = (int*)carve(64 * 4);
    int*   nodeorder = (int*)carve((size_t)N * 4);
    float4* x4   = (float4*)carve((size_t)N * 16);
    int*   rank  = (int*)carve((size_t)E * 4);
    int*   csr_src = (int*)carve((size_t)E * 4);
    size_t need_full = o;

    // Ps/Pd live in d_out (N*128 <= out_size N*131); fully overwritten later.
    float* Ps = (float*)d_out;
    float* Pd = Ps + (size_t)N * HID;

    const int gE  = (E + 255) / 256;
    const int Nb  = (N + 1023) / 1024;
    const int tiles = (N + 15) / 16;
    const int gT  = (tiles + 3) / 4;       // 4 tiles (waves) per block

    hipMemsetAsync(cnt, 0, (size_t)N * 4, stream);
    prep_weights<<<(61504 + 255) / 256, 256, 0, stream>>>(
        We1, We2, Wh1, Wh2, Wt1, Wt2, WbfA, WpB1, WpH1, WpH2);
    node_pre<<<gT, 256, 0, stream>>>(h, WpB1, be1, x, Ps, Pd, x4, N);

    if (ws_size >= need_full) {
        // ---- CSR build + parallel two-level degree counting sort ----
        count_kernel<<<gE, 256, 0, stream>>>(dst, cnt, rank, E);
        scan1<<<Nb, 1024, 0, stream>>>(cnt, off, bsum, N);
        scan3<<<(N + 256) / 256, 256, 0, stream>>>(off, bsum, Nb, N, E);
        scatter_src<<<gE, 256, 0, stream>>>(dst, src, rank, off, csr_src, E);
        hist_local<<<nblk, HB, 0, stream>>>(cnt, lrank, blockcnt, N);
        hist_tot<<<1, 1024, 0, stream>>>(blockcnt, bucketbase, nblk);
        hist_scan2<<<64, 64, 0, stream>>>(blockcnt, bucketbase, nblk);
        degscatter2<<<nblk, HB, 0, stream>>>(cnt, lrank, blockcnt, nodeorder, N);
        // ---- fused gather: quad-node MFMA batches ----
        const int quads = (N + 3) / 4;
        gather_kernel<<<(quads + 3) / 4, 256, 0, stream>>>(
            csr_src, off, nodeorder, x4, Ps, Pd, Wt1, WbfA, be2,
            ln_g, ln_b, Wx, bx, Wg, bg, agg_h, agg_x, N);
    } else {
        // ---- fallback: atomic aggregation ----
        hipMemsetAsync(agg_h, 0, (size_t)N * 67 * 4, stream);
        count_kernel<<<gE, 256, 0, stream>>>(dst, cnt, nullptr, E);
        edge_kernel_atomic<<<gE, 256, 0, stream>>>(src, dst, x, Ps, Pd, Wt1, Wt2,
                                                   be2, ln_g, ln_b, Wx, bx,
                                                   Wg, bg, agg_h, agg_x, E);
    }

    node_kernel<<<gT, 256, 0, stream>>>(h, x, agg_h, agg_x, cnt,
                                        WpH1, WpH2, bh1, bh2, (float*)d_out, N);
}

// Round 17
// 188.647 us; speedup vs baseline: 2.0328x; 1.0492x over previous
//
#include <hip/hip_runtime.h>
#include <math.h>

#define HID 64
#define DF  128
#define HB  256   // hist block size

typedef __attribute__((ext_vector_type(8))) short short8v;   // 8 bf16
typedef __attribute__((ext_vector_type(4))) float float4v;
typedef __attribute__((ext_vector_type(4))) unsigned int uint4v;

__device__ __forceinline__ float silu_f(float v) {
    return v * __builtin_amdgcn_rcpf(1.0f + __expf(-v));
}

__device__ __forceinline__ unsigned short f2bf(float f) {   // RNE f32->bf16
    unsigned u = __float_as_uint(f);
    u += 0x7FFFu + ((u >> 16) & 1u);
    return (unsigned short)(u >> 16);
}

// packed 2x f32 -> 2x bf16 in one instr (RNE; gfx950)
__device__ __forceinline__ unsigned cvt2(float lo, float hi) {
    unsigned r;
    asm("v_cvt_pk_bf16_f32 %0, %1, %2" : "=v"(r) : "v"(lo), "v"(hi));
    return r;
}

__device__ __forceinline__ short8v pack8(float a0, float a1, float a2, float a3,
                                         float a4, float a5, float a6, float a7) {
    uint4v w;
    w[0] = cvt2(a0, a1);
    w[1] = cvt2(a2, a3);
    w[2] = cvt2(a4, a5);
    w[3] = cvt2(a6, a7);
    union { uint4v u; short8v s; } cv;
    cv.u = w;
    return cv.s;
}

__device__ __forceinline__ short8v pack_bf16(float4 a, float4 b) {
    return pack8(a.x, a.y, a.z, a.w, b.x, b.y, b.z, b.w);
}

// 4 simultaneous wave-wide sums
__device__ __forceinline__ void wredsum4(float& a, float& b, float& c, float& d) {
#pragma unroll
    for (int t = 1; t < 64; t <<= 1) {
        a += __shfl_xor(a, t, 64);
        b += __shfl_xor(b, t, 64);
        c += __shfl_xor(c, t, 64);
        d += __shfl_xor(d, t, 64);
    }
}

// ---------------------------------------------------------------------------
// Weight prep + cnt zeroing (memset folded in).
//  WbfA : We2 A-frags for gather              (4096 sh)
//  WpB1 : [Ps|Pd] B-frags, 8 ftiles x 4 kc    (16384 sh)
//  WpH1 : Wh1 B-frags, 4 ftiles x 6 kc        (12288 sh)
//  WpH2 : Wh2 B-frags, 8 ftiles x 2 kc        (8192 sh)
// ---------------------------------------------------------------------------
#define PREPW 61504
__global__ void prep_weights(const float* __restrict__ We1, const float* __restrict__ We2,
                             const float* __restrict__ Wh1, const float* __restrict__ Wh2,
                             float* __restrict__ Wt1, float* __restrict__ Wt2,
                             unsigned short* __restrict__ WbfA,
                             unsigned short* __restrict__ WpB1,
                             unsigned short* __restrict__ WpH1,
                             unsigned short* __restrict__ WpH2,
                             int* __restrict__ cnt, int N) {
    int i = blockIdx.x * 256 + threadIdx.x;
    if (i >= PREPW) {
        int n = i - PREPW;
        if (n < N) cnt[n] = 0;
        return;
    }
    if (i < 257 * 64) {
        int k = i >> 6, f = i & 63;
        Wt1[i] = We1[f * 257 + k];
        return;
    }
    int j = i - 257 * 64;
    if (j < 64 * 64) {
        int k = j >> 6, f = j & 63;
        Wt2[j] = We2[f * 64 + k];
        return;
    }
    j -= 64 * 64;
    if (j < 4096) {
        int jj = j & 7, lane = (j >> 3) & 63, kc = (j >> 9) & 1, t = (j >> 10) & 3;
        int f = t * 16 + (lane & 15);
        int k = kc * 32 + ((lane >> 4) * 8) + jj;
        WbfA[j] = f2bf(We2[f * 64 + k]);
        return;
    }
    j -= 4096;
    if (j < 16384) {
        int jj = j & 7, lane = (j >> 3) & 63, kc = (j >> 9) & 3, ft = j >> 11;
        int f = ft * 16 + (lane & 15);
        int k = kc * 32 + ((lane >> 4) * 8) + jj;
        float v = (f < 64) ? We1[f * 257 + k] : We1[(f - 64) * 257 + 128 + k];
        WpB1[j] = f2bf(v);
        return;
    }
    j -= 16384;
    if (j < 12288) {
        int jj = j & 7, lane = (j >> 3) & 63, idx = j >> 9;
        int kc = idx % 6, ft = idx / 6;
        int f = ft * 16 + (lane & 15);
        int k = kc * 32 + ((lane >> 4) * 8) + jj;
        WpH1[j] = f2bf(Wh1[f * 192 + k]);
        return;
    }
    j -= 12288;
    if (j < 8192) {
        int jj = j & 7, lane = (j >> 3) & 63, idx = j >> 9;
        int kc = idx & 1, ft = idx >> 1;
        int c = ft * 16 + (lane & 15);
        int k = kc * 32 + ((lane >> 4) * 8) + jj;
        WpH2[j] = f2bf(Wh2[c * 64 + k]);
        return;
    }
}

// ---------------------------------------------------------------------------
// CSR build
// ---------------------------------------------------------------------------
__global__ __launch_bounds__(256) void count_kernel(const int* __restrict__ dst,
                                                    int* __restrict__ cnt,
                                                    int* __restrict__ rank, int E) {
    int e = blockIdx.x * 256 + threadIdx.x;
    if (e >= E) return;
    int r = atomicAdd(&cnt[dst[e]], 1);
    if (rank) rank[e] = r;
}

__global__ __launch_bounds__(1024) void scan1(const int* __restrict__ cnt,
                                              int* __restrict__ off,
                                              int* __restrict__ bsum, int N) {
    __shared__ int sm[1024];
    int tid = threadIdx.x;
    int i = blockIdx.x * 1024 + tid;
    int v = (i < N) ? cnt[i] : 0;
    sm[tid] = v;
    __syncthreads();
    for (int ofs = 1; ofs < 1024; ofs <<= 1) {
        int t = (tid >= ofs) ? sm[tid - ofs] : 0;
        __syncthreads();
        sm[tid] += t;
        __syncthreads();
    }
    if (i < N) off[i] = sm[tid] - v;
    if (tid == 1023) bsum[blockIdx.x] = sm[1023];
}

__global__ __launch_bounds__(256) void scan3(int* __restrict__ off,
                                             const int* __restrict__ bsum,
                                             int Nb, int N, int E) {
    __shared__ int pref[64];
    if (threadIdx.x == 0) {
        int s = 0;
        for (int b = 0; b < Nb; ++b) { pref[b] = s; s += bsum[b]; }
    }
    __syncthreads();
    int i = blockIdx.x * 256 + threadIdx.x;
    if (i > N) return;
    if (i == N) off[N] = E;
    else off[i] += pref[i >> 10];
}

__global__ __launch_bounds__(256) void scatter_src(const int* __restrict__ dst,
                                                   const int* __restrict__ srcI,
                                                   const int* __restrict__ rank,
                                                   const int* __restrict__ off,
                                                   int* __restrict__ csr_src, int E) {
    int e = blockIdx.x * 256 + threadIdx.x;
    if (e >= E) return;
    csr_src[off[dst[e]] + rank[e]] = srcI[e];
}

// ---------------------------------------------------------------------------
// Degree counting-sort, two-level, no global atomics, no serial scans.
// ---------------------------------------------------------------------------
__global__ __launch_bounds__(HB) void hist_local(const int* __restrict__ cnt,
                                                 int* __restrict__ lrank,
                                                 int* __restrict__ blockcnt, int N) {
    __shared__ int lh[64];
    int tid = threadIdx.x;
    if (tid < 64) lh[tid] = 0;
    __syncthreads();
    int n = blockIdx.x * HB + tid;
    if (n < N) {
        int b = min(cnt[n], 63);
        lrank[n] = atomicAdd(&lh[b], 1);
    }
    __syncthreads();
    if (tid < 64) blockcnt[blockIdx.x * 64 + tid] = lh[tid];
}

__global__ __launch_bounds__(1024) void hist_tot(const int* __restrict__ blockcnt,
                                                 int* __restrict__ bucketbase, int nblk) {
    __shared__ int part[16][64];
    int b = threadIdx.x & 63, j = threadIdx.x >> 6;
    int s = 0;
    for (int k = j; k < nblk; k += 16) s += blockcnt[k * 64 + b];
    part[j][b] = s;
    __syncthreads();
    if (threadIdx.x < 64) {
        int t = 0;
#pragma unroll
        for (int jj = 1; jj < 16; ++jj) t += part[jj][threadIdx.x];
        part[0][threadIdx.x] += t;
    }
    __syncthreads();
    if (threadIdx.x == 0) {
        int base = 0;
        for (int bb = 0; bb < 64; ++bb) {
            int t = part[0][bb];
            bucketbase[bb] = base;
            base += t;
        }
    }
}

__global__ __launch_bounds__(64) void hist_scan2(int* __restrict__ blockcnt,
                                                 const int* __restrict__ bucketbase,
                                                 int nblk) {
    int b = blockIdx.x;
    int lane = threadIdx.x;
    int carry = bucketbase[b];
    for (int chunk = 0; chunk * 64 < nblk; ++chunk) {
        int k = chunk * 64 + lane;
        int c = (k < nblk) ? blockcnt[k * 64 + b] : 0;
        int v = c;
#pragma unroll
        for (int ofs = 1; ofs < 64; ofs <<= 1) {
            int t = __shfl_up(v, ofs, 64);
            if (lane >= ofs) v += t;
        }
        if (k < nblk) blockcnt[k * 64 + b] = carry + v - c;
        carry += __shfl(v, 63, 64);
    }
}

__global__ __launch_bounds__(HB) void degscatter2(const int* __restrict__ cnt,
                                                  const int* __restrict__ lrank,
                                                  const int* __restrict__ blockcnt,
                                                  int* __restrict__ nodeorder, int N) {
    int n = blockIdx.x * HB + threadIdx.x;
    if (n >= N) return;
    int b = min(cnt[n], 63);
    int pos = blockcnt[(n / HB) * 64 + b] + lrank[n];
    nodeorder[N - 1 - pos] = n;   // descending degree
}

// ---------------------------------------------------------------------------
// node_pre (MFMA): one wave per 16-node tile. Ps|Pd = h @ [Wsrc|Wdst]^T
// (be1 baked into Pd). Also packs x -> float4.
// ---------------------------------------------------------------------------
__global__ __launch_bounds__(256) void node_pre(
    const float* __restrict__ h, const unsigned short* __restrict__ WpB1,
    const float* __restrict__ be1, const float* __restrict__ xin,
    float* __restrict__ Ps, float* __restrict__ Pd,
    float4* __restrict__ x4, int N) {
    const int lane = threadIdx.x & 63;
    const int wslot = threadIdx.x >> 6;
    {
        int n = blockIdx.x * 64 + threadIdx.x;
        if (threadIdx.x < 64 && n < N)
            x4[n] = make_float4(xin[3 * n], xin[3 * n + 1], xin[3 * n + 2], 0.f);
    }
    const int tile = (blockIdx.x * 4 + wslot) * 16;
    if (tile >= N) return;
    const int r15 = lane & 15, kg = lane >> 4;
    const int arow = min(tile + r15, N - 1);
    const float* hr = h + (size_t)arow * DF + kg * 8;
    short8v A[4];
#pragma unroll
    for (int kc = 0; kc < 4; ++kc) {
        float4 q0 = *(const float4*)(hr + kc * 32);
        float4 q1 = *(const float4*)(hr + kc * 32 + 4);
        A[kc] = pack_bf16(q0, q1);
    }
#pragma unroll
    for (int ft = 0; ft < 8; ++ft) {
        float4v c = (float4v){0.f, 0.f, 0.f, 0.f};
#pragma unroll
        for (int kc = 0; kc < 4; ++kc) {
            short8v B = *(const short8v*)&WpB1[(((ft * 4 + kc) * 64) + lane) * 8];
            c = __builtin_amdgcn_mfma_f32_16x16x32_bf16(A[kc], B, c, 0, 0, 0);
        }
        int f = ft * 16 + r15;
        float bias = (f >= 64) ? be1[f - 64] : 0.f;
#pragma unroll
        for (int r = 0; r < 4; ++r) {
            int n = tile + kg * 4 + r;
            if (n < N) {
                float v = c[r] + bias;
                if (f < 64) Ps[(size_t)n * 64 + f] = v;
                else        Pd[(size_t)n * 64 + (f - 64)] = v;
            }
        }
    }
}

// ---------------------------------------------------------------------------
// Gather v11: quad-node MFMA batches + cvt_pk bf16 packing + next-src
// prefetch + final x-output written directly (deg = end-beg known here).
// NEVER pass a min-waves launch_bounds arg (r3/r11 spill cliffs).
// ---------------------------------------------------------------------------
__global__ __launch_bounds__(256) void gather_kernel(
    const int* __restrict__ csr_src, const int* __restrict__ off,
    const int* __restrict__ nodeorder, const float4* __restrict__ x4,
    const float* __restrict__ Ps, const float* __restrict__ Pd,
    const float* __restrict__ Wt1, const unsigned short* __restrict__ WbfA,
    const float* __restrict__ be2,
    const float* __restrict__ ln_g, const float* __restrict__ ln_b,
    const float* __restrict__ Wx, const float* __restrict__ bx,
    const float* __restrict__ Wg, const float* __restrict__ bg,
    float* __restrict__ agg_h, float* __restrict__ xout, int N) {
    const int lane = threadIdx.x & 63;
    const int wid = blockIdx.x * 4 + (threadIdx.x >> 6);
    const int e16 = lane & 15;
    const int hg = lane >> 4;
    const int k0 = hg * 8;
    const int p = e16 & 3;
    if (wid * 4 >= N) return;
    const int slot = wid * 4 + (e16 >> 2);

    short8v a[4][2];
#pragma unroll
    for (int t = 0; t < 4; ++t)
#pragma unroll
        for (int kc = 0; kc < 2; ++kc)
            a[t][kc] = *(const short8v*)&WbfA[(((t * 2 + kc) * 64) + lane) * 8];

    const float* colW = Wt1 + 256 * HID;
    float colWk[16];
#pragma unroll
    for (int j = 0; j < 8; ++j) {
        colWk[j] = colW[k0 + j];
        colWk[8 + j] = colW[k0 + 32 + j];
    }
    float be2r[16], cgr[16], cxr[16];
#pragma unroll
    for (int t = 0; t < 4; ++t)
#pragma unroll
        for (int r = 0; r < 4; ++r) {
            int f = t * 16 + hg * 4 + r;
            float g = ln_g[f];
            be2r[4 * t + r] = be2[f];
            cgr[4 * t + r] = g * Wg[f];
            cxr[4 * t + r] = g * Wx[f];
        }
    const float bgs = bg[0], bxs = bx[0];

    float Cg = ln_g[lane] * Wg[lane], Cx = ln_g[lane] * Wx[lane];
    float Cbg = ln_b[lane] * Wg[lane], Cbx = ln_b[lane] * Wx[lane];
    wredsum4(Cg, Cx, Cbg, Cbx);
    const float g0 = (lane < 16) ? 1.0f : 0.0f;

    const int nj = (slot < N) ? nodeorder[slot] : -1;
    int beg = 0, end = 0;
    if (nj >= 0) { beg = off[nj]; end = off[nj + 1]; }
    const float4 xdv = (nj >= 0) ? x4[nj] : make_float4(0.f, 0.f, 0.f, 0.f);
    float baseK[16];
    {
        const float4v* pd4 = (const float4v*)(Pd + (size_t)max(nj, 0) * HID + k0);
        float4v p0 = pd4[0], p1 = pd4[1], p2 = pd4[8], p3 = pd4[9];
#pragma unroll
        for (int j = 0; j < 4; ++j) {
            baseK[j] = p0[j];
            baseK[4 + j] = p1[j];
            baseK[8 + j] = p2[j];
            baseK[12 + j] = p3[j];
        }
    }

    int nb = (end - beg + 3) >> 2;
#pragma unroll
    for (int mk = 1; mk < 64; mk <<= 1) nb = max(nb, __shfl_xor(nb, mk, 64));
    nb = __builtin_amdgcn_readfirstlane(nb);

    float4v acc[4];
#pragma unroll
    for (int t = 0; t < 4; ++t) acc[t] = (float4v){0.f, 0.f, 0.f, 0.f};
    float ax0 = 0.f, ax1 = 0.f, ax2 = 0.f, Sa = 0.f, Smu = 0.f;

    // prefetch first batch's src index
    int sC = 0;
    if (nb > 0) {
        int idx = beg + p;
        int ic = (idx < end) ? idx : (end > 0 ? end - 1 : 0);
        sC = csr_src[ic];
    }

    for (int b = 0; b < nb; ++b) {
        int idx = beg + b * 4 + p;
        float validf = (idx < end) ? 1.0f : 0.0f;
        int s = sC;
        // prefetch next batch's src index (1 VGPR; halves dependent chain)
        if (b + 1 < nb) {
            int idx2 = beg + (b + 1) * 4 + p;
            int ic2 = (idx2 < end) ? idx2 : (end > 0 ? end - 1 : 0);
            sC = csr_src[ic2];
        }
        float4 xs = x4[s];
        const float4v* ps4 = (const float4v*)(Ps + (size_t)s * HID + k0);
        float4v q0 = ps4[0], q1 = ps4[1], q2 = ps4[8], q3 = ps4[9];

        float r0 = xs.x - xdv.x, r1 = xs.y - xdv.y, r2 = xs.z - xdv.z;
        float dsq = r0 * r0 + r1 * r1 + r2 * r2;
        float inv = __builtin_amdgcn_rcpf(__builtin_amdgcn_sqrtf(dsq) + 1e-8f);

        float zb[16];
#pragma unroll
        for (int j = 0; j < 4; ++j) {
            zb[j]      = silu_f(q0[j] + baseK[j] + dsq * colWk[j]);
            zb[4 + j]  = silu_f(q1[j] + baseK[4 + j] + dsq * colWk[4 + j]);
            zb[8 + j]  = silu_f(q2[j] + baseK[8 + j] + dsq * colWk[8 + j]);
            zb[12 + j] = silu_f(q3[j] + baseK[12 + j] + dsq * colWk[12 + j]);
        }
        short8v b0 = pack8(zb[0], zb[1], zb[2], zb[3], zb[4], zb[5], zb[6], zb[7]);
        short8v b1 = pack8(zb[8], zb[9], zb[10], zb[11], zb[12], zb[13], zb[14], zb[15]);

        float ms[16];
        float S1 = 0.f, S2 = 0.f, Sg = 0.f, Sx = 0.f;
#pragma unroll
        for (int t = 0; t < 4; ++t) {
            float4v c = (float4v){be2r[4 * t], be2r[4 * t + 1],
                                  be2r[4 * t + 2], be2r[4 * t + 3]};
            c = __builtin_amdgcn_mfma_f32_16x16x32_bf16(a[t][0], b0, c, 0, 0, 0);
            c = __builtin_amdgcn_mfma_f32_16x16x32_bf16(a[t][1], b1, c, 0, 0, 0);
#pragma unroll
            for (int r = 0; r < 4; ++r) {
                float v = c[r] * __builtin_amdgcn_rcpf(1.0f + __expf(-c[r]));
                ms[4 * t + r] = v;
                S1 += v;
                S2 = fmaf(v, v, S2);
                Sg = fmaf(v, cgr[4 * t + r], Sg);
                Sx = fmaf(v, cxr[4 * t + r], Sx);
            }
        }
#pragma unroll
        for (int mk = 16; mk < 64; mk <<= 1) {
            S1 += __shfl_xor(S1, mk, 64);
            S2 += __shfl_xor(S2, mk, 64);
            Sg += __shfl_xor(Sg, mk, 64);
            Sx += __shfl_xor(Sx, mk, 64);
        }

        float mu = S1 * (1.0f / HID);
        float var = S2 * (1.0f / HID) - mu * mu;
        float rstd = __builtin_amdgcn_rsqf(var + 1e-5f);
        float dg = fmaf(rstd, Sg - mu * Cg, Cbg);
        float dx = fmaf(rstd, Sx - mu * Cx, Cbx);
        float alpha = __builtin_amdgcn_rcpf(1.0f + __expf(-(dg + bgs))) * validf;
        float ta = __expf(2.0f * fmaf(alpha, dx, bxs));
        float cwv = 1.0f - 2.0f * __builtin_amdgcn_rcpf(ta + 1.0f);

        float u = rstd * alpha;
        Sa += alpha;
        Smu = fmaf(u, mu, Smu);
#pragma unroll
        for (int t = 0; t < 4; ++t) {
            float4v av = acc[t];
#pragma unroll
            for (int r = 0; r < 4; ++r) av[r] = fmaf(u, ms[4 * t + r], av[r]);
            acc[t] = av;
        }
        float rc = inv * cwv * validf * g0;
        ax0 = fmaf(r0, rc, ax0);
        ax1 = fmaf(r1, rc, ax1);
        ax2 = fmaf(r2, rc, ax2);
    }

#pragma unroll
    for (int t = 0; t < 4; ++t) {
        float4v av = acc[t];
#pragma unroll
        for (int r = 0; r < 4; ++r) {
            float v = av[r];
            v += __shfl_xor(v, 1, 64);
            v += __shfl_xor(v, 2, 64);
            av[r] = v;
        }
        acc[t] = av;
    }
    Sa  += __shfl_xor(Sa, 1, 64);  Sa  += __shfl_xor(Sa, 2, 64);
    Smu += __shfl_xor(Smu, 1, 64); Smu += __shfl_xor(Smu, 2, 64);
    ax0 += __shfl_xor(ax0, 1, 64); ax0 += __shfl_xor(ax0, 2, 64);
    ax1 += __shfl_xor(ax1, 1, 64); ax1 += __shfl_xor(ax1, 2, 64);
    ax2 += __shfl_xor(ax2, 1, 64); ax2 += __shfl_xor(ax2, 2, 64);

    if (p == 0 && nj >= 0) {
        float* dstp = agg_h + (size_t)nj * HID + hg * 4;
#pragma unroll
        for (int t = 0; t < 4; ++t) {
            int f = t * 16 + hg * 4;
            float4 o;
            o.x = fmaf(ln_g[f + 0], acc[t][0] - Smu, ln_b[f + 0] * Sa);
            o.y = fmaf(ln_g[f + 1], acc[t][1] - Smu, ln_b[f + 1] * Sa);
            o.z = fmaf(ln_g[f + 2], acc[t][2] - Smu, ln_b[f + 2] * Sa);
            o.w = fmaf(ln_g[f + 3], acc[t][3] - Smu, ln_b[f + 3] * Sa);
            *(float4*)(dstp + t * 16) = o;
        }
        if (hg == 0) {
            // final coordinate output (coords_agg='mean')
            float invd = 1.0f / fmaxf((float)(end - beg), 1.0f);
            float* ox = xout + (size_t)nj * 3;
            ox[0] = xdv.x + ax0 * invd;
            ox[1] = xdv.y + ax1 * invd;
            ox[2] = xdv.z + ax2 * invd;
        }
    }
}

// ---------------------------------------------------------------------------
// Fallback edge kernel (atomic aggregation) — only if ws too small for CSR.
// ---------------------------------------------------------------------------
__global__ __launch_bounds__(256) void edge_kernel_atomic(
    const int* __restrict__ src, const int* __restrict__ dst,
    const float* __restrict__ x,
    const float* __restrict__ Ps, const float* __restrict__ Pd,
    const float* __restrict__ Wt1, const float* __restrict__ Wt2,
    const float* __restrict__ be2,
    const float* __restrict__ ln_g, const float* __restrict__ ln_b,
    const float* __restrict__ Wx, const float* __restrict__ bx,
    const float* __restrict__ Wg, const float* __restrict__ bg,
    float* __restrict__ agg_h, float* __restrict__ agg_x, int E) {
    int e = blockIdx.x * 256 + threadIdx.x;
    if (e >= E) return;
    int s = src[e], d = dst[e];
    float r0 = x[s * 3] - x[d * 3], r1 = x[s * 3 + 1] - x[d * 3 + 1], r2 = x[s * 3 + 2] - x[d * 3 + 2];
    float dsq = r0 * r0 + r1 * r1 + r2 * r2;
    float inv = 1.0f / (sqrtf(dsq) + 1e-8f);
    float rn0 = r0 * inv, rn1 = r1 * inv, rn2 = r2 * inv;
    float z[HID];
    const float4* ps = (const float4*)(Ps + (size_t)s * HID);
    const float4* pd = (const float4*)(Pd + (size_t)d * HID);
    const float* colW = Wt1 + 256 * HID;
#pragma unroll
    for (int f4 = 0; f4 < HID / 4; ++f4) {
        float4 aa = ps[f4];
        float4 b = pd[f4];
        float av[4] = {aa.x, aa.y, aa.z, aa.w};
        float bv[4] = {b.x, b.y, b.z, b.w};
#pragma unroll
        for (int j = 0; j < 4; ++j) {
            int f = 4 * f4 + j;
            z[f] = silu_f(av[j] + bv[j] + dsq * colW[f]);
        }
    }
    float m[HID];
#pragma unroll
    for (int f = 0; f < HID; ++f) m[f] = be2[f];
#pragma unroll
    for (int k = 0; k < HID; ++k) {
        float zv = z[k];
#pragma unroll
        for (int f = 0; f < HID; ++f) m[f] = fmaf(zv, Wt2[k * HID + f], m[f]);
    }
#pragma unroll
    for (int f = 0; f < HID; ++f) m[f] = silu_f(m[f]);
    float mu = 0.f;
#pragma unroll
    for (int f = 0; f < HID; ++f) mu += m[f];
    mu *= (1.0f / HID);
    float var = 0.f;
#pragma unroll
    for (int f = 0; f < HID; ++f) {
        float t = m[f] - mu;
        var = fmaf(t, t, var);
    }
    var *= (1.0f / HID);
    float rstd = 1.0f / sqrtf(var + 1e-5f);
#pragma unroll
    for (int f = 0; f < HID; ++f) m[f] = (m[f] - mu) * rstd * ln_g[f] + ln_b[f];
    float dotg = 0.f, dotx = 0.f;
#pragma unroll
    for (int f = 0; f < HID; ++f) {
        dotg = fmaf(m[f], Wg[f], dotg);
        dotx = fmaf(m[f], Wx[f], dotx);
    }
    float alpha = 1.0f / (1.0f + __expf(-(dotg + bg[0])));
    float ta = __expf(2.0f * fmaf(alpha, dotx, bx[0]));
    float cw = 1.0f - 2.0f / (ta + 1.0f);
    float* ah = agg_h + (size_t)d * HID;
#pragma unroll
    for (int f = 0; f < HID; ++f) atomicAdd(&ah[f], m[f] * alpha);
    atomicAdd(&agg_x[d * 3 + 0], rn0 * cw);
    atomicAdd(&agg_x[d * 3 + 1], rn1 * cw);
    atomicAdd(&agg_x[d * 3 + 2], rn2 * cw);
}

// ---------------------------------------------------------------------------
// node_kernel (MFMA): one wave per 16-node tile. x-tail only when writeX!=0
// (fallback path; main path writes x in gather).
// ---------------------------------------------------------------------------
__global__ __launch_bounds__(256) void node_kernel(
    const float* __restrict__ h, const float* __restrict__ xin,
    const float* __restrict__ agg_h, const float* __restrict__ agg_x,
    const int* __restrict__ degI,
    const unsigned short* __restrict__ WpH1, const unsigned short* __restrict__ WpH2,
    const float* __restrict__ bh1, const float* __restrict__ bh2,
    float* __restrict__ out, int N, int writeX) {
    __shared__ float hhL[4][16][72];
    const int lane = threadIdx.x & 63;
    const int wslot = threadIdx.x >> 6;
    if (writeX) {
        int n = blockIdx.x * 64 + threadIdx.x;
        if (threadIdx.x < 64 && n < N) {
            float dv = (float)degI[n];
            float invd = 1.0f / fmaxf(dv, 1.0f);
            float* ox = out + (size_t)N * DF + (size_t)n * 3;
            ox[0] = xin[n * 3 + 0] + agg_x[n * 3 + 0] * invd;
            ox[1] = xin[n * 3 + 1] + agg_x[n * 3 + 1] * invd;
            ox[2] = xin[n * 3 + 2] + agg_x[n * 3 + 2] * invd;
        }
    }
    const int tile = (blockIdx.x * 4 + wslot) * 16;
    if (tile >= N) return;
    const int r15 = lane & 15, kg = lane >> 4;
    const int arow = min(tile + r15, N - 1);

    short8v A[6];
    const float* hr = h + (size_t)arow * DF + kg * 8;
#pragma unroll
    for (int kc = 0; kc < 4; ++kc) {
        float4 q0 = *(const float4*)(hr + kc * 32);
        float4 q1 = *(const float4*)(hr + kc * 32 + 4);
        A[kc] = pack_bf16(q0, q1);
    }
    const float* ar = agg_h + (size_t)arow * HID + kg * 8;
#pragma unroll
    for (int kc = 0; kc < 2; ++kc) {
        float4 q0 = *(const float4*)(ar + kc * 32);
        float4 q1 = *(const float4*)(ar + kc * 32 + 4);
        A[4 + kc] = pack_bf16(q0, q1);
    }

#pragma unroll
    for (int ft = 0; ft < 4; ++ft) {
        float4v c = (float4v){0.f, 0.f, 0.f, 0.f};
#pragma unroll
        for (int kc = 0; kc < 6; ++kc) {
            short8v B = *(const short8v*)&WpH1[(((ft * 6 + kc) * 64) + lane) * 8];
            c = __builtin_amdgcn_mfma_f32_16x16x32_bf16(A[kc], B, c, 0, 0, 0);
        }
        int f = ft * 16 + r15;
        float b1v = bh1[f];
#pragma unroll
        for (int r = 0; r < 4; ++r)
            hhL[wslot][kg * 4 + r][f] = silu_f(c[r] + b1v);
    }
    __builtin_amdgcn_wave_barrier();

    short8v HA[2];
#pragma unroll
    for (int kc = 0; kc < 2; ++kc) {
        float4 q0 = *(const float4*)&hhL[wslot][r15][kc * 32 + kg * 8];
        float4 q1 = *(const float4*)&hhL[wslot][r15][kc * 32 + kg * 8 + 4];
        HA[kc] = pack_bf16(q0, q1);
    }

#pragma unroll
    for (int ft = 0; ft < 8; ++ft) {
        float4v c = (float4v){0.f, 0.f, 0.f, 0.f};
#pragma unroll
        for (int kc = 0; kc < 2; ++kc) {
            short8v B = *(const short8v*)&WpH2[(((ft * 2 + kc) * 64) + lane) * 8];
            c = __builtin_amdgcn_mfma_f32_16x16x32_bf16(HA[kc], B, c, 0, 0, 0);
        }
        int cc = ft * 16 + r15;
        float b2 = bh2[cc];
#pragma unroll
        for (int r = 0; r < 4; ++r) {
            int n = tile + kg * 4 + r;
            if (n < N)
                out[(size_t)n * DF + cc] = h[(size_t)n * DF + cc] + c[r] + b2;
        }
    }
}

extern "C" void kernel_launch(void* const* d_in, const int* in_sizes, int n_in,
                              void* d_out, int out_size, void* d_ws, size_t ws_size,
                              hipStream_t stream) {
    const float* h    = (const float*)d_in[0];
    const float* x    = (const float*)d_in[1];
    const int*   ei   = (const int*)d_in[2];
    const float* We1  = (const float*)d_in[3];
    const float* be1  = (const float*)d_in[4];
    const float* We2  = (const float*)d_in[5];
    const float* be2  = (const float*)d_in[6];
    const float* ln_g = (const float*)d_in[7];
    const float* ln_b = (const float*)d_in[8];
    const float* Wh1  = (const float*)d_in[9];
    const float* bh1  = (const float*)d_in[10];
    const float* Wh2  = (const float*)d_in[11];
    const float* bh2  = (const float*)d_in[12];
    const float* Wx   = (const float*)d_in[13];
    const float* bx   = (const float*)d_in[14];
    const float* Wg   = (const float*)d_in[15];
    const float* bg   = (const float*)d_in[16];

    const int E = in_sizes[2] / 2;
    const int N = in_sizes[0] / DF;
    const int* src = ei;
    const int* dst = ei + E;

    // ---- workspace carve (16B aligned regions) ----
    char* base = (char*)d_ws;
    size_t o = 0;
    auto carve = [&](size_t bytes) -> void* {
        void* r = base + o;
        o = (o + bytes + 15) & ~(size_t)15;
        return r;
    };
    const int nblk = (N + HB - 1) / HB;
    float* agg_h = (float*)carve((size_t)N * HID * 4);
    float* agg_x = (float*)carve((size_t)N * 3 * 4);
    float* Wt1   = (float*)carve(257 * 64 * 4);
    float* Wt2   = (float*)carve(64 * 64 * 4);
    unsigned short* WbfA = (unsigned short*)carve(4096 * 2);
    unsigned short* WpB1 = (unsigned short*)carve(16384 * 2);
    unsigned short* WpH1 = (unsigned short*)carve(12288 * 2);
    unsigned short* WpH2 = (unsigned short*)carve(8192 * 2);
    int*   cnt   = (int*)carve((size_t)N * 4);
    int*   off   = (int*)carve(((size_t)N + 1) * 4);
    int*   bsum  = (int*)carve(256 * 4);
    int*   lrank = (int*)carve((size_t)N * 4);
    int*   blockcnt = (int*)carve((size_t)nblk * 64 * 4);
    int*   bucketbase = (int*)carve(64 * 4);
    int*   nodeorder = (int*)carve((size_t)N * 4);
    float4* x4   = (float4*)carve((size_t)N * 16);
    int*   rank  = (int*)carve((size_t)E * 4);
    int*   csr_src = (int*)carve((size_t)E * 4);
    size_t need_full = o;

    // Ps/Pd live in d_out (N*128 <= out_size N*131); fully overwritten later.
    float* Ps = (float*)d_out;
    float* Pd = Ps + (size_t)N * HID;
    float* xout = (float*)d_out + (size_t)N * DF;

    const int gE  = (E + 255) / 256;
    const int Nb  = (N + 1023) / 1024;
    const int tiles = (N + 15) / 16;
    const int gT  = (tiles + 3) / 4;

    prep_weights<<<(PREPW + N + 255) / 256, 256, 0, stream>>>(
        We1, We2, Wh1, Wh2, Wt1, Wt2, WbfA, WpB1, WpH1, WpH2, cnt, N);
    node_pre<<<gT, 256, 0, stream>>>(h, WpB1, be1, x, Ps, Pd, x4, N);

    if (ws_size >= need_full) {
        // ---- CSR build + parallel two-level degree counting sort ----
        count_kernel<<<gE, 256, 0, stream>>>(dst, cnt, rank, E);
        scan1<<<Nb, 1024, 0, stream>>>(cnt, off, bsum, N);
        scan3<<<(N + 256) / 256, 256, 0, stream>>>(off, bsum, Nb, N, E);
        scatter_src<<<gE, 256, 0, stream>>>(dst, src, rank, off, csr_src, E);
        hist_local<<<nblk, HB, 0, stream>>>(cnt, lrank, blockcnt, N);
        hist_tot<<<1, 1024, 0, stream>>>(blockcnt, bucketbase, nblk);
        hist_scan2<<<64, 64, 0, stream>>>(blockcnt, bucketbase, nblk);
        degscatter2<<<nblk, HB, 0, stream>>>(cnt, lrank, blockcnt, nodeorder, N);
        // ---- fused gather: quad-node MFMA batches; writes xout directly ----
        const int quads = (N + 3) / 4;
        gather_kernel<<<(quads + 3) / 4, 256, 0, stream>>>(
            csr_src, off, nodeorder, x4, Ps, Pd, Wt1, WbfA, be2,
            ln_g, ln_b, Wx, bx, Wg, bg, agg_h, xout, N);
        node_kernel<<<gT, 256, 0, stream>>>(h, x, agg_h, agg_x, cnt,
                                            WpH1, WpH2, bh1, bh2, (float*)d_out, N, 0);
    } else {
        // ---- fallback: atomic aggregation ----
        hipMemsetAsync(agg_h, 0, (size_t)N * 67 * 4, stream);
        count_kernel<<<gE, 256, 0, stream>>>(dst, cnt, nullptr, E);
        edge_kernel_atomic<<<gE, 256, 0, stream>>>(src, dst, x, Ps, Pd, Wt1, Wt2,
                                                   be2, ln_g, ln_b, Wx, bx,
                                                   Wg, bg, agg_h, agg_x, E);
        node_kernel<<<gT, 256, 0, stream>>>(h, x, agg_h, agg_x, cnt,
                                            WpH1, WpH2, bh1, bh2, (float*)d_out, N, 1);
    }
}

// Round 18
// 185.820 us; speedup vs baseline: 2.0637x; 1.0152x over previous
//
#include <hip/hip_runtime.h>
#include <math.h>

#define HID 64
#define DF  128
#define HB  256   // hist block size

typedef __attribute__((ext_vector_type(8))) short short8v;   // 8 bf16
typedef __attribute__((ext_vector_type(4))) float float4v;
typedef __attribute__((ext_vector_type(4))) unsigned int uint4v;

__device__ __forceinline__ float silu_f(float v) {
    return v * __builtin_amdgcn_rcpf(1.0f + __expf(-v));
}

__device__ __forceinline__ unsigned short f2bf(float f) {   // RNE f32->bf16
    unsigned u = __float_as_uint(f);
    u += 0x7FFFu + ((u >> 16) & 1u);
    return (unsigned short)(u >> 16);
}

// packed 2x f32 -> 2x bf16 in one instr (RNE; gfx950)
__device__ __forceinline__ unsigned cvt2(float lo, float hi) {
    unsigned r;
    asm("v_cvt_pk_bf16_f32 %0, %1, %2" : "=v"(r) : "v"(lo), "v"(hi));
    return r;
}

__device__ __forceinline__ short8v pack8(float a0, float a1, float a2, float a3,
                                         float a4, float a5, float a6, float a7) {
    uint4v w;
    w[0] = cvt2(a0, a1);
    w[1] = cvt2(a2, a3);
    w[2] = cvt2(a4, a5);
    w[3] = cvt2(a6, a7);
    union { uint4v u; short8v s; } cv;
    cv.u = w;
    return cv.s;
}

__device__ __forceinline__ short8v pack_bf16(float4 a, float4 b) {
    return pack8(a.x, a.y, a.z, a.w, b.x, b.y, b.z, b.w);
}

// 4 simultaneous wave-wide sums
__device__ __forceinline__ void wredsum4(float& a, float& b, float& c, float& d) {
#pragma unroll
    for (int t = 1; t < 64; t <<= 1) {
        a += __shfl_xor(a, t, 64);
        b += __shfl_xor(b, t, 64);
        c += __shfl_xor(c, t, 64);
        d += __shfl_xor(d, t, 64);
    }
}

// ---------------------------------------------------------------------------
// Weight prep + cnt zeroing (memset folded in).
// ---------------------------------------------------------------------------
#define PREPW 61504
__global__ void prep_weights(const float* __restrict__ We1, const float* __restrict__ We2,
                             const float* __restrict__ Wh1, const float* __restrict__ Wh2,
                             float* __restrict__ Wt1, float* __restrict__ Wt2,
                             unsigned short* __restrict__ WbfA,
                             unsigned short* __restrict__ WpB1,
                             unsigned short* __restrict__ WpH1,
                             unsigned short* __restrict__ WpH2,
                             int* __restrict__ cnt, int N) {
    int i = blockIdx.x * 256 + threadIdx.x;
    if (i >= PREPW) {
        int n = i - PREPW;
        if (n < N) cnt[n] = 0;
        return;
    }
    if (i < 257 * 64) {
        int k = i >> 6, f = i & 63;
        Wt1[i] = We1[f * 257 + k];
        return;
    }
    int j = i - 257 * 64;
    if (j < 64 * 64) {
        int k = j >> 6, f = j & 63;
        Wt2[j] = We2[f * 64 + k];
        return;
    }
    j -= 64 * 64;
    if (j < 4096) {
        int jj = j & 7, lane = (j >> 3) & 63, kc = (j >> 9) & 1, t = (j >> 10) & 3;
        int f = t * 16 + (lane & 15);
        int k = kc * 32 + ((lane >> 4) * 8) + jj;
        WbfA[j] = f2bf(We2[f * 64 + k]);
        return;
    }
    j -= 4096;
    if (j < 16384) {
        int jj = j & 7, lane = (j >> 3) & 63, kc = (j >> 9) & 3, ft = j >> 11;
        int f = ft * 16 + (lane & 15);
        int k = kc * 32 + ((lane >> 4) * 8) + jj;
        float v = (f < 64) ? We1[f * 257 + k] : We1[(f - 64) * 257 + 128 + k];
        WpB1[j] = f2bf(v);
        return;
    }
    j -= 16384;
    if (j < 12288) {
        int jj = j & 7, lane = (j >> 3) & 63, idx = j >> 9;
        int kc = idx % 6, ft = idx / 6;
        int f = ft * 16 + (lane & 15);
        int k = kc * 32 + ((lane >> 4) * 8) + jj;
        WpH1[j] = f2bf(Wh1[f * 192 + k]);
        return;
    }
    j -= 12288;
    if (j < 8192) {
        int jj = j & 7, lane = (j >> 3) & 63, idx = j >> 9;
        int kc = idx & 1, ft = idx >> 1;
        int c = ft * 16 + (lane & 15);
        int k = kc * 32 + ((lane >> 4) * 8) + jj;
        WpH2[j] = f2bf(Wh2[c * 64 + k]);
        return;
    }
}

// ---------------------------------------------------------------------------
// CSR build
// ---------------------------------------------------------------------------
__global__ __launch_bounds__(256) void count_kernel(const int* __restrict__ dst,
                                                    int* __restrict__ cnt,
                                                    int* __restrict__ rank, int E) {
    int e = blockIdx.x * 256 + threadIdx.x;
    if (e >= E) return;
    int r = atomicAdd(&cnt[dst[e]], 1);
    if (rank) rank[e] = r;
}

__global__ __launch_bounds__(1024) void scan1(const int* __restrict__ cnt,
                                              int* __restrict__ off,
                                              int* __restrict__ bsum, int N) {
    __shared__ int sm[1024];
    int tid = threadIdx.x;
    int i = blockIdx.x * 1024 + tid;
    int v = (i < N) ? cnt[i] : 0;
    sm[tid] = v;
    __syncthreads();
    for (int ofs = 1; ofs < 1024; ofs <<= 1) {
        int t = (tid >= ofs) ? sm[tid - ofs] : 0;
        __syncthreads();
        sm[tid] += t;
        __syncthreads();
    }
    if (i < N) off[i] = sm[tid] - v;
    if (tid == 1023) bsum[blockIdx.x] = sm[1023];
}

__global__ __launch_bounds__(256) void scan3(int* __restrict__ off,
                                             const int* __restrict__ bsum,
                                             int Nb, int N, int E) {
    __shared__ int pref[64];
    if (threadIdx.x == 0) {
        int s = 0;
        for (int b = 0; b < Nb; ++b) { pref[b] = s; s += bsum[b]; }
    }
    __syncthreads();
    int i = blockIdx.x * 256 + threadIdx.x;
    if (i > N) return;
    if (i == N) off[N] = E;
    else off[i] += pref[i >> 10];
}

__global__ __launch_bounds__(256) void scatter_src(const int* __restrict__ dst,
                                                   const int* __restrict__ srcI,
                                                   const int* __restrict__ rank,
                                                   const int* __restrict__ off,
                                                   int* __restrict__ csr_src, int E) {
    int e = blockIdx.x * 256 + threadIdx.x;
    if (e >= E) return;
    csr_src[off[dst[e]] + rank[e]] = srcI[e];
}

// ---------------------------------------------------------------------------
// Degree counting-sort, two-level, no global atomics, no serial scans.
// ---------------------------------------------------------------------------
__global__ __launch_bounds__(HB) void hist_local(const int* __restrict__ cnt,
                                                 int* __restrict__ lrank,
                                                 int* __restrict__ blockcnt, int N) {
    __shared__ int lh[64];
    int tid = threadIdx.x;
    if (tid < 64) lh[tid] = 0;
    __syncthreads();
    int n = blockIdx.x * HB + tid;
    if (n < N) {
        int b = min(cnt[n], 63);
        lrank[n] = atomicAdd(&lh[b], 1);
    }
    __syncthreads();
    if (tid < 64) blockcnt[blockIdx.x * 64 + tid] = lh[tid];
}

__global__ __launch_bounds__(1024) void hist_tot(const int* __restrict__ blockcnt,
                                                 int* __restrict__ bucketbase, int nblk) {
    __shared__ int part[16][64];
    int b = threadIdx.x & 63, j = threadIdx.x >> 6;
    int s = 0;
    for (int k = j; k < nblk; k += 16) s += blockcnt[k * 64 + b];
    part[j][b] = s;
    __syncthreads();
    if (threadIdx.x < 64) {
        int t = 0;
#pragma unroll
        for (int jj = 1; jj < 16; ++jj) t += part[jj][threadIdx.x];
        part[0][threadIdx.x] += t;
    }
    __syncthreads();
    if (threadIdx.x == 0) {
        int base = 0;
        for (int bb = 0; bb < 64; ++bb) {
            int t = part[0][bb];
            bucketbase[bb] = base;
            base += t;
        }
    }
}

__global__ __launch_bounds__(64) void hist_scan2(int* __restrict__ blockcnt,
                                                 const int* __restrict__ bucketbase,
                                                 int nblk) {
    int b = blockIdx.x;
    int lane = threadIdx.x;
    int carry = bucketbase[b];
    for (int chunk = 0; chunk * 64 < nblk; ++chunk) {
        int k = chunk * 64 + lane;
        int c = (k < nblk) ? blockcnt[k * 64 + b] : 0;
        int v = c;
#pragma unroll
        for (int ofs = 1; ofs < 64; ofs <<= 1) {
            int t = __shfl_up(v, ofs, 64);
            if (lane >= ofs) v += t;
        }
        if (k < nblk) blockcnt[k * 64 + b] = carry + v - c;
        carry += __shfl(v, 63, 64);
    }
}

__global__ __launch_bounds__(HB) void degscatter2(const int* __restrict__ cnt,
                                                  const int* __restrict__ lrank,
                                                  const int* __restrict__ blockcnt,
                                                  int* __restrict__ nodeorder, int N) {
    int n = blockIdx.x * HB + threadIdx.x;
    if (n >= N) return;
    int b = min(cnt[n], 63);
    int pos = blockcnt[(n / HB) * 64 + b] + lrank[n];
    nodeorder[N - 1 - pos] = n;   // descending degree
}

// ---------------------------------------------------------------------------
// node_pre (MFMA): one wave per 16-node tile. Ps|Pd = h @ [Wsrc|Wdst]^T
// (be1 baked into Pd). Also packs x -> float4.
// ---------------------------------------------------------------------------
__global__ __launch_bounds__(256) void node_pre(
    const float* __restrict__ h, const unsigned short* __restrict__ WpB1,
    const float* __restrict__ be1, const float* __restrict__ xin,
    float* __restrict__ Ps, float* __restrict__ Pd,
    float4* __restrict__ x4, int N) {
    const int lane = threadIdx.x & 63;
    const int wslot = threadIdx.x >> 6;
    {
        int n = blockIdx.x * 64 + threadIdx.x;
        if (threadIdx.x < 64 && n < N)
            x4[n] = make_float4(xin[3 * n], xin[3 * n + 1], xin[3 * n + 2], 0.f);
    }
    const int tile = (blockIdx.x * 4 + wslot) * 16;
    if (tile >= N) return;
    const int r15 = lane & 15, kg = lane >> 4;
    const int arow = min(tile + r15, N - 1);
    const float* hr = h + (size_t)arow * DF + kg * 8;
    short8v A[4];
#pragma unroll
    for (int kc = 0; kc < 4; ++kc) {
        float4 q0 = *(const float4*)(hr + kc * 32);
        float4 q1 = *(const float4*)(hr + kc * 32 + 4);
        A[kc] = pack_bf16(q0, q1);
    }
#pragma unroll
    for (int ft = 0; ft < 8; ++ft) {
        float4v c = (float4v){0.f, 0.f, 0.f, 0.f};
#pragma unroll
        for (int kc = 0; kc < 4; ++kc) {
            short8v B = *(const short8v*)&WpB1[(((ft * 4 + kc) * 64) + lane) * 8];
            c = __builtin_amdgcn_mfma_f32_16x16x32_bf16(A[kc], B, c, 0, 0, 0);
        }
        int f = ft * 16 + r15;
        float bias = (f >= 64) ? be1[f - 64] : 0.f;
#pragma unroll
        for (int r = 0; r < 4; ++r) {
            int n = tile + kg * 4 + r;
            if (n < N) {
                float v = c[r] + bias;
                if (f < 64) Ps[(size_t)n * 64 + f] = v;
                else        Pd[(size_t)n * 64 + (f - 64)] = v;
            }
        }
    }
}

// ---------------------------------------------------------------------------
// Gather v12: quad-node MFMA batches + FULL one-batch software pipeline:
// during batch b's compute, batch b+1's entire load chain (csr_src -> x4 ->
// Ps) is in flight. Rotate set ~+21 VGPR: 104 -> ~124, still 4 waves/SIMD.
// NEVER pass a min-waves launch_bounds arg (r3/r11 spill cliffs).
// ---------------------------------------------------------------------------
__global__ __launch_bounds__(256) void gather_kernel(
    const int* __restrict__ csr_src, const int* __restrict__ off,
    const int* __restrict__ nodeorder, const float4* __restrict__ x4,
    const float* __restrict__ Ps, const float* __restrict__ Pd,
    const float* __restrict__ Wt1, const unsigned short* __restrict__ WbfA,
    const float* __restrict__ be2,
    const float* __restrict__ ln_g, const float* __restrict__ ln_b,
    const float* __restrict__ Wx, const float* __restrict__ bx,
    const float* __restrict__ Wg, const float* __restrict__ bg,
    float* __restrict__ agg_h, float* __restrict__ xout, int N) {
    const int lane = threadIdx.x & 63;
    const int wid = blockIdx.x * 4 + (threadIdx.x >> 6);
    const int e16 = lane & 15;
    const int hg = lane >> 4;
    const int k0 = hg * 8;
    const int p = e16 & 3;
    if (wid * 4 >= N) return;
    const int slot = wid * 4 + (e16 >> 2);

    short8v a[4][2];
#pragma unroll
    for (int t = 0; t < 4; ++t)
#pragma unroll
        for (int kc = 0; kc < 2; ++kc)
            a[t][kc] = *(const short8v*)&WbfA[(((t * 2 + kc) * 64) + lane) * 8];

    const float* colW = Wt1 + 256 * HID;
    float colWk[16];
#pragma unroll
    for (int j = 0; j < 8; ++j) {
        colWk[j] = colW[k0 + j];
        colWk[8 + j] = colW[k0 + 32 + j];
    }
    float be2r[16], cgr[16], cxr[16];
#pragma unroll
    for (int t = 0; t < 4; ++t)
#pragma unroll
        for (int r = 0; r < 4; ++r) {
            int f = t * 16 + hg * 4 + r;
            float g = ln_g[f];
            be2r[4 * t + r] = be2[f];
            cgr[4 * t + r] = g * Wg[f];
            cxr[4 * t + r] = g * Wx[f];
        }
    const float bgs = bg[0], bxs = bx[0];

    float Cg = ln_g[lane] * Wg[lane], Cx = ln_g[lane] * Wx[lane];
    float Cbg = ln_b[lane] * Wg[lane], Cbx = ln_b[lane] * Wx[lane];
    wredsum4(Cg, Cx, Cbg, Cbx);
    const float g0 = (lane < 16) ? 1.0f : 0.0f;

    const int nj = (slot < N) ? nodeorder[slot] : -1;
    int beg = 0, end = 0;
    if (nj >= 0) { beg = off[nj]; end = off[nj + 1]; }
    const float4 xdv = (nj >= 0) ? x4[nj] : make_float4(0.f, 0.f, 0.f, 0.f);
    float baseK[16];
    {
        const float4v* pd4 = (const float4v*)(Pd + (size_t)max(nj, 0) * HID + k0);
        float4v p0 = pd4[0], p1 = pd4[1], p2 = pd4[8], p3 = pd4[9];
#pragma unroll
        for (int j = 0; j < 4; ++j) {
            baseK[j] = p0[j];
            baseK[4 + j] = p1[j];
            baseK[8 + j] = p2[j];
            baseK[12 + j] = p3[j];
        }
    }

    int nb = (end - beg + 3) >> 2;
#pragma unroll
    for (int mk = 1; mk < 64; mk <<= 1) nb = max(nb, __shfl_xor(nb, mk, 64));
    nb = __builtin_amdgcn_readfirstlane(nb);

    float4v acc[4];
#pragma unroll
    for (int t = 0; t < 4; ++t) acc[t] = (float4v){0.f, 0.f, 0.f, 0.f};
    float ax0 = 0.f, ax1 = 0.f, ax2 = 0.f, Sa = 0.f, Smu = 0.f;

    // ---- one-batch pipeline: prime batch 0's loads ----
    float4 xsC = xdv;
    float4v q0C = (float4v){0.f, 0.f, 0.f, 0.f}, q1C = q0C, q2C = q0C, q3C = q0C;
    if (nb > 0) {
        int idx = beg + p;
        int ic = (idx < end) ? idx : (end > 0 ? end - 1 : 0);
        int s0 = csr_src[ic];
        xsC = x4[s0];
        const float4v* ps4 = (const float4v*)(Ps + (size_t)s0 * HID + k0);
        q0C = ps4[0]; q1C = ps4[1]; q2C = ps4[8]; q3C = ps4[9];
    }

    for (int b = 0; b < nb; ++b) {
        // consume current batch's pipelined registers
        float4 xs = xsC;
        float4v q0 = q0C, q1 = q1C, q2 = q2C, q3 = q3C;
        float validf = ((beg + b * 4 + p) < end) ? 1.0f : 0.0f;

        // issue next batch's full load chain (overlaps with compute below)
        if (b + 1 < nb) {
            int idx2 = beg + (b + 1) * 4 + p;
            int ic2 = (idx2 < end) ? idx2 : (end > 0 ? end - 1 : 0);
            int sN = csr_src[ic2];
            xsC = x4[sN];
            const float4v* ps4 = (const float4v*)(Ps + (size_t)sN * HID + k0);
            q0C = ps4[0]; q1C = ps4[1]; q2C = ps4[8]; q3C = ps4[9];
        }

        float r0 = xs.x - xdv.x, r1 = xs.y - xdv.y, r2 = xs.z - xdv.z;
        float dsq = r0 * r0 + r1 * r1 + r2 * r2;
        float inv = __builtin_amdgcn_rcpf(__builtin_amdgcn_sqrtf(dsq) + 1e-8f);

        float zb[16];
#pragma unroll
        for (int j = 0; j < 4; ++j) {
            zb[j]      = silu_f(q0[j] + baseK[j] + dsq * colWk[j]);
            zb[4 + j]  = silu_f(q1[j] + baseK[4 + j] + dsq * colWk[4 + j]);
            zb[8 + j]  = silu_f(q2[j] + baseK[8 + j] + dsq * colWk[8 + j]);
            zb[12 + j] = silu_f(q3[j] + baseK[12 + j] + dsq * colWk[12 + j]);
        }
        short8v b0 = pack8(zb[0], zb[1], zb[2], zb[3], zb[4], zb[5], zb[6], zb[7]);
        short8v b1 = pack8(zb[8], zb[9], zb[10], zb[11], zb[12], zb[13], zb[14], zb[15]);

        float ms[16];
        float S1 = 0.f, S2 = 0.f, Sg = 0.f, Sx = 0.f;
#pragma unroll
        for (int t = 0; t < 4; ++t) {
            float4v c = (float4v){be2r[4 * t], be2r[4 * t + 1],
                                  be2r[4 * t + 2], be2r[4 * t + 3]};
            c = __builtin_amdgcn_mfma_f32_16x16x32_bf16(a[t][0], b0, c, 0, 0, 0);
            c = __builtin_amdgcn_mfma_f32_16x16x32_bf16(a[t][1], b1, c, 0, 0, 0);
#pragma unroll
            for (int r = 0; r < 4; ++r) {
                float v = c[r] * __builtin_amdgcn_rcpf(1.0f + __expf(-c[r]));
                ms[4 * t + r] = v;
                S1 += v;
                S2 = fmaf(v, v, S2);
                Sg = fmaf(v, cgr[4 * t + r], Sg);
                Sx = fmaf(v, cxr[4 * t + r], Sx);
            }
        }
#pragma unroll
        for (int mk = 16; mk < 64; mk <<= 1) {
            S1 += __shfl_xor(S1, mk, 64);
            S2 += __shfl_xor(S2, mk, 64);
            Sg += __shfl_xor(Sg, mk, 64);
            Sx += __shfl_xor(Sx, mk, 64);
        }

        float mu = S1 * (1.0f / HID);
        float var = S2 * (1.0f / HID) - mu * mu;
        float rstd = __builtin_amdgcn_rsqf(var + 1e-5f);
        float dg = fmaf(rstd, Sg - mu * Cg, Cbg);
        float dx = fmaf(rstd, Sx - mu * Cx, Cbx);
        float alpha = __builtin_amdgcn_rcpf(1.0f + __expf(-(dg + bgs))) * validf;
        float ta = __expf(2.0f * fmaf(alpha, dx, bxs));
        float cwv = 1.0f - 2.0f * __builtin_amdgcn_rcpf(ta + 1.0f);

        float u = rstd * alpha;
        Sa += alpha;
        Smu = fmaf(u, mu, Smu);
#pragma unroll
        for (int t = 0; t < 4; ++t) {
            float4v av = acc[t];
#pragma unroll
            for (int r = 0; r < 4; ++r) av[r] = fmaf(u, ms[4 * t + r], av[r]);
            acc[t] = av;
        }
        float rc = inv * cwv * validf * g0;
        ax0 = fmaf(r0, rc, ax0);
        ax1 = fmaf(r1, rc, ax1);
        ax2 = fmaf(r2, rc, ax2);
    }

#pragma unroll
    for (int t = 0; t < 4; ++t) {
        float4v av = acc[t];
#pragma unroll
        for (int r = 0; r < 4; ++r) {
            float v = av[r];
            v += __shfl_xor(v, 1, 64);
            v += __shfl_xor(v, 2, 64);
            av[r] = v;
        }
        acc[t] = av;
    }
    Sa  += __shfl_xor(Sa, 1, 64);  Sa  += __shfl_xor(Sa, 2, 64);
    Smu += __shfl_xor(Smu, 1, 64); Smu += __shfl_xor(Smu, 2, 64);
    ax0 += __shfl_xor(ax0, 1, 64); ax0 += __shfl_xor(ax0, 2, 64);
    ax1 += __shfl_xor(ax1, 1, 64); ax1 += __shfl_xor(ax1, 2, 64);
    ax2 += __shfl_xor(ax2, 1, 64); ax2 += __shfl_xor(ax2, 2, 64);

    if (p == 0 && nj >= 0) {
        float* dstp = agg_h + (size_t)nj * HID + hg * 4;
#pragma unroll
        for (int t = 0; t < 4; ++t) {
            int f = t * 16 + hg * 4;
            float4 o;
            o.x = fmaf(ln_g[f + 0], acc[t][0] - Smu, ln_b[f + 0] * Sa);
            o.y = fmaf(ln_g[f + 1], acc[t][1] - Smu, ln_b[f + 1] * Sa);
            o.z = fmaf(ln_g[f + 2], acc[t][2] - Smu, ln_b[f + 2] * Sa);
            o.w = fmaf(ln_g[f + 3], acc[t][3] - Smu, ln_b[f + 3] * Sa);
            *(float4*)(dstp + t * 16) = o;
        }
        if (hg == 0) {
            float invd = 1.0f / fmaxf((float)(end - beg), 1.0f);
            float* ox = xout + (size_t)nj * 3;
            ox[0] = xdv.x + ax0 * invd;
            ox[1] = xdv.y + ax1 * invd;
            ox[2] = xdv.z + ax2 * invd;
        }
    }
}

// ---------------------------------------------------------------------------
// Fallback edge kernel (atomic aggregation) — only if ws too small for CSR.
// ---------------------------------------------------------------------------
__global__ __launch_bounds__(256) void edge_kernel_atomic(
    const int* __restrict__ src, const int* __restrict__ dst,
    const float* __restrict__ x,
    const float* __restrict__ Ps, const float* __restrict__ Pd,
    const float* __restrict__ Wt1, const float* __restrict__ Wt2,
    const float* __restrict__ be2,
    const float* __restrict__ ln_g, const float* __restrict__ ln_b,
    const float* __restrict__ Wx, const float* __restrict__ bx,
    const float* __restrict__ Wg, const float* __restrict__ bg,
    float* __restrict__ agg_h, float* __restrict__ agg_x, int E) {
    int e = blockIdx.x * 256 + threadIdx.x;
    if (e >= E) return;
    int s = src[e], d = dst[e];
    float r0 = x[s * 3] - x[d * 3], r1 = x[s * 3 + 1] - x[d * 3 + 1], r2 = x[s * 3 + 2] - x[d * 3 + 2];
    float dsq = r0 * r0 + r1 * r1 + r2 * r2;
    float inv = 1.0f / (sqrtf(dsq) + 1e-8f);
    float rn0 = r0 * inv, rn1 = r1 * inv, rn2 = r2 * inv;
    float z[HID];
    const float4* ps = (const float4*)(Ps + (size_t)s * HID);
    const float4* pd = (const float4*)(Pd + (size_t)d * HID);
    const float* colW = Wt1 + 256 * HID;
#pragma unroll
    for (int f4 = 0; f4 < HID / 4; ++f4) {
        float4 aa = ps[f4];
        float4 b = pd[f4];
        float av[4] = {aa.x, aa.y, aa.z, aa.w};
        float bv[4] = {b.x, b.y, b.z, b.w};
#pragma unroll
        for (int j = 0; j < 4; ++j) {
            int f = 4 * f4 + j;
            z[f] = silu_f(av[j] + bv[j] + dsq * colW[f]);
        }
    }
    float m[HID];
#pragma unroll
    for (int f = 0; f < HID; ++f) m[f] = be2[f];
#pragma unroll
    for (int k = 0; k < HID; ++k) {
        float zv = z[k];
#pragma unroll
        for (int f = 0; f < HID; ++f) m[f] = fmaf(zv, Wt2[k * HID + f], m[f]);
    }
#pragma unroll
    for (int f = 0; f < HID; ++f) m[f] = silu_f(m[f]);
    float mu = 0.f;
#pragma unroll
    for (int f = 0; f < HID; ++f) mu += m[f];
    mu *= (1.0f / HID);
    float var = 0.f;
#pragma unroll
    for (int f = 0; f < HID; ++f) {
        float t = m[f] - mu;
        var = fmaf(t, t, var);
    }
    var *= (1.0f / HID);
    float rstd = 1.0f / sqrtf(var + 1e-5f);
#pragma unroll
    for (int f = 0; f < HID; ++f) m[f] = (m[f] - mu) * rstd * ln_g[f] + ln_b[f];
    float dotg = 0.f, dotx = 0.f;
#pragma unroll
    for (int f = 0; f < HID; ++f) {
        dotg = fmaf(m[f], Wg[f], dotg);
        dotx = fmaf(m[f], Wx[f], dotx);
    }
    float alpha = 1.0f / (1.0f + __expf(-(dotg + bg[0])));
    float ta = __expf(2.0f * fmaf(alpha, dotx, bx[0]));
    float cw = 1.0f - 2.0f / (ta + 1.0f);
    float* ah = agg_h + (size_t)d * HID;
#pragma unroll
    for (int f = 0; f < HID; ++f) atomicAdd(&ah[f], m[f] * alpha);
    atomicAdd(&agg_x[d * 3 + 0], rn0 * cw);
    atomicAdd(&agg_x[d * 3 + 1], rn1 * cw);
    atomicAdd(&agg_x[d * 3 + 2], rn2 * cw);
}

// ---------------------------------------------------------------------------
// node_kernel (MFMA): one wave per 16-node tile. x-tail only when writeX!=0.
// ---------------------------------------------------------------------------
__global__ __launch_bounds__(256) void node_kernel(
    const float* __restrict__ h, const float* __restrict__ xin,
    const float* __restrict__ agg_h, const float* __restrict__ agg_x,
    const int* __restrict__ degI,
    const unsigned short* __restrict__ WpH1, const unsigned short* __restrict__ WpH2,
    const float* __restrict__ bh1, const float* __restrict__ bh2,
    float* __restrict__ out, int N, int writeX) {
    __shared__ float hhL[4][16][72];
    const int lane = threadIdx.x & 63;
    const int wslot = threadIdx.x >> 6;
    if (writeX) {
        int n = blockIdx.x * 64 + threadIdx.x;
        if (threadIdx.x < 64 && n < N) {
            float dv = (float)degI[n];
            float invd = 1.0f / fmaxf(dv, 1.0f);
            float* ox = out + (size_t)N * DF + (size_t)n * 3;
            ox[0] = xin[n * 3 + 0] + agg_x[n * 3 + 0] * invd;
            ox[1] = xin[n * 3 + 1] + agg_x[n * 3 + 1] * invd;
            ox[2] = xin[n * 3 + 2] + agg_x[n * 3 + 2] * invd;
        }
    }
    const int tile = (blockIdx.x * 4 + wslot) * 16;
    if (tile >= N) return;
    const int r15 = lane & 15, kg = lane >> 4;
    const int arow = min(tile + r15, N - 1);

    short8v A[6];
    const float* hr = h + (size_t)arow * DF + kg * 8;
#pragma unroll
    for (int kc = 0; kc < 4; ++kc) {
        float4 q0 = *(const float4*)(hr + kc * 32);
        float4 q1 = *(const float4*)(hr + kc * 32 + 4);
        A[kc] = pack_bf16(q0, q1);
    }
    const float* ar = agg_h + (size_t)arow * HID + kg * 8;
#pragma unroll
    for (int kc = 0; kc < 2; ++kc) {
        float4 q0 = *(const float4*)(ar + kc * 32);
        float4 q1 = *(const float4*)(ar + kc * 32 + 4);
        A[4 + kc] = pack_bf16(q0, q1);
    }

#pragma unroll
    for (int ft = 0; ft < 4; ++ft) {
        float4v c = (float4v){0.f, 0.f, 0.f, 0.f};
#pragma unroll
        for (int kc = 0; kc < 6; ++kc) {
            short8v B = *(const short8v*)&WpH1[(((ft * 6 + kc) * 64) + lane) * 8];
            c = __builtin_amdgcn_mfma_f32_16x16x32_bf16(A[kc], B, c, 0, 0, 0);
        }
        int f = ft * 16 + r15;
        float b1v = bh1[f];
#pragma unroll
        for (int r = 0; r < 4; ++r)
            hhL[wslot][kg * 4 + r][f] = silu_f(c[r] + b1v);
    }
    __builtin_amdgcn_wave_barrier();

    short8v HA[2];
#pragma unroll
    for (int kc = 0; kc < 2; ++kc) {
        float4 q0 = *(const float4*)&hhL[wslot][r15][kc * 32 + kg * 8];
        float4 q1 = *(const float4*)&hhL[wslot][r15][kc * 32 + kg * 8 + 4];
        HA[kc] = pack_bf16(q0, q1);
    }

#pragma unroll
    for (int ft = 0; ft < 8; ++ft) {
        float4v c = (float4v){0.f, 0.f, 0.f, 0.f};
#pragma unroll
        for (int kc = 0; kc < 2; ++kc) {
            short8v B = *(const short8v*)&WpH2[(((ft * 2 + kc) * 64) + lane) * 8];
            c = __builtin_amdgcn_mfma_f32_16x16x32_bf16(HA[kc], B, c, 0, 0, 0);
        }
        int cc = ft * 16 + r15;
        float b2 = bh2[cc];
#pragma unroll
        for (int r = 0; r < 4; ++r) {
            int n = tile + kg * 4 + r;
            if (n < N)
                out[(size_t)n * DF + cc] = h[(size_t)n * DF + cc] + c[r] + b2;
        }
    }
}

extern "C" void kernel_launch(void* const* d_in, const int* in_sizes, int n_in,
                              void* d_out, int out_size, void* d_ws, size_t ws_size,
                              hipStream_t stream) {
    const float* h    = (const float*)d_in[0];
    const float* x    = (const float*)d_in[1];
    const int*   ei   = (const int*)d_in[2];
    const float* We1  = (const float*)d_in[3];
    const float* be1  = (const float*)d_in[4];
    const float* We2  = (const float*)d_in[5];
    const float* be2  = (const float*)d_in[6];
    const float* ln_g = (const float*)d_in[7];
    const float* ln_b = (const float*)d_in[8];
    const float* Wh1  = (const float*)d_in[9];
    const float* bh1  = (const float*)d_in[10];
    const float* Wh2  = (const float*)d_in[11];
    const float* bh2  = (const float*)d_in[12];
    const float* Wx   = (const float*)d_in[13];
    const float* bx   = (const float*)d_in[14];
    const float* Wg   = (const float*)d_in[15];
    const float* bg   = (const float*)d_in[16];

    const int E = in_sizes[2] / 2;
    const int N = in_sizes[0] / DF;
    const int* src = ei;
    const int* dst = ei + E;

    // ---- workspace carve (16B aligned regions) ----
    char* base = (char*)d_ws;
    size_t o = 0;
    auto carve = [&](size_t bytes) -> void* {
        void* r = base + o;
        o = (o + bytes + 15) & ~(size_t)15;
        return r;
    };
    const int nblk = (N + HB - 1) / HB;
    float* agg_h = (float*)carve((size_t)N * HID * 4);
    float* agg_x = (float*)carve((size_t)N * 3 * 4);
    float* Wt1   = (float*)carve(257 * 64 * 4);
    float* Wt2   = (float*)carve(64 * 64 * 4);
    unsigned short* WbfA = (unsigned short*)carve(4096 * 2);
    unsigned short* WpB1 = (unsigned short*)carve(16384 * 2);
    unsigned short* WpH1 = (unsigned short*)carve(12288 * 2);
    unsigned short* WpH2 = (unsigned short*)carve(8192 * 2);
    int*   cnt   = (int*)carve((size_t)N * 4);
    int*   off   = (int*)carve(((size_t)N + 1) * 4);
    int*   bsum  = (int*)carve(256 * 4);
    int*   lrank = (int*)carve((size_t)N * 4);
    int*   blockcnt = (int*)carve((size_t)nblk * 64 * 4);
    int*   bucketbase = (int*)carve(64 * 4);
    int*   nodeorder = (int*)carve((size_t)N * 4);
    float4* x4   = (float4*)carve((size_t)N * 16);
    int*   rank  = (int*)carve((size_t)E * 4);
    int*   csr_src = (int*)carve((size_t)E * 4);
    size_t need_full = o;

    // Ps/Pd live in d_out (N*128 <= out_size N*131); fully overwritten later.
    float* Ps = (float*)d_out;
    float* Pd = Ps + (size_t)N * HID;
    float* xout = (float*)d_out + (size_t)N * DF;

    const int gE  = (E + 255) / 256;
    const int Nb  = (N + 1023) / 1024;
    const int tiles = (N + 15) / 16;
    const int gT  = (tiles + 3) / 4;

    prep_weights<<<(PREPW + N + 255) / 256, 256, 0, stream>>>(
        We1, We2, Wh1, Wh2, Wt1, Wt2, WbfA, WpB1, WpH1, WpH2, cnt, N);
    node_pre<<<gT, 256, 0, stream>>>(h, WpB1, be1, x, Ps, Pd, x4, N);

    if (ws_size >= need_full) {
        // ---- CSR build + parallel two-level degree counting sort ----
        count_kernel<<<gE, 256, 0, stream>>>(dst, cnt, rank, E);
        scan1<<<Nb, 1024, 0, stream>>>(cnt, off, bsum, N);
        scan3<<<(N + 256) / 256, 256, 0, stream>>>(off, bsum, Nb, N, E);
        scatter_src<<<gE, 256, 0, stream>>>(dst, src, rank, off, csr_src, E);
        hist_local<<<nblk, HB, 0, stream>>>(cnt, lrank, blockcnt, N);
        hist_tot<<<1, 1024, 0, stream>>>(blockcnt, bucketbase, nblk);
        hist_scan2<<<64, 64, 0, stream>>>(blockcnt, bucketbase, nblk);
        degscatter2<<<nblk, HB, 0, stream>>>(cnt, lrank, blockcnt, nodeorder, N);
        // ---- fused gather: quad-node MFMA batches; writes xout directly ----
        const int quads = (N + 3) / 4;
        gather_kernel<<<(quads + 3) / 4, 256, 0, stream>>>(
            csr_src, off, nodeorder, x4, Ps, Pd, Wt1, WbfA, be2,
            ln_g, ln_b, Wx, bx, Wg, bg, agg_h, xout, N);
        node_kernel<<<gT, 256, 0, stream>>>(h, x, agg_h, agg_x, cnt,
                                            WpH1, WpH2, bh1, bh2, (float*)d_out, N, 0);
    } else {
        // ---- fallback: atomic aggregation ----
        hipMemsetAsync(agg_h, 0, (size_t)N * 67 * 4, stream);
        count_kernel<<<gE, 256, 0, stream>>>(dst, cnt, nullptr, E);
        edge_kernel_atomic<<<gE, 256, 0, stream>>>(src, dst, x, Ps, Pd, Wt1, Wt2,
                                                   be2, ln_g, ln_b, Wx, bx,
                                                   Wg, bg, agg_h, agg_x, E);
        node_kernel<<<gT, 256, 0, stream>>>(h, x, agg_h, agg_x, cnt,
                                            WpH1, WpH2, bh1, bh2, (float*)d_out, N, 1);
    }
}